// Round 1
// baseline (3524.878 us; speedup 1.0000x reference)
//
#include <hip/hip_runtime.h>
#include <hip/hip_bf16.h>
#include <math.h>

#define DIM   2048
#define S_LEN 2048
#define BATCH 2
#define NH    16
#define NKV   4
#define CQ_   128
#define QN_   96
#define QR_   32
#define CKV_  128
#define KN_   64
#define KR_   64
#define VD_   256
#define ROWS_TOT (BATCH*S_LEN)   // 4096

// ---------------------------------------------------------------------------
// K1: y = x @ [w_dq | w_dkv]  (per-row), then LN(q), LN(ckv), RoPE(k_rope)
//   x: (4096, 2048); w_dq: (2048,128); w_dkv: (2048,192)
//   outputs: cq_ln (4096,128), ckv_ln (4096,128), kr_rope (4096,64)
// 320 threads, 4 rows per block.
// ---------------------------------------------------------------------------
#define K1_ROWS 4
__global__ __launch_bounds__(320)
void k1_down_ln_rope(const float* __restrict__ x,
                     const float* __restrict__ w_dq,
                     const float* __restrict__ gamma_q,
                     const float* __restrict__ w_dkv,
                     const float* __restrict__ gamma_kv,
                     float* __restrict__ cq_ln,
                     float* __restrict__ ckv_ln,
                     float* __restrict__ kr_rope)
{
    __shared__ float xs[K1_ROWS][DIM];     // 32 KB
    __shared__ float ys[K1_ROWS][320];     // 5 KB
    __shared__ float stats[K1_ROWS][4];    // mu_q, rs_q, mu_kv, rs_kv
    const int tid = threadIdx.x;
    const int r0  = blockIdx.x * K1_ROWS;

    for (int i = tid; i < K1_ROWS * DIM; i += 320) {
        int rr = i >> 11, k = i & (DIM - 1);
        xs[rr][k] = x[(size_t)(r0 + rr) * DIM + k];
    }
    __syncthreads();

    float acc0 = 0.f, acc1 = 0.f, acc2 = 0.f, acc3 = 0.f;
    if (tid < 128) {
        const float* w = w_dq + tid;
        for (int k = 0; k < DIM; ++k) {
            float wv = w[(size_t)k * CQ_];
            acc0 += xs[0][k] * wv; acc1 += xs[1][k] * wv;
            acc2 += xs[2][k] * wv; acc3 += xs[3][k] * wv;
        }
    } else {
        const float* w = w_dkv + (tid - 128);
        for (int k = 0; k < DIM; ++k) {
            float wv = w[(size_t)k * (CKV_ + KR_)];
            acc0 += xs[0][k] * wv; acc1 += xs[1][k] * wv;
            acc2 += xs[2][k] * wv; acc3 += xs[3][k] * wv;
        }
    }
    ys[0][tid] = acc0; ys[1][tid] = acc1; ys[2][tid] = acc2; ys[3][tid] = acc3;
    __syncthreads();

    if (tid < 8) {
        int rr = tid >> 1;
        int base = (tid & 1) ? 128 : 0;
        float s1 = 0.f, s2 = 0.f;
        for (int j = 0; j < 128; ++j) { float v = ys[rr][base + j]; s1 += v; s2 += v * v; }
        float mu  = s1 * (1.f / 128.f);
        float var = s2 * (1.f / 128.f) - mu * mu;
        stats[rr][(tid & 1) * 2 + 0] = mu;
        stats[rr][(tid & 1) * 2 + 1] = rsqrtf(var + 1e-5f);
    }
    __syncthreads();

    for (int rr = 0; rr < K1_ROWS; ++rr) {
        int r = r0 + rr;
        int spos = r & (S_LEN - 1);
        if (tid < 128) {
            cq_ln[(size_t)r * CQ_ + tid] =
                (ys[rr][tid] - stats[rr][0]) * stats[rr][1] * gamma_q[tid];
        } else if (tid < 256) {
            int j = tid - 128;
            ckv_ln[(size_t)r * CKV_ + j] =
                (ys[rr][tid] - stats[rr][2]) * stats[rr][3] * gamma_kv[j];
        } else {
            int d = tid - 256;            // 0..63, RoPE over D=64
            int i2 = d >> 1;
            float xe = ys[rr][256 + (d & ~1)];
            float xo = ys[rr][256 + (d | 1)];
            float inv = powf(10000.f, -((float)(2 * i2)) / 64.f);
            float ang = (float)spos * inv;
            float sn, c; sincosf(ang, &sn, &c);
            kr_rope[(size_t)r * KR_ + d] = (d & 1) ? (xe * sn + xo * c)
                                                   : (xe * c - xo * sn);
        }
    }
}

// ---------------------------------------------------------------------------
// K2: q = cq_ln @ w_uq (128 -> 2048), split nope/rope, RoPE(D=32) per head,
//     store q_states as (B, H, S, 128)  [0..95 nope, 96..127 rope]
// 256 threads, 8 rows per block, 8 cols per thread.
// ---------------------------------------------------------------------------
#define K2_ROWS 8
__global__ __launch_bounds__(256)
void k2_upq_rope(const float* __restrict__ cq_ln,
                 const float* __restrict__ w_uq,
                 float* __restrict__ q_states)
{
    __shared__ float cs[K2_ROWS][CQ_];          // 4 KB
    __shared__ float qraw[K2_ROWS][NH * QR_];   // 16 KB (rope cols pre-rotation)
    const int tid = threadIdx.x;
    const int r0  = blockIdx.x * K2_ROWS;

    for (int i = tid; i < K2_ROWS * CQ_; i += 256)
        cs[i >> 7][i & 127] = cq_ln[(size_t)r0 * CQ_ + i];
    __syncthreads();

    float acc[K2_ROWS][8];
    #pragma unroll
    for (int rr = 0; rr < K2_ROWS; ++rr)
        #pragma unroll
        for (int cc = 0; cc < 8; ++cc) acc[rr][cc] = 0.f;

    for (int k = 0; k < CQ_; ++k) {
        float a[K2_ROWS];
        #pragma unroll
        for (int rr = 0; rr < K2_ROWS; ++rr) a[rr] = cs[rr][k];
        const float* wrow = w_uq + (size_t)k * (NH * (QN_ + QR_)) + tid;
        #pragma unroll
        for (int cc = 0; cc < 8; ++cc) {
            float b = wrow[cc * 256];
            #pragma unroll
            for (int rr = 0; rr < K2_ROWS; ++rr) acc[rr][cc] += a[rr] * b;
        }
    }

    #pragma unroll
    for (int cc = 0; cc < 8; ++cc) {
        int j = cc * 256 + tid;
        if (j < NH * QN_) {
            int h = j / QN_, d = j % QN_;
            for (int rr = 0; rr < K2_ROWS; ++rr) {
                int r = r0 + rr, b = r >> 11, spos = r & (S_LEN - 1);
                q_states[(((size_t)b * NH + h) * S_LEN + spos) * 128 + d] = acc[rr][cc];
            }
        } else {
            int jj = j - NH * QN_;
            for (int rr = 0; rr < K2_ROWS; ++rr) qraw[rr][jj] = acc[rr][cc];
        }
    }
    __syncthreads();

    for (int i = tid; i < K2_ROWS * NH * QR_; i += 256) {
        int rr = i >> 9, jj = i & 511;
        int h = jj >> 5, d = jj & 31;
        int r = r0 + rr, b = r >> 11, spos = r & (S_LEN - 1);
        int i2 = d >> 1;
        float xe = qraw[rr][(h << 5) + (d & ~1)];
        float xo = qraw[rr][(h << 5) + (d | 1)];
        float inv = powf(10000.f, -((float)(2 * i2)) / 32.f);
        float ang = (float)spos * inv;
        float sn, c; sincosf(ang, &sn, &c);
        float v = (d & 1) ? (xe * sn + xo * c) : (xe * c - xo * sn);
        q_states[(((size_t)b * NH + h) * S_LEN + spos) * 128 + QN_ + d] = v;
    }
}

// ---------------------------------------------------------------------------
// K3: kv = ckv_ln @ w_ukv (128 -> 1280), split k_nope/v, broadcast k_rope.
//   k_states: (B, KV, S, 128) [0..63 nope, 64..127 rope]
//   v_states: (B, KV, S, 256)
// 256 threads, 8 rows per block, 5 cols per thread.
// ---------------------------------------------------------------------------
#define K3_ROWS 8
__global__ __launch_bounds__(256)
void k3_upkv(const float* __restrict__ ckv_ln,
             const float* __restrict__ w_ukv,
             const float* __restrict__ kr_rope,
             float* __restrict__ k_states,
             float* __restrict__ v_states)
{
    __shared__ float cs[K3_ROWS][CKV_];
    const int tid = threadIdx.x;
    const int r0  = blockIdx.x * K3_ROWS;
    const int NCOL = NKV * (KN_ + VD_);   // 1280

    for (int i = tid; i < K3_ROWS * CKV_; i += 256)
        cs[i >> 7][i & 127] = ckv_ln[(size_t)r0 * CKV_ + i];
    __syncthreads();

    float acc[K3_ROWS][5];
    #pragma unroll
    for (int rr = 0; rr < K3_ROWS; ++rr)
        #pragma unroll
        for (int cc = 0; cc < 5; ++cc) acc[rr][cc] = 0.f;

    for (int k = 0; k < CKV_; ++k) {
        float a[K3_ROWS];
        #pragma unroll
        for (int rr = 0; rr < K3_ROWS; ++rr) a[rr] = cs[rr][k];
        const float* wrow = w_ukv + (size_t)k * NCOL + tid;
        #pragma unroll
        for (int cc = 0; cc < 5; ++cc) {
            float b = wrow[cc * 256];
            #pragma unroll
            for (int rr = 0; rr < K3_ROWS; ++rr) acc[rr][cc] += a[rr] * b;
        }
    }

    #pragma unroll
    for (int cc = 0; cc < 5; ++cc) {
        int j = cc * 256 + tid;
        if (j < NKV * KN_) {              // 256 k_nope cols
            int kvh = j >> 6, d = j & 63;
            for (int rr = 0; rr < K3_ROWS; ++rr) {
                int r = r0 + rr, b = r >> 11, spos = r & (S_LEN - 1);
                k_states[(((size_t)b * NKV + kvh) * S_LEN + spos) * 128 + d] = acc[rr][cc];
            }
        } else {                          // 1024 v cols
            int jj = j - NKV * KN_;
            int kvh = jj >> 8, d = jj & 255;
            for (int rr = 0; rr < K3_ROWS; ++rr) {
                int r = r0 + rr, b = r >> 11, spos = r & (S_LEN - 1);
                v_states[(((size_t)b * NKV + kvh) * S_LEN + spos) * VD_ + d] = acc[rr][cc];
            }
        }
    }

    for (int i = tid; i < K3_ROWS * KR_; i += 256) {
        int rr = i >> 6, d = i & 63;
        int r = r0 + rr, b = r >> 11, spos = r & (S_LEN - 1);
        float v = kr_rope[(size_t)r * KR_ + d];
        #pragma unroll
        for (int kvh = 0; kvh < NKV; ++kvh)
            k_states[(((size_t)b * NKV + kvh) * S_LEN + spos) * 128 + KN_ + d] = v;
    }
}

// ---------------------------------------------------------------------------
// K4: causal flash attention, f32.
//   grid: B * H * (S/64) blocks; 256 threads.
//   Per block: (b, h, qtile of 64 rows). Iterate k-tiles of 16.
//   Thread (qrow = tid&63, cg = tid>>6) accumulates o[64] (cols cg*64..+63).
// ---------------------------------------------------------------------------
__global__ __launch_bounds__(256)
void k4_attn(const float* __restrict__ q_states,
             const float* __restrict__ k_states,
             const float* __restrict__ v_states,
             float* __restrict__ attn_out)
{
    __shared__ float qs[64][132];   // 33.0 KB (pad 132: 16B-aligned rows, spread banks)
    __shared__ float ks[16][132];   //  8.25 KB
    __shared__ float vs[16][256];   // 16 KB
    __shared__ float ss[64][17];    //  4.25 KB
    const int tid = threadIdx.x;
    const int qt  = blockIdx.x & 31;
    const int h   = (blockIdx.x >> 5) & 15;
    const int b   = blockIdx.x >> 9;
    const int kvh = h >> 2;   // G = 4

    const float* qbase = q_states + (((size_t)b * NH + h)   * S_LEN + qt * 64) * 128;
    const float* kbase = k_states + (((size_t)b * NKV + kvh) * S_LEN) * 128;
    const float* vbase = v_states + (((size_t)b * NKV + kvh) * S_LEN) * VD_;

    const float scale = 0.08838834764831845f;   // 1/sqrt(128)
    // load Q tile (scaled) as float4
    for (int i = tid; i < 64 * 32; i += 256) {
        int row = i >> 5, c4 = i & 31;
        float4 q4 = reinterpret_cast<const float4*>(qbase + (size_t)row * 128)[c4];
        q4.x *= scale; q4.y *= scale; q4.z *= scale; q4.w *= scale;
        *reinterpret_cast<float4*>(&qs[row][c4 * 4]) = q4;
    }

    float o[64];
    #pragma unroll
    for (int c = 0; c < 64; ++c) o[c] = 0.f;
    float m = -1e30f, l = 0.f;
    const int qrow = tid & 63, cg = tid >> 6;
    const int qg = qt * 64 + qrow;
    const int nkt = (qt + 1) * 4;

    for (int kt = 0; kt < nkt; ++kt) {
        __syncthreads();   // protect ks/vs/ss reuse (also covers initial q load)
        for (int i = tid; i < 16 * 32; i += 256) {
            int row = i >> 5, c4 = i & 31;
            *reinterpret_cast<float4*>(&ks[row][c4 * 4]) =
                reinterpret_cast<const float4*>(kbase + (size_t)(kt * 16 + row) * 128)[c4];
        }
        for (int i = tid; i < 16 * 64; i += 256) {
            int row = i >> 6, c4 = i & 63;
            *reinterpret_cast<float4*>(&vs[row][c4 * 4]) =
                reinterpret_cast<const float4*>(vbase + (size_t)(kt * 16 + row) * VD_)[c4];
        }
        __syncthreads();

        // scores: this thread computes rows (tid&63) x 4 j's
        {
            const int j0 = cg * 4;
            float sacc[4] = {0.f, 0.f, 0.f, 0.f};
            for (int d4 = 0; d4 < 32; ++d4) {
                float4 q4 = *reinterpret_cast<const float4*>(&qs[qrow][d4 * 4]);
                #pragma unroll
                for (int j = 0; j < 4; ++j) {
                    float4 k4 = *reinterpret_cast<const float4*>(&ks[j0 + j][d4 * 4]);
                    sacc[j] += q4.x * k4.x + q4.y * k4.y + q4.z * k4.z + q4.w * k4.w;
                }
            }
            #pragma unroll
            for (int j = 0; j < 4; ++j) {
                int kg = kt * 16 + j0 + j;
                ss[qrow][j0 + j] = (kg <= qg) ? sacc[j] : -1e30f;
            }
        }
        __syncthreads();

        // online softmax update + PV
        float mnew = m;
        float p[16];
        #pragma unroll
        for (int j = 0; j < 16; ++j) { p[j] = ss[qrow][j]; mnew = fmaxf(mnew, p[j]); }
        float corr = __expf(m - mnew);
        m = mnew;
        float psum = 0.f;
        #pragma unroll
        for (int j = 0; j < 16; ++j) { p[j] = __expf(p[j] - mnew); psum += p[j]; }
        l = l * corr + psum;
        #pragma unroll
        for (int c = 0; c < 64; ++c) o[c] *= corr;
        for (int j = 0; j < 16; ++j) {
            float pj = p[j];
            const float4* v4p = reinterpret_cast<const float4*>(&vs[j][cg * 64]);
            #pragma unroll
            for (int c4 = 0; c4 < 16; ++c4) {
                float4 v4 = v4p[c4];
                o[c4 * 4 + 0] += pj * v4.x; o[c4 * 4 + 1] += pj * v4.y;
                o[c4 * 4 + 2] += pj * v4.z; o[c4 * 4 + 3] += pj * v4.w;
            }
        }
    }

    // write: attn_out layout (B, S, H, VD)
    const float inv_l = 1.f / l;
    const int spos = qt * 64 + qrow;
    float* obase = attn_out + (((size_t)(b * S_LEN + spos) * NH + h) * VD_) + cg * 64;
    #pragma unroll
    for (int c4 = 0; c4 < 16; ++c4) {
        float4 v4 = make_float4(o[c4 * 4 + 0] * inv_l, o[c4 * 4 + 1] * inv_l,
                                o[c4 * 4 + 2] * inv_l, o[c4 * 4 + 3] * inv_l);
        *reinterpret_cast<float4*>(obase + c4 * 4) = v4;
    }
}

// ---------------------------------------------------------------------------
// K5: out = attn_out (4096x4096) @ w_o (4096x2048), f32 tiled GEMM.
//   64x64 tile per block, BK=16, 256 threads, 4x4 micro-tile per thread.
// ---------------------------------------------------------------------------
__global__ __launch_bounds__(256)
void k5_gemm(const float* __restrict__ A,   // attn_out
             const float* __restrict__ B,   // w_o
             float* __restrict__ C)         // out
{
    const int M = ROWS_TOT;        // 4096
    const int N = DIM;             // 2048
    const int K = NH * VD_;        // 4096
    const int bn = blockIdx.x & 31, bm = blockIdx.x >> 5;
    const int t  = threadIdx.x;
    const int tn = t & 15, tm = t >> 4;
    __shared__ float As[16][68];   // A tile transposed: As[k][m]
    __shared__ float Bs[16][68];
    float c[4][4];
    #pragma unroll
    for (int i = 0; i < 4; ++i)
        #pragma unroll
        for (int j = 0; j < 4; ++j) c[i][j] = 0.f;
    const int m0 = bm * 64, n0 = bn * 64;

    for (int k0 = 0; k0 < K; k0 += 16) {
        {
            int m = t >> 2, kq = (t & 3) * 4;
            float4 a4 = *reinterpret_cast<const float4*>(&A[(size_t)(m0 + m) * K + k0 + kq]);
            As[kq + 0][m] = a4.x; As[kq + 1][m] = a4.y;
            As[kq + 2][m] = a4.z; As[kq + 3][m] = a4.w;
            int kk = t >> 4, nq = (t & 15) * 4;
            float4 b4 = *reinterpret_cast<const float4*>(&B[(size_t)(k0 + kk) * N + n0 + nq]);
            *reinterpret_cast<float4*>(&Bs[kk][nq]) = b4;
        }
        __syncthreads();
        #pragma unroll
        for (int k = 0; k < 16; ++k) {
            float4 a4 = *reinterpret_cast<const float4*>(&As[k][tm * 4]);
            float4 b4 = *reinterpret_cast<const float4*>(&Bs[k][tn * 4]);
            c[0][0] += a4.x * b4.x; c[0][1] += a4.x * b4.y; c[0][2] += a4.x * b4.z; c[0][3] += a4.x * b4.w;
            c[1][0] += a4.y * b4.x; c[1][1] += a4.y * b4.y; c[1][2] += a4.y * b4.z; c[1][3] += a4.y * b4.w;
            c[2][0] += a4.z * b4.x; c[2][1] += a4.z * b4.y; c[2][2] += a4.z * b4.z; c[2][3] += a4.z * b4.w;
            c[3][0] += a4.w * b4.x; c[3][1] += a4.w * b4.y; c[3][2] += a4.w * b4.z; c[3][3] += a4.w * b4.w;
        }
        __syncthreads();
    }

    #pragma unroll
    for (int i = 0; i < 4; ++i) {
        float4 v4 = make_float4(c[i][0], c[i][1], c[i][2], c[i][3]);
        *reinterpret_cast<float4*>(&C[(size_t)(m0 + tm * 4 + i) * N + n0 + tn * 4]) = v4;
    }
}

// ---------------------------------------------------------------------------
extern "C" void kernel_launch(void* const* d_in, const int* in_sizes, int n_in,
                              void* d_out, int out_size, void* d_ws, size_t ws_size,
                              hipStream_t stream)
{
    const float* x        = (const float*)d_in[0];
    const float* w_dq     = (const float*)d_in[1];
    const float* gamma_q  = (const float*)d_in[2];
    const float* w_uq     = (const float*)d_in[3];
    const float* w_dkv    = (const float*)d_in[4];
    const float* gamma_kv = (const float*)d_in[5];
    const float* w_ukv    = (const float*)d_in[6];
    const float* w_o      = (const float*)d_in[7];
    float* out = (float*)d_out;

    float* ws = (float*)d_ws;
    float* cq_ln    = ws;                 // 4096*128     =   524288
    float* ckv_ln   = cq_ln    + 524288;  // 4096*128     =   524288
    float* kr_rope  = ckv_ln   + 524288;  // 4096*64      =   262144
    float* q_states = kr_rope  + 262144;  // 2*16*2048*128 = 8388608
    float* k_states = q_states + 8388608; // 2*4*2048*128  = 2097152
    float* v_states = k_states + 2097152; // 2*4*2048*256  = 4194304
    float* attn_out = v_states + 4194304; // 2*2048*4096   = 16777216
    // total 32,768,000 floats = 131 MB

    k1_down_ln_rope<<<dim3(ROWS_TOT / K1_ROWS), dim3(320), 0, stream>>>(
        x, w_dq, gamma_q, w_dkv, gamma_kv, cq_ln, ckv_ln, kr_rope);

    k2_upq_rope<<<dim3(ROWS_TOT / K2_ROWS), dim3(256), 0, stream>>>(
        cq_ln, w_uq, q_states);

    k3_upkv<<<dim3(ROWS_TOT / K3_ROWS), dim3(256), 0, stream>>>(
        ckv_ln, w_ukv, kr_rope, k_states, v_states);

    k4_attn<<<dim3(BATCH * NH * (S_LEN / 64)), dim3(256), 0, stream>>>(
        q_states, k_states, v_states, attn_out);

    k5_gemm<<<dim3((ROWS_TOT / 64) * (DIM / 64)), dim3(256), 0, stream>>>(
        attn_out, w_o, out);
}

// Round 2
// 655.327 us; speedup vs baseline: 5.3788x; 5.3788x over previous
//
#include <hip/hip_runtime.h>
#include <hip/hip_bf16.h>
#include <math.h>

#define DIM   2048
#define S_LEN 2048
#define BATCH 2
#define NH    16
#define NKV   4
#define CQ_   128
#define QN_   96
#define QR_   32
#define CKV_  128
#define KN_   64
#define KR_   64
#define VD_   256
#define ROWS_TOT (BATCH*S_LEN)   // 4096

typedef __attribute__((ext_vector_type(8))) short short8;
typedef __attribute__((ext_vector_type(4))) float float4v;

__device__ inline short f2bf(float x) {
    union { __hip_bfloat16 h; short s; } u;
    u.h = __float2bfloat16(x);
    return u.s;
}

// ---------------------------------------------------------------------------
// K0T: w_o (4096 x 2048) f32  ->  w_oT (2048 x 4096) bf16
// 64x64 tiles, LDS pad 65 (f32: bank stride 1 -> conflict-free col reads)
// ---------------------------------------------------------------------------
__global__ __launch_bounds__(256)
void k0t_transpose_wo(const float* __restrict__ w_o, short* __restrict__ w_oT)
{
    __shared__ float tf[64][65];
    const int tid = threadIdx.x;
    const int nt = blockIdx.x & 31, kt = blockIdx.x >> 5;
    const int k0 = kt * 64, n0 = nt * 64;

    #pragma unroll
    for (int u4 = 0; u4 < 4; ++u4) {           // 1024 float4 chunks
        int u = u4 * 256 + tid;
        int kr = u >> 4, nc4 = (u & 15) * 4;
        float4 v = *reinterpret_cast<const float4*>(&w_o[(size_t)(k0 + kr) * DIM + n0 + nc4]);
        tf[kr][nc4 + 0] = v.x; tf[kr][nc4 + 1] = v.y;
        tf[kr][nc4 + 2] = v.z; tf[kr][nc4 + 3] = v.w;
    }
    __syncthreads();
    #pragma unroll
    for (int u2 = 0; u2 < 2; ++u2) {           // 512 bf16x8 chunks out
        int u = u2 * 256 + tid;
        int nr = u >> 3, kc8 = (u & 7) * 8;
        short8 o;
        #pragma unroll
        for (int j = 0; j < 8; ++j) o[j] = f2bf(tf[kc8 + j][nr]);
        *reinterpret_cast<short8*>(&w_oT[(size_t)(n0 + nr) * 4096 + k0 + kc8]) = o;
    }
}

// ---------------------------------------------------------------------------
// K1: y = x @ [w_dq | w_dkv], LN(q), LN(ckv), RoPE(k_rope)  (unchanged, f32)
// ---------------------------------------------------------------------------
#define K1_ROWS 4
__global__ __launch_bounds__(320)
void k1_down_ln_rope(const float* __restrict__ x,
                     const float* __restrict__ w_dq,
                     const float* __restrict__ gamma_q,
                     const float* __restrict__ w_dkv,
                     const float* __restrict__ gamma_kv,
                     float* __restrict__ cq_ln,
                     float* __restrict__ ckv_ln,
                     float* __restrict__ kr_rope)
{
    __shared__ float xs[K1_ROWS][DIM];
    __shared__ float ys[K1_ROWS][320];
    __shared__ float stats[K1_ROWS][4];
    const int tid = threadIdx.x;
    const int r0  = blockIdx.x * K1_ROWS;

    for (int i = tid; i < K1_ROWS * DIM; i += 320) {
        int rr = i >> 11, k = i & (DIM - 1);
        xs[rr][k] = x[(size_t)(r0 + rr) * DIM + k];
    }
    __syncthreads();

    float acc0 = 0.f, acc1 = 0.f, acc2 = 0.f, acc3 = 0.f;
    if (tid < 128) {
        const float* w = w_dq + tid;
        for (int k = 0; k < DIM; ++k) {
            float wv = w[(size_t)k * CQ_];
            acc0 += xs[0][k] * wv; acc1 += xs[1][k] * wv;
            acc2 += xs[2][k] * wv; acc3 += xs[3][k] * wv;
        }
    } else {
        const float* w = w_dkv + (tid - 128);
        for (int k = 0; k < DIM; ++k) {
            float wv = w[(size_t)k * (CKV_ + KR_)];
            acc0 += xs[0][k] * wv; acc1 += xs[1][k] * wv;
            acc2 += xs[2][k] * wv; acc3 += xs[3][k] * wv;
        }
    }
    ys[0][tid] = acc0; ys[1][tid] = acc1; ys[2][tid] = acc2; ys[3][tid] = acc3;
    __syncthreads();

    if (tid < 8) {
        int rr = tid >> 1;
        int base = (tid & 1) ? 128 : 0;
        float s1 = 0.f, s2 = 0.f;
        for (int j = 0; j < 128; ++j) { float v = ys[rr][base + j]; s1 += v; s2 += v * v; }
        float mu  = s1 * (1.f / 128.f);
        float var = s2 * (1.f / 128.f) - mu * mu;
        stats[rr][(tid & 1) * 2 + 0] = mu;
        stats[rr][(tid & 1) * 2 + 1] = rsqrtf(var + 1e-5f);
    }
    __syncthreads();

    for (int rr = 0; rr < K1_ROWS; ++rr) {
        int r = r0 + rr;
        int spos = r & (S_LEN - 1);
        if (tid < 128) {
            cq_ln[(size_t)r * CQ_ + tid] =
                (ys[rr][tid] - stats[rr][0]) * stats[rr][1] * gamma_q[tid];
        } else if (tid < 256) {
            int j = tid - 128;
            ckv_ln[(size_t)r * CKV_ + j] =
                (ys[rr][tid] - stats[rr][2]) * stats[rr][3] * gamma_kv[j];
        } else {
            int d = tid - 256;
            int i2 = d >> 1;
            float xe = ys[rr][256 + (d & ~1)];
            float xo = ys[rr][256 + (d | 1)];
            float inv = powf(10000.f, -((float)(2 * i2)) / 64.f);
            float ang = (float)spos * inv;
            float sn, c; sincosf(ang, &sn, &c);
            kr_rope[(size_t)r * KR_ + d] = (d & 1) ? (xe * sn + xo * c)
                                                   : (xe * c - xo * sn);
        }
    }
}

// ---------------------------------------------------------------------------
// K2: q = cq_ln @ w_uq, RoPE, scale 1/sqrt(128) folded -> q_states bf16
//     layout (B, H, S, 128)
// ---------------------------------------------------------------------------
#define K2_ROWS 8
#define QK_SCALE 0.08838834764831845f
__global__ __launch_bounds__(256)
void k2_upq_rope(const float* __restrict__ cq_ln,
                 const float* __restrict__ w_uq,
                 short* __restrict__ q_states)
{
    __shared__ float cs[K2_ROWS][CQ_];
    __shared__ float qraw[K2_ROWS][NH * QR_];
    const int tid = threadIdx.x;
    const int r0  = blockIdx.x * K2_ROWS;

    for (int i = tid; i < K2_ROWS * CQ_; i += 256)
        cs[i >> 7][i & 127] = cq_ln[(size_t)r0 * CQ_ + i];
    __syncthreads();

    float acc[K2_ROWS][8];
    #pragma unroll
    for (int rr = 0; rr < K2_ROWS; ++rr)
        #pragma unroll
        for (int cc = 0; cc < 8; ++cc) acc[rr][cc] = 0.f;

    for (int k = 0; k < CQ_; ++k) {
        float a[K2_ROWS];
        #pragma unroll
        for (int rr = 0; rr < K2_ROWS; ++rr) a[rr] = cs[rr][k];
        const float* wrow = w_uq + (size_t)k * (NH * (QN_ + QR_)) + tid;
        #pragma unroll
        for (int cc = 0; cc < 8; ++cc) {
            float b = wrow[cc * 256];
            #pragma unroll
            for (int rr = 0; rr < K2_ROWS; ++rr) acc[rr][cc] += a[rr] * b;
        }
    }

    #pragma unroll
    for (int cc = 0; cc < 8; ++cc) {
        int j = cc * 256 + tid;
        if (j < NH * QN_) {
            int h = j / QN_, d = j % QN_;
            for (int rr = 0; rr < K2_ROWS; ++rr) {
                int r = r0 + rr, b = r >> 11, spos = r & (S_LEN - 1);
                q_states[(((size_t)b * NH + h) * S_LEN + spos) * 128 + d] =
                    f2bf(acc[rr][cc] * QK_SCALE);
            }
        } else {
            int jj = j - NH * QN_;
            for (int rr = 0; rr < K2_ROWS; ++rr) qraw[rr][jj] = acc[rr][cc];
        }
    }
    __syncthreads();

    for (int i = tid; i < K2_ROWS * NH * QR_; i += 256) {
        int rr = i >> 9, jj = i & 511;
        int h = jj >> 5, d = jj & 31;
        int r = r0 + rr, b = r >> 11, spos = r & (S_LEN - 1);
        int i2 = d >> 1;
        float xe = qraw[rr][(h << 5) + (d & ~1)];
        float xo = qraw[rr][(h << 5) + (d | 1)];
        float inv = powf(10000.f, -((float)(2 * i2)) / 32.f);
        float ang = (float)spos * inv;
        float sn, c; sincosf(ang, &sn, &c);
        float v = (d & 1) ? (xe * sn + xo * c) : (xe * c - xo * sn);
        q_states[(((size_t)b * NH + h) * S_LEN + spos) * 128 + QN_ + d] =
            f2bf(v * QK_SCALE);
    }
}

// ---------------------------------------------------------------------------
// K3: kv = ckv_ln @ w_ukv -> k_states bf16 (B,KV,S,128), v_states bf16 (B,KV,S,256)
// ---------------------------------------------------------------------------
#define K3_ROWS 8
__global__ __launch_bounds__(256)
void k3_upkv(const float* __restrict__ ckv_ln,
             const float* __restrict__ w_ukv,
             const float* __restrict__ kr_rope,
             short* __restrict__ k_states,
             short* __restrict__ v_states)
{
    __shared__ float cs[K3_ROWS][CKV_];
    const int tid = threadIdx.x;
    const int r0  = blockIdx.x * K3_ROWS;
    const int NCOL = NKV * (KN_ + VD_);   // 1280

    for (int i = tid; i < K3_ROWS * CKV_; i += 256)
        cs[i >> 7][i & 127] = ckv_ln[(size_t)r0 * CKV_ + i];
    __syncthreads();

    float acc[K3_ROWS][5];
    #pragma unroll
    for (int rr = 0; rr < K3_ROWS; ++rr)
        #pragma unroll
        for (int cc = 0; cc < 5; ++cc) acc[rr][cc] = 0.f;

    for (int k = 0; k < CKV_; ++k) {
        float a[K3_ROWS];
        #pragma unroll
        for (int rr = 0; rr < K3_ROWS; ++rr) a[rr] = cs[rr][k];
        const float* wrow = w_ukv + (size_t)k * NCOL + tid;
        #pragma unroll
        for (int cc = 0; cc < 5; ++cc) {
            float b = wrow[cc * 256];
            #pragma unroll
            for (int rr = 0; rr < K3_ROWS; ++rr) acc[rr][cc] += a[rr] * b;
        }
    }

    #pragma unroll
    for (int cc = 0; cc < 5; ++cc) {
        int j = cc * 256 + tid;
        if (j < NKV * KN_) {
            int kvh = j >> 6, d = j & 63;
            for (int rr = 0; rr < K3_ROWS; ++rr) {
                int r = r0 + rr, b = r >> 11, spos = r & (S_LEN - 1);
                k_states[(((size_t)b * NKV + kvh) * S_LEN + spos) * 128 + d] =
                    f2bf(acc[rr][cc]);
            }
        } else {
            int jj = j - NKV * KN_;
            int kvh = jj >> 8, d = jj & 255;
            for (int rr = 0; rr < K3_ROWS; ++rr) {
                int r = r0 + rr, b = r >> 11, spos = r & (S_LEN - 1);
                v_states[(((size_t)b * NKV + kvh) * S_LEN + spos) * VD_ + d] =
                    f2bf(acc[rr][cc]);
            }
        }
    }

    for (int i = tid; i < K3_ROWS * KR_; i += 256) {
        int rr = i >> 6, d = i & 63;
        int r = r0 + rr, b = r >> 11, spos = r & (S_LEN - 1);
        short v = f2bf(kr_rope[(size_t)r * KR_ + d]);
        #pragma unroll
        for (int kvh = 0; kvh < NKV; ++kvh)
            k_states[(((size_t)b * NKV + kvh) * S_LEN + spos) * 128 + KN_ + d] = v;
    }
}

// ---------------------------------------------------------------------------
// K3T: v_states (B,KV,S,VD) bf16 -> vt (B,KV,VD,S) bf16.  64x64 tiles.
// LDS pad 66 shorts (132B rows): column reads conflict-free-ish (2-way).
// ---------------------------------------------------------------------------
__global__ __launch_bounds__(256)
void k3t_transpose_v(const short* __restrict__ v, short* __restrict__ vt)
{
    __shared__ short t[64][66];
    const int tid = threadIdx.x;
    const int vtile = blockIdx.x & 3;
    const int stile = (blockIdx.x >> 2) & 31;
    const int bk    = blockIdx.x >> 7;       // b*NKV+kv, 0..7

    const short* src = v + ((size_t)bk * S_LEN + stile * 64) * VD_ + vtile * 64;
    #pragma unroll
    for (int u2 = 0; u2 < 2; ++u2) {
        int u = u2 * 256 + tid;
        int srow = u >> 3, vc8 = (u & 7) * 8;
        short8 val = *reinterpret_cast<const short8*>(src + (size_t)srow * VD_ + vc8);
        #pragma unroll
        for (int j = 0; j < 8; ++j) t[srow][vc8 + j] = val[j];
    }
    __syncthreads();
    short* dst = vt + ((size_t)bk * VD_ + vtile * 64) * S_LEN + stile * 64;
    #pragma unroll
    for (int u2 = 0; u2 < 2; ++u2) {
        int u = u2 * 256 + tid;
        int vr = u >> 3, sc8 = (u & 7) * 8;
        short8 o;
        #pragma unroll
        for (int j = 0; j < 8; ++j) o[j] = t[sc8 + j][vr];
        *reinterpret_cast<short8*>(dst + (size_t)vr * S_LEN + sc8) = o;
    }
}

// ---------------------------------------------------------------------------
// K4: bf16 MFMA causal flash attention.
//   grid: B*NH*32 blocks, 256 threads (4 waves). Q-tile 64 rows; wave w owns
//   rows w*16..w*16+15. KV tiles of 64. mfma_f32_16x16x32_bf16.
//   K tile + V^T tile in XOR-swizzled LDS; P transposed via per-wave LDS strip.
// ---------------------------------------------------------------------------
__global__ __launch_bounds__(256)
void k4_attn_mfma(const short* __restrict__ q_states,
                  const short* __restrict__ k_states,
                  const short* __restrict__ vt,
                  short* __restrict__ attn_out)
{
    __shared__ __align__(16) short ks_lds[64 * 128];    // 16 KB
    __shared__ __align__(16) short vt_lds[256 * 64];    // 32 KB
    __shared__ __align__(16) short ps_lds[4 * 16 * 64]; //  8 KB (per-wave strips)

    const int tid  = threadIdx.x;
    const int lane = tid & 63;
    const int w    = tid >> 6;
    const int g    = lane >> 4;     // 0..3
    const int l15  = lane & 15;
    const int qt  = blockIdx.x & 31;
    const int h   = (blockIdx.x >> 5) & 15;
    const int b   = blockIdx.x >> 9;
    const int kvh = h >> 2;

    const short* qbase  = q_states + (((size_t)b * NH  + h)   * S_LEN + qt * 64) * 128;
    const short* kbase  = k_states + (((size_t)b * NKV + kvh) * S_LEN) * 128;
    const short* vtbase = vt       + (((size_t)b * NKV + kvh) * VD_) * S_LEN;

    // Q fragments (scale already folded in): rows w*16+l15, k = g*8 + kb*32 + i
    short8 qfrag[4];
    {
        const short* qrow = qbase + (size_t)(w * 16 + l15) * 128 + g * 8;
        #pragma unroll
        for (int kb = 0; kb < 4; ++kb)
            qfrag[kb] = *reinterpret_cast<const short8*>(qrow + kb * 32);
    }

    float4v o[16];
    #pragma unroll
    for (int cb = 0; cb < 16; ++cb) o[cb] = (float4v){0.f, 0.f, 0.f, 0.f};
    float m[4] = {-1e30f, -1e30f, -1e30f, -1e30f};
    float l[4] = {0.f, 0.f, 0.f, 0.f};

    const int nkt = qt + 1;
    for (int kt = 0; kt < nkt; ++kt) {
        __syncthreads();
        // ---- stage K tile (64 x 128 bf16) swizzled ----
        {
            const short* src = kbase + (size_t)kt * 64 * 128;
            #pragma unroll
            for (int u4 = 0; u4 < 4; ++u4) {
                int u = u4 * 256 + tid;
                int row = u >> 4, c16 = (u & 15) * 16;
                short8 val = *reinterpret_cast<const short8*>(src + row * 128 + (u & 15) * 8);
                *reinterpret_cast<short8*>((char*)ks_lds + row * 256 + (c16 ^ ((row & 7) << 4))) = val;
            }
            // ---- stage V^T tile (256 x 64 bf16) swizzled ----
            const short* vsrc = vtbase + kt * 64;
            #pragma unroll
            for (int u8 = 0; u8 < 8; ++u8) {
                int u = u8 * 256 + tid;
                int row = u >> 3, c16 = (u & 7) * 16;
                short8 val = *reinterpret_cast<const short8*>(vsrc + (size_t)row * S_LEN + (u & 7) * 8);
                *reinterpret_cast<short8*>((char*)vt_lds + row * 128 + (c16 ^ ((row & 7) << 4))) = val;
            }
        }
        __syncthreads();

        // ---- S = Q K^T (16x16 frags: rows w*16.., cols nj*16..) ----
        float4v s[4];
        #pragma unroll
        for (int nj = 0; nj < 4; ++nj) s[nj] = (float4v){0.f, 0.f, 0.f, 0.f};
        #pragma unroll
        for (int kb = 0; kb < 4; ++kb) {
            #pragma unroll
            for (int nj = 0; nj < 4; ++nj) {
                int row = nj * 16 + l15;
                short8 kf = *reinterpret_cast<const short8*>(
                    (const char*)ks_lds + row * 256 + (((g * 16) + kb * 64) ^ ((row & 7) << 4)));
                s[nj] = __builtin_amdgcn_mfma_f32_16x16x32_bf16(qfrag[kb], kf, s[nj], 0, 0, 0);
            }
        }

        // ---- causal mask on diagonal tile ----
        if (kt == qt) {
            #pragma unroll
            for (int nj = 0; nj < 4; ++nj)
                #pragma unroll
                for (int r = 0; r < 4; ++r) {
                    int qrow = w * 16 + g * 4 + r;
                    int kcol = nj * 16 + l15;
                    if (kcol > qrow) s[nj][r] = -1e30f;
                }
        }

        // ---- online softmax (row-reduce across 16-lane group) ----
        #pragma unroll
        for (int r = 0; r < 4; ++r) {
            float mx = fmaxf(fmaxf(s[0][r], s[1][r]), fmaxf(s[2][r], s[3][r]));
            mx = fmaxf(mx, __shfl_xor(mx, 1, 64));
            mx = fmaxf(mx, __shfl_xor(mx, 2, 64));
            mx = fmaxf(mx, __shfl_xor(mx, 4, 64));
            mx = fmaxf(mx, __shfl_xor(mx, 8, 64));
            float mnew = fmaxf(m[r], mx);
            float corr = __expf(m[r] - mnew);
            m[r] = mnew;
            float psum = 0.f;
            #pragma unroll
            for (int nj = 0; nj < 4; ++nj) {
                float p = __expf(s[nj][r] - mnew);
                s[nj][r] = p;
                psum += p;
            }
            psum += __shfl_xor(psum, 1, 64);
            psum += __shfl_xor(psum, 2, 64);
            psum += __shfl_xor(psum, 4, 64);
            psum += __shfl_xor(psum, 8, 64);
            l[r] = l[r] * corr + psum;
            #pragma unroll
            for (int cb = 0; cb < 16; ++cb) o[cb][r] *= corr;
        }

        // ---- P -> per-wave LDS strip (bf16, swizzled); same-wave DS is in-order ----
        {
            char* base = (char*)(ps_lds + w * 1024);
            #pragma unroll
            for (int nj = 0; nj < 4; ++nj)
                #pragma unroll
                for (int r = 0; r < 4; ++r) {
                    int prow = g * 4 + r, pcol = nj * 16 + l15;
                    *reinterpret_cast<short*>(base + prow * 128 + ((pcol * 2) ^ ((prow & 7) << 4))) =
                        f2bf(s[nj][r]);
                }
        }

        // ---- O += P @ V (A from own strip, B from vt_lds) ----
        const char* pbase = (const char*)(ps_lds + w * 1024);
        #pragma unroll
        for (int kb = 0; kb < 2; ++kb) {
            int prow = l15;
            short8 pa = *reinterpret_cast<const short8*>(
                pbase + prow * 128 + (((g * 16) + kb * 64) ^ ((prow & 7) << 4)));
            #pragma unroll
            for (int cb = 0; cb < 16; ++cb) {
                int vrow = cb * 16 + l15;
                short8 vb = *reinterpret_cast<const short8*>(
                    (const char*)vt_lds + vrow * 128 + (((g * 16) + kb * 64) ^ ((vrow & 7) << 4)));
                o[cb] = __builtin_amdgcn_mfma_f32_16x16x32_bf16(pa, vb, o[cb], 0, 0, 0);
            }
        }
    }

    // ---- epilogue: normalize, write attn_out bf16 (B,S,H,VD) ----
    float invl[4];
    #pragma unroll
    for (int r = 0; r < 4; ++r) invl[r] = 1.f / l[r];
    #pragma unroll
    for (int cb = 0; cb < 16; ++cb)
        #pragma unroll
        for (int r = 0; r < 4; ++r) {
            int spos = qt * 64 + w * 16 + g * 4 + r;
            attn_out[(((size_t)b * S_LEN + spos) * NH + h) * VD_ + cb * 16 + l15] =
                f2bf(o[cb][r] * invl[r]);
        }
}

// ---------------------------------------------------------------------------
// K5: out = attn_out (4096x4096 bf16) @ w_o  via w_oT (2048x4096 bf16), f32 out.
//   128x128 tile, BK=64, 4 waves (2x2), each wave 64x64 (4x4 MFMA frags).
// ---------------------------------------------------------------------------
__global__ __launch_bounds__(256)
void k5_gemm_mfma(const short* __restrict__ A,    // attn_out
                  const short* __restrict__ Bt,   // w_oT
                  float* __restrict__ C)
{
    __shared__ __align__(16) short at[128 * 64];  // 16 KB swizzled
    __shared__ __align__(16) short bt[128 * 64];  // 16 KB swizzled
    const int tid  = threadIdx.x;
    const int lane = tid & 63;
    const int wid  = tid >> 6;
    const int wm = wid >> 1, wn = wid & 1;
    const int g = lane >> 4, l15 = lane & 15;
    const int bn = blockIdx.x & 15, bm = blockIdx.x >> 4;
    const int m0 = bm * 128, n0 = bn * 128;

    float4v acc[4][4];
    #pragma unroll
    for (int mi = 0; mi < 4; ++mi)
        #pragma unroll
        for (int nj = 0; nj < 4; ++nj) acc[mi][nj] = (float4v){0.f, 0.f, 0.f, 0.f};

    for (int k0 = 0; k0 < 4096; k0 += 64) {
        __syncthreads();
        #pragma unroll
        for (int u4 = 0; u4 < 4; ++u4) {      // A tile: 128 rows x 128B
            int u = u4 * 256 + tid;
            int row = u >> 3, c16 = (u & 7) * 16;
            short8 va = *reinterpret_cast<const short8*>(A + (size_t)(m0 + row) * 4096 + k0 + (u & 7) * 8);
            *reinterpret_cast<short8*>((char*)at + row * 128 + (c16 ^ ((row & 7) << 4))) = va;
            short8 vb = *reinterpret_cast<const short8*>(Bt + (size_t)(n0 + row) * 4096 + k0 + (u & 7) * 8);
            *reinterpret_cast<short8*>((char*)bt + row * 128 + (c16 ^ ((row & 7) << 4))) = vb;
        }
        __syncthreads();

        #pragma unroll
        for (int kb = 0; kb < 2; ++kb) {
            short8 af[4], bfr[4];
            #pragma unroll
            for (int mi = 0; mi < 4; ++mi) {
                int row = wm * 64 + mi * 16 + l15;
                af[mi] = *reinterpret_cast<const short8*>(
                    (const char*)at + row * 128 + (((g * 16) + kb * 64) ^ ((row & 7) << 4)));
            }
            #pragma unroll
            for (int nj = 0; nj < 4; ++nj) {
                int row = wn * 64 + nj * 16 + l15;
                bfr[nj] = *reinterpret_cast<const short8*>(
                    (const char*)bt + row * 128 + (((g * 16) + kb * 64) ^ ((row & 7) << 4)));
            }
            #pragma unroll
            for (int mi = 0; mi < 4; ++mi)
                #pragma unroll
                for (int nj = 0; nj < 4; ++nj)
                    acc[mi][nj] = __builtin_amdgcn_mfma_f32_16x16x32_bf16(af[mi], bfr[nj], acc[mi][nj], 0, 0, 0);
        }
    }

    #pragma unroll
    for (int mi = 0; mi < 4; ++mi)
        #pragma unroll
        for (int nj = 0; nj < 4; ++nj)
            #pragma unroll
            for (int r = 0; r < 4; ++r)
                C[(size_t)(m0 + wm * 64 + mi * 16 + g * 4 + r) * DIM + n0 + wn * 64 + nj * 16 + l15] =
                    acc[mi][nj][r];
}

// ---------------------------------------------------------------------------
extern "C" void kernel_launch(void* const* d_in, const int* in_sizes, int n_in,
                              void* d_out, int out_size, void* d_ws, size_t ws_size,
                              hipStream_t stream)
{
    const float* x        = (const float*)d_in[0];
    const float* w_dq     = (const float*)d_in[1];
    const float* gamma_q  = (const float*)d_in[2];
    const float* w_uq     = (const float*)d_in[3];
    const float* w_dkv    = (const float*)d_in[4];
    const float* gamma_kv = (const float*)d_in[5];
    const float* w_ukv    = (const float*)d_in[6];
    const float* w_o      = (const float*)d_in[7];
    float* out = (float*)d_out;

    char* ws = (char*)d_ws;
    float* cq_ln    = (float*)(ws);                       // 524288 f32  (2 MB)
    float* ckv_ln   = (float*)(ws + (2u << 20));          // 524288 f32  (2 MB)
    float* kr_rope  = (float*)(ws + (4u << 20));          // 262144 f32  (1 MB)
    short* q_states = (short*)(ws + (5u << 20));          // 8388608 bf16 (16 MB)
    short* k_states = (short*)(ws + (21u << 20));         // 2097152 bf16 (4 MB)
    short* v_states = (short*)(ws + (25u << 20));         // 4194304 bf16 (8 MB)
    short* vt       = (short*)(ws + (33u << 20));         // 4194304 bf16 (8 MB)
    short* attn_out = (short*)(ws + (41u << 20));         // 16777216 bf16 (32 MB)
    short* w_oT     = (short*)(ws + (73u << 20));         // 8388608 bf16 (16 MB)
    // total 89 MB

    k0t_transpose_wo<<<dim3(2048), dim3(256), 0, stream>>>(w_o, w_oT);

    k1_down_ln_rope<<<dim3(ROWS_TOT / K1_ROWS), dim3(320), 0, stream>>>(
        x, w_dq, gamma_q, w_dkv, gamma_kv, cq_ln, ckv_ln, kr_rope);

    k2_upq_rope<<<dim3(ROWS_TOT / K2_ROWS), dim3(256), 0, stream>>>(
        cq_ln, w_uq, q_states);

    k3_upkv<<<dim3(ROWS_TOT / K3_ROWS), dim3(256), 0, stream>>>(
        ckv_ln, w_ukv, kr_rope, k_states, v_states);

    k3t_transpose_v<<<dim3(BATCH * NKV * 32 * 4), dim3(256), 0, stream>>>(
        v_states, vt);

    k4_attn_mfma<<<dim3(BATCH * NH * 32), dim3(256), 0, stream>>>(
        q_states, k_states, vt, attn_out);

    k5_gemm_mfma<<<dim3((ROWS_TOT / 128) * (DIM / 128)), dim3(256), 0, stream>>>(
        attn_out, w_oT, out);
}

// Round 3
// 562.587 us; speedup vs baseline: 6.2655x; 1.1648x over previous
//
#include <hip/hip_runtime.h>
#include <hip/hip_bf16.h>
#include <math.h>

#define DIM   2048
#define S_LEN 2048
#define BATCH 2
#define NH    16
#define NKV   4
#define CQ_   128
#define QN_   96
#define QR_   32
#define CKV_  128
#define KN_   64
#define KR_   64
#define VD_   256
#define ROWS_TOT (BATCH*S_LEN)   // 4096

typedef __attribute__((ext_vector_type(8))) short short8;
typedef __attribute__((ext_vector_type(4))) float float4v;

__device__ inline short f2bf(float x) {
    union { __hip_bfloat16 h; short s; } u;
    u.h = __float2bfloat16(x);
    return u.s;
}

// async global->LDS, 16B per lane. LDS dest must be wave-uniform base (HW
// writes base + lane*16, linear). Swizzled layouts => pre-swizzle the GLOBAL
// source address per-lane and keep LDS linear (m173 pattern).
__device__ __forceinline__ void gl_lds16(const short* g, short* lds) {
    __builtin_amdgcn_global_load_lds(
        (const __attribute__((address_space(1))) unsigned int*)(g),
        (__attribute__((address_space(3))) unsigned int*)(lds),
        16, 0, 0);
}

// ---------------------------------------------------------------------------
// KC: x (4096x2048 f32) -> xbf bf16
// ---------------------------------------------------------------------------
__global__ __launch_bounds__(256)
void kcast_x(const float* __restrict__ x, short* __restrict__ xbf)
{
    int i = (blockIdx.x * 256 + threadIdx.x) * 8;
    float4 a = *reinterpret_cast<const float4*>(x + i);
    float4 b = *reinterpret_cast<const float4*>(x + i + 4);
    short8 o;
    o[0] = f2bf(a.x); o[1] = f2bf(a.y); o[2] = f2bf(a.z); o[3] = f2bf(a.w);
    o[4] = f2bf(b.x); o[5] = f2bf(b.y); o[6] = f2bf(b.z); o[7] = f2bf(b.w);
    *reinterpret_cast<short8*>(xbf + i) = o;
}

// ---------------------------------------------------------------------------
// KW: wdT (320 x 2048) bf16 = [w_dq | w_dkv]^T.  64x64 f32 tiles via LDS.
// ---------------------------------------------------------------------------
__global__ __launch_bounds__(256)
void kprep_wd(const float* __restrict__ w_dq, const float* __restrict__ w_dkv,
              short* __restrict__ wdT)
{
    __shared__ float tf[64][65];
    const int tid = threadIdx.x;
    const int nt = blockIdx.x % 5, kt = blockIdx.x / 5;
    const int k0 = kt * 64, n0 = nt * 64;
    const float* src; int stride, nbase;
    if (nt < 2) { src = w_dq;  stride = 128; nbase = n0; }
    else        { src = w_dkv; stride = 192; nbase = n0 - 128; }

    #pragma unroll
    for (int u4 = 0; u4 < 4; ++u4) {
        int u = u4 * 256 + tid;
        int kr = u >> 4, nc = (u & 15) * 4;
        float4 v = *reinterpret_cast<const float4*>(&src[(size_t)(k0 + kr) * stride + nbase + nc]);
        tf[kr][nc + 0] = v.x; tf[kr][nc + 1] = v.y;
        tf[kr][nc + 2] = v.z; tf[kr][nc + 3] = v.w;
    }
    __syncthreads();
    #pragma unroll
    for (int u2 = 0; u2 < 2; ++u2) {
        int u = u2 * 256 + tid;
        int nr = u >> 3, kc8 = (u & 7) * 8;
        short8 o;
        #pragma unroll
        for (int j = 0; j < 8; ++j) o[j] = f2bf(tf[kc8 + j][nr]);
        *reinterpret_cast<short8*>(&wdT[(size_t)(n0 + nr) * 2048 + k0 + kc8]) = o;
    }
}

// ---------------------------------------------------------------------------
// K0T: w_o (4096 x 2048) f32 -> w_oT (2048 x 4096) bf16
// ---------------------------------------------------------------------------
__global__ __launch_bounds__(256)
void k0t_transpose_wo(const float* __restrict__ w_o, short* __restrict__ w_oT)
{
    __shared__ float tf[64][65];
    const int tid = threadIdx.x;
    const int nt = blockIdx.x & 31, kt = blockIdx.x >> 5;
    const int k0 = kt * 64, n0 = nt * 64;

    #pragma unroll
    for (int u4 = 0; u4 < 4; ++u4) {
        int u = u4 * 256 + tid;
        int kr = u >> 4, nc4 = (u & 15) * 4;
        float4 v = *reinterpret_cast<const float4*>(&w_o[(size_t)(k0 + kr) * DIM + n0 + nc4]);
        tf[kr][nc4 + 0] = v.x; tf[kr][nc4 + 1] = v.y;
        tf[kr][nc4 + 2] = v.z; tf[kr][nc4 + 3] = v.w;
    }
    __syncthreads();
    #pragma unroll
    for (int u2 = 0; u2 < 2; ++u2) {
        int u = u2 * 256 + tid;
        int nr = u >> 3, kc8 = (u & 7) * 8;
        short8 o;
        #pragma unroll
        for (int j = 0; j < 8; ++j) o[j] = f2bf(tf[kc8 + j][nr]);
        *reinterpret_cast<short8*>(&w_oT[(size_t)(n0 + nr) * 4096 + k0 + kc8]) = o;
    }
}

// ---------------------------------------------------------------------------
// K1: MFMA GEMM (M-tile 16, N=320, K=2048) + fused LN + K-RoPE.
//   A-frags & B-frags straight from global (W is L2-resident, no intra-block
//   reuse of B -> LDS staging would add nothing). Epilogue via LDS.
// ---------------------------------------------------------------------------
__global__ __launch_bounds__(256)
void k1_mfma(const short* __restrict__ xbf, const short* __restrict__ wdT,
             const float* __restrict__ gamma_q, const float* __restrict__ gamma_kv,
             float* __restrict__ cq_ln, float* __restrict__ ckv_ln,
             float* __restrict__ kr_rope)
{
    __shared__ float ys[16][321];
    __shared__ float st[16][4];
    const int tid = threadIdx.x, lane = tid & 63, w = tid >> 6;
    const int g = lane >> 4, l15 = lane & 15;
    const int m0 = blockIdx.x * 16;
    const int wn0 = w * 80;

    float4v acc[5];
    #pragma unroll
    for (int nj = 0; nj < 5; ++nj) acc[nj] = (float4v){0.f, 0.f, 0.f, 0.f};

    const short* arow = xbf + (size_t)(m0 + l15) * 2048 + g * 8;
    for (int ks = 0; ks < 64; ++ks) {
        short8 a = *reinterpret_cast<const short8*>(arow + ks * 32);
        #pragma unroll
        for (int nj = 0; nj < 5; ++nj) {
            short8 bf = *reinterpret_cast<const short8*>(
                wdT + (size_t)(wn0 + nj * 16 + l15) * 2048 + ks * 32 + g * 8);
            acc[nj] = __builtin_amdgcn_mfma_f32_16x16x32_bf16(a, bf, acc[nj], 0, 0, 0);
        }
    }

    #pragma unroll
    for (int nj = 0; nj < 5; ++nj)
        #pragma unroll
        for (int r = 0; r < 4; ++r)
            ys[g * 4 + r][wn0 + nj * 16 + l15] = acc[nj][r];
    __syncthreads();

    if (tid < 32) {
        int row = tid >> 1, seg = tid & 1, base = seg * 128;
        float s1 = 0.f, s2 = 0.f;
        for (int j = 0; j < 128; ++j) { float v = ys[row][base + j]; s1 += v; s2 += v * v; }
        float mu  = s1 * (1.f / 128.f);
        float var = s2 * (1.f / 128.f) - mu * mu;
        st[row][seg * 2 + 0] = mu;
        st[row][seg * 2 + 1] = rsqrtf(var + 1e-5f);
    }
    __syncthreads();

    for (int i = tid; i < 16 * 320; i += 256) {
        int row = i / 320, col = i - row * 320;
        int r = m0 + row, spos = r & (S_LEN - 1);
        float v = ys[row][col];
        if (col < 128) {
            cq_ln[(size_t)r * CQ_ + col] = (v - st[row][0]) * st[row][1] * gamma_q[col];
        } else if (col < 256) {
            ckv_ln[(size_t)r * CKV_ + (col - 128)] =
                (v - st[row][2]) * st[row][3] * gamma_kv[col - 128];
        } else {
            int d = col - 256, i2 = d >> 1;
            float xe = ys[row][256 + (d & ~1)];
            float xo = ys[row][256 + (d | 1)];
            float inv = powf(10000.f, -((float)(2 * i2)) / 64.f);
            float ang = (float)spos * inv;
            float sn, c; sincosf(ang, &sn, &c);
            kr_rope[(size_t)r * KR_ + d] = (d & 1) ? (xe * sn + xo * c)
                                                   : (xe * c - xo * sn);
        }
    }
}

// ---------------------------------------------------------------------------
// K2: q = cq_ln @ w_uq, RoPE, scale folded -> q_states bf16 (B,H,S,128)
// ---------------------------------------------------------------------------
#define K2_ROWS 8
#define QK_SCALE 0.08838834764831845f
__global__ __launch_bounds__(256)
void k2_upq_rope(const float* __restrict__ cq_ln,
                 const float* __restrict__ w_uq,
                 short* __restrict__ q_states)
{
    __shared__ float cs[K2_ROWS][CQ_];
    __shared__ float qraw[K2_ROWS][NH * QR_];
    const int tid = threadIdx.x;
    const int r0  = blockIdx.x * K2_ROWS;

    for (int i = tid; i < K2_ROWS * CQ_; i += 256)
        cs[i >> 7][i & 127] = cq_ln[(size_t)r0 * CQ_ + i];
    __syncthreads();

    float acc[K2_ROWS][8];
    #pragma unroll
    for (int rr = 0; rr < K2_ROWS; ++rr)
        #pragma unroll
        for (int cc = 0; cc < 8; ++cc) acc[rr][cc] = 0.f;

    for (int k = 0; k < CQ_; ++k) {
        float a[K2_ROWS];
        #pragma unroll
        for (int rr = 0; rr < K2_ROWS; ++rr) a[rr] = cs[rr][k];
        const float* wrow = w_uq + (size_t)k * (NH * (QN_ + QR_)) + tid;
        #pragma unroll
        for (int cc = 0; cc < 8; ++cc) {
            float b = wrow[cc * 256];
            #pragma unroll
            for (int rr = 0; rr < K2_ROWS; ++rr) acc[rr][cc] += a[rr] * b;
        }
    }

    #pragma unroll
    for (int cc = 0; cc < 8; ++cc) {
        int j = cc * 256 + tid;
        if (j < NH * QN_) {
            int h = j / QN_, d = j % QN_;
            for (int rr = 0; rr < K2_ROWS; ++rr) {
                int r = r0 + rr, b = r >> 11, spos = r & (S_LEN - 1);
                q_states[(((size_t)b * NH + h) * S_LEN + spos) * 128 + d] =
                    f2bf(acc[rr][cc] * QK_SCALE);
            }
        } else {
            int jj = j - NH * QN_;
            for (int rr = 0; rr < K2_ROWS; ++rr) qraw[rr][jj] = acc[rr][cc];
        }
    }
    __syncthreads();

    for (int i = tid; i < K2_ROWS * NH * QR_; i += 256) {
        int rr = i >> 9, jj = i & 511;
        int h = jj >> 5, d = jj & 31;
        int r = r0 + rr, b = r >> 11, spos = r & (S_LEN - 1);
        int i2 = d >> 1;
        float xe = qraw[rr][(h << 5) + (d & ~1)];
        float xo = qraw[rr][(h << 5) + (d | 1)];
        float inv = powf(10000.f, -((float)(2 * i2)) / 32.f);
        float ang = (float)spos * inv;
        float sn, c; sincosf(ang, &sn, &c);
        float v = (d & 1) ? (xe * sn + xo * c) : (xe * c - xo * sn);
        q_states[(((size_t)b * NH + h) * S_LEN + spos) * 128 + QN_ + d] =
            f2bf(v * QK_SCALE);
    }
}

// ---------------------------------------------------------------------------
// K3: kv = ckv_ln @ w_ukv -> k_states bf16 (B,KV,S,128), v_states bf16 (B,KV,S,256)
// ---------------------------------------------------------------------------
#define K3_ROWS 8
__global__ __launch_bounds__(256)
void k3_upkv(const float* __restrict__ ckv_ln,
             const float* __restrict__ w_ukv,
             const float* __restrict__ kr_rope,
             short* __restrict__ k_states,
             short* __restrict__ v_states)
{
    __shared__ float cs[K3_ROWS][CKV_];
    const int tid = threadIdx.x;
    const int r0  = blockIdx.x * K3_ROWS;
    const int NCOL = NKV * (KN_ + VD_);   // 1280

    for (int i = tid; i < K3_ROWS * CKV_; i += 256)
        cs[i >> 7][i & 127] = ckv_ln[(size_t)r0 * CKV_ + i];
    __syncthreads();

    float acc[K3_ROWS][5];
    #pragma unroll
    for (int rr = 0; rr < K3_ROWS; ++rr)
        #pragma unroll
        for (int cc = 0; cc < 5; ++cc) acc[rr][cc] = 0.f;

    for (int k = 0; k < CKV_; ++k) {
        float a[K3_ROWS];
        #pragma unroll
        for (int rr = 0; rr < K3_ROWS; ++rr) a[rr] = cs[rr][k];
        const float* wrow = w_ukv + (size_t)k * NCOL + tid;
        #pragma unroll
        for (int cc = 0; cc < 5; ++cc) {
            float b = wrow[cc * 256];
            #pragma unroll
            for (int rr = 0; rr < K3_ROWS; ++rr) acc[rr][cc] += a[rr] * b;
        }
    }

    #pragma unroll
    for (int cc = 0; cc < 5; ++cc) {
        int j = cc * 256 + tid;
        if (j < NKV * KN_) {
            int kvh = j >> 6, d = j & 63;
            for (int rr = 0; rr < K3_ROWS; ++rr) {
                int r = r0 + rr, b = r >> 11, spos = r & (S_LEN - 1);
                k_states[(((size_t)b * NKV + kvh) * S_LEN + spos) * 128 + d] =
                    f2bf(acc[rr][cc]);
            }
        } else {
            int jj = j - NKV * KN_;
            int kvh = jj >> 8, d = jj & 255;
            for (int rr = 0; rr < K3_ROWS; ++rr) {
                int r = r0 + rr, b = r >> 11, spos = r & (S_LEN - 1);
                v_states[(((size_t)b * NKV + kvh) * S_LEN + spos) * VD_ + d] =
                    f2bf(acc[rr][cc]);
            }
        }
    }

    for (int i = tid; i < K3_ROWS * KR_; i += 256) {
        int rr = i >> 6, d = i & 63;
        int r = r0 + rr, b = r >> 11, spos = r & (S_LEN - 1);
        short v = f2bf(kr_rope[(size_t)r * KR_ + d]);
        #pragma unroll
        for (int kvh = 0; kvh < NKV; ++kvh)
            k_states[(((size_t)b * NKV + kvh) * S_LEN + spos) * 128 + KN_ + d] = v;
    }
}

// ---------------------------------------------------------------------------
// K3T: v_states (B,KV,S,VD) bf16 -> vt (B,KV,VD,S) bf16
// ---------------------------------------------------------------------------
__global__ __launch_bounds__(256)
void k3t_transpose_v(const short* __restrict__ v, short* __restrict__ vt)
{
    __shared__ short t[64][66];
    const int tid = threadIdx.x;
    const int vtile = blockIdx.x & 3;
    const int stile = (blockIdx.x >> 2) & 31;
    const int bk    = blockIdx.x >> 7;

    const short* src = v + ((size_t)bk * S_LEN + stile * 64) * VD_ + vtile * 64;
    #pragma unroll
    for (int u2 = 0; u2 < 2; ++u2) {
        int u = u2 * 256 + tid;
        int srow = u >> 3, vc8 = (u & 7) * 8;
        short8 val = *reinterpret_cast<const short8*>(src + (size_t)srow * VD_ + vc8);
        #pragma unroll
        for (int j = 0; j < 8; ++j) t[srow][vc8 + j] = val[j];
    }
    __syncthreads();
    short* dst = vt + ((size_t)bk * VD_ + vtile * 64) * S_LEN + stile * 64;
    #pragma unroll
    for (int u2 = 0; u2 < 2; ++u2) {
        int u = u2 * 256 + tid;
        int vr = u >> 3, sc8 = (u & 7) * 8;
        short8 o;
        #pragma unroll
        for (int j = 0; j < 8; ++j) o[j] = t[sc8 + j][vr];
        *reinterpret_cast<short8*>(dst + (size_t)vr * S_LEN + sc8) = o;
    }
}

// ---------------------------------------------------------------------------
// K4: bf16 MFMA causal flash attention, Q-tile 128 rows.
//   grid: 512 blocks (qt descending so longest run first), 256 thr (4 waves).
//   Wave w owns q-rows [w*32, w*32+32) of the tile (2 row-frags).
//   KV tiles of 64; K & V^T staged via global_load_lds w/ pre-swizzled source.
// ---------------------------------------------------------------------------
__global__ __launch_bounds__(256, 2)
void k4_attn_mfma(const short* __restrict__ q_states,
                  const short* __restrict__ k_states,
                  const short* __restrict__ vt,
                  short* __restrict__ attn_out)
{
    __shared__ __align__(16) short ks_lds[64 * 128];    // 16 KB (rows 256B, 16 chunks)
    __shared__ __align__(16) short vt_lds[256 * 64];    // 32 KB (rows 128B, 8 chunks)
    __shared__ __align__(16) short ps_lds[4 * 32 * 64]; // 16 KB per-wave P strips

    const int tid  = threadIdx.x;
    const int lane = tid & 63;
    const int w    = tid >> 6;
    const int g    = lane >> 4;
    const int l15  = lane & 15;
    const int qtrev = blockIdx.x >> 5;          // 0..15
    const int qt    = 15 - qtrev;               // longest first
    const int bh    = blockIdx.x & 31;
    const int h     = bh & 15;
    const int b     = bh >> 4;
    const int kvh   = h >> 2;

    const short* qbase  = q_states + (((size_t)b * NH  + h)   * S_LEN + qt * 128) * 128;
    const short* kbase  = k_states + (((size_t)b * NKV + kvh) * S_LEN) * 128;
    const short* vtbase = vt       + (((size_t)b * NKV + kvh) * VD_) * S_LEN;

    // Q fragments: rows w*32 + mi*16 + l15, k = kb*32 + g*8
    short8 qfrag[2][4];
    #pragma unroll
    for (int mi = 0; mi < 2; ++mi) {
        const short* qrow = qbase + (size_t)(w * 32 + mi * 16 + l15) * 128 + g * 8;
        #pragma unroll
        for (int kb = 0; kb < 4; ++kb)
            qfrag[mi][kb] = *reinterpret_cast<const short8*>(qrow + kb * 32);
    }

    float4v o[2][16];
    #pragma unroll
    for (int mi = 0; mi < 2; ++mi)
        #pragma unroll
        for (int cb = 0; cb < 16; ++cb) o[mi][cb] = (float4v){0.f, 0.f, 0.f, 0.f};
    float m[2][4], l[2][4];
    #pragma unroll
    for (int mi = 0; mi < 2; ++mi)
        #pragma unroll
        for (int r = 0; r < 4; ++r) { m[mi][r] = -1e30f; l[mi][r] = 0.f; }

    const int qrow0 = qt * 128 + w * 32;        // this wave's first global q-row
    const int nkt = 2 * qt + 2;

    for (int kt = 0; kt < nkt; ++kt) {
        __syncthreads();   // previous tile's LDS fully consumed
        // ---- stage K tile 64x128 bf16 (4 insts/wave) ----
        {
            const short* ksrc = kbase + (size_t)kt * 64 * 128;
            #pragma unroll
            for (int i = 0; i < 4; ++i) {
                int row = w * 16 + i * 4 + (lane >> 4);
                int ch  = lane & 15;
                gl_lds16(ksrc + row * 128 + ((ch ^ (row & 7)) * 8),
                         ks_lds + w * 2048 + i * 512);
            }
            // ---- stage V^T tile 256x64 bf16 (8 insts/wave) ----
            const short* vsrc = vtbase + kt * 64;
            #pragma unroll
            for (int i = 0; i < 8; ++i) {
                int row = w * 64 + i * 8 + (lane >> 3);
                int ch  = lane & 7;
                gl_lds16(vsrc + (size_t)row * S_LEN + ((ch ^ (row & 7)) * 8),
                         vt_lds + w * 4096 + i * 512);
            }
        }
        __syncthreads();   // drains vmcnt (compiler emits waitcnt before barrier)

        const bool active = (kt * 64 <= qrow0 + 31);
        if (active) {
            // ---- S = Q K^T ----
            float4v s[2][4];
            #pragma unroll
            for (int mi = 0; mi < 2; ++mi)
                #pragma unroll
                for (int nj = 0; nj < 4; ++nj) s[mi][nj] = (float4v){0.f, 0.f, 0.f, 0.f};
            #pragma unroll
            for (int kb = 0; kb < 4; ++kb) {
                #pragma unroll
                for (int nj = 0; nj < 4; ++nj) {
                    int row = nj * 16 + l15;
                    short8 kf = *reinterpret_cast<const short8*>(
                        ks_lds + row * 128 + (((g + 4 * kb) ^ (row & 7)) * 8));
                    #pragma unroll
                    for (int mi = 0; mi < 2; ++mi)
                        s[mi][nj] = __builtin_amdgcn_mfma_f32_16x16x32_bf16(
                            qfrag[mi][kb], kf, s[mi][nj], 0, 0, 0);
                }
            }

            // ---- causal mask ----
            #pragma unroll
            for (int mi = 0; mi < 2; ++mi) {
                if (kt * 64 + 63 > qrow0 + mi * 16) {
                    #pragma unroll
                    for (int nj = 0; nj < 4; ++nj)
                        #pragma unroll
                        for (int r = 0; r < 4; ++r) {
                            int qrow = qrow0 + mi * 16 + g * 4 + r;
                            int kcol = kt * 64 + nj * 16 + l15;
                            if (kcol > qrow) s[mi][nj][r] = -1e30f;
                        }
                }
            }

            // ---- online softmax + P write + PV ----
            #pragma unroll
            for (int mi = 0; mi < 2; ++mi) {
                #pragma unroll
                for (int r = 0; r < 4; ++r) {
                    float mx = fmaxf(fmaxf(s[mi][0][r], s[mi][1][r]),
                                     fmaxf(s[mi][2][r], s[mi][3][r]));
                    mx = fmaxf(mx, __shfl_xor(mx, 1, 64));
                    mx = fmaxf(mx, __shfl_xor(mx, 2, 64));
                    mx = fmaxf(mx, __shfl_xor(mx, 4, 64));
                    mx = fmaxf(mx, __shfl_xor(mx, 8, 64));
                    float mnew = fmaxf(m[mi][r], mx);
                    float corr = __expf(m[mi][r] - mnew);
                    m[mi][r] = mnew;
                    float psum = 0.f;
                    #pragma unroll
                    for (int nj = 0; nj < 4; ++nj) {
                        float p = __expf(s[mi][nj][r] - mnew);
                        s[mi][nj][r] = p;
                        psum += p;
                    }
                    psum += __shfl_xor(psum, 1, 64);
                    psum += __shfl_xor(psum, 2, 64);
                    psum += __shfl_xor(psum, 4, 64);
                    psum += __shfl_xor(psum, 8, 64);
                    l[mi][r] = l[mi][r] * corr + psum;
                    #pragma unroll
                    for (int cb = 0; cb < 16; ++cb) o[mi][cb][r] *= corr;
                }
                // P strip write (same-wave DS ordering)
                char* base = (char*)(ps_lds + w * 2048);
                #pragma unroll
                for (int nj = 0; nj < 4; ++nj)
                    #pragma unroll
                    for (int r = 0; r < 4; ++r) {
                        int prow = mi * 16 + g * 4 + r, pcol = nj * 16 + l15;
                        *reinterpret_cast<short*>(
                            base + prow * 128 + ((pcol * 2) ^ ((prow & 7) << 4))) =
                            f2bf(s[mi][nj][r]);
                    }
            }

            // ---- O += P @ V ----
            const short* pbase = ps_lds + w * 2048;
            #pragma unroll
            for (int kb = 0; kb < 2; ++kb) {
                short8 pa[2];
                #pragma unroll
                for (int mi = 0; mi < 2; ++mi) {
                    int prow = mi * 16 + l15;
                    pa[mi] = *reinterpret_cast<const short8*>(
                        pbase + prow * 64 + (((g + 4 * kb) ^ (prow & 7)) * 8));
                }
                #pragma unroll
                for (int cb = 0; cb < 16; ++cb) {
                    int vrow = cb * 16 + l15;
                    short8 vb = *reinterpret_cast<const short8*>(
                        vt_lds + vrow * 64 + (((g + 4 * kb) ^ (vrow & 7)) * 8));
                    #pragma unroll
                    for (int mi = 0; mi < 2; ++mi)
                        o[mi][cb] = __builtin_amdgcn_mfma_f32_16x16x32_bf16(
                            pa[mi], vb, o[mi][cb], 0, 0, 0);
                }
            }
        }
    }

    // ---- epilogue ----
    #pragma unroll
    for (int mi = 0; mi < 2; ++mi) {
        float invl[4];
        #pragma unroll
        for (int r = 0; r < 4; ++r) invl[r] = 1.f / l[mi][r];
        #pragma unroll
        for (int cb = 0; cb < 16; ++cb)
            #pragma unroll
            for (int r = 0; r < 4; ++r) {
                int spos = qrow0 + mi * 16 + g * 4 + r;
                attn_out[(((size_t)b * S_LEN + spos) * NH + h) * VD_ + cb * 16 + l15] =
                    f2bf(o[mi][cb][r] * invl[r]);
            }
    }
}

// ---------------------------------------------------------------------------
// K5: out = attn_out (4096x4096 bf16) @ w_oT (2048x4096 bf16), f32 out.
//   128x128 tile, BK=64, global_load_lds staging w/ pre-swizzled source.
// ---------------------------------------------------------------------------
__global__ __launch_bounds__(256)
void k5_gemm_mfma(const short* __restrict__ A,
                  const short* __restrict__ Bt,
                  float* __restrict__ C)
{
    __shared__ __align__(16) short at[128 * 64];  // rows 128B, 8 chunks
    __shared__ __align__(16) short bt[128 * 64];
    const int tid  = threadIdx.x;
    const int lane = tid & 63;
    const int wid  = tid >> 6;
    const int wm = wid >> 1, wn = wid & 1;
    const int g = lane >> 4, l15 = lane & 15;
    const int bn = blockIdx.x & 15, bm = blockIdx.x >> 4;
    const int m0 = bm * 128, n0 = bn * 128;

    float4v acc[4][4];
    #pragma unroll
    for (int mi = 0; mi < 4; ++mi)
        #pragma unroll
        for (int nj = 0; nj < 4; ++nj) acc[mi][nj] = (float4v){0.f, 0.f, 0.f, 0.f};

    for (int k0 = 0; k0 < 4096; k0 += 64) {
        __syncthreads();
        #pragma unroll
        for (int i = 0; i < 4; ++i) {
            int row = wid * 32 + i * 8 + (lane >> 3);
            int ch  = lane & 7;
            gl_lds16(A + (size_t)(m0 + row) * 4096 + k0 + ((ch ^ (row & 7)) * 8),
                     at + wid * 2048 + i * 512);
            gl_lds16(Bt + (size_t)(n0 + row) * 4096 + k0 + ((ch ^ (row & 7)) * 8),
                     bt + wid * 2048 + i * 512);
        }
        __syncthreads();

        #pragma unroll
        for (int kb = 0; kb < 2; ++kb) {
            short8 af[4], bfr[4];
            #pragma unroll
            for (int mi = 0; mi < 4; ++mi) {
                int row = wm * 64 + mi * 16 + l15;
                af[mi] = *reinterpret_cast<const short8*>(
                    at + row * 64 + (((g + 4 * kb) ^ (row & 7)) * 8));
            }
            #pragma unroll
            for (int nj = 0; nj < 4; ++nj) {
                int row = wn * 64 + nj * 16 + l15;
                bfr[nj] = *reinterpret_cast<const short8*>(
                    bt + row * 64 + (((g + 4 * kb) ^ (row & 7)) * 8));
            }
            #pragma unroll
            for (int mi = 0; mi < 4; ++mi)
                #pragma unroll
                for (int nj = 0; nj < 4; ++nj)
                    acc[mi][nj] = __builtin_amdgcn_mfma_f32_16x16x32_bf16(
                        af[mi], bfr[nj], acc[mi][nj], 0, 0, 0);
        }
    }

    #pragma unroll
    for (int mi = 0; mi < 4; ++mi)
        #pragma unroll
        for (int nj = 0; nj < 4; ++nj)
            #pragma unroll
            for (int r = 0; r < 4; ++r)
                C[(size_t)(m0 + wm * 64 + mi * 16 + g * 4 + r) * DIM + n0 + wn * 64 + nj * 16 + l15] =
                    acc[mi][nj][r];
}

// ---------------------------------------------------------------------------
extern "C" void kernel_launch(void* const* d_in, const int* in_sizes, int n_in,
                              void* d_out, int out_size, void* d_ws, size_t ws_size,
                              hipStream_t stream)
{
    const float* x        = (const float*)d_in[0];
    const float* w_dq     = (const float*)d_in[1];
    const float* gamma_q  = (const float*)d_in[2];
    const float* w_uq     = (const float*)d_in[3];
    const float* w_dkv    = (const float*)d_in[4];
    const float* gamma_kv = (const float*)d_in[5];
    const float* w_ukv    = (const float*)d_in[6];
    const float* w_o      = (const float*)d_in[7];
    float* out = (float*)d_out;

    char* ws = (char*)d_ws;
    float* cq_ln    = (float*)(ws);                       // 2 MB
    float* ckv_ln   = (float*)(ws + (2ull  << 20));       // 2 MB
    float* kr_rope  = (float*)(ws + (4ull  << 20));       // 1 MB
    short* q_states = (short*)(ws + (5ull  << 20));       // 16 MB
    short* k_states = (short*)(ws + (21ull << 20));       // 4 MB
    short* v_states = (short*)(ws + (25ull << 20));       // 8 MB
    short* vt       = (short*)(ws + (33ull << 20));       // 8 MB
    short* attn_out = (short*)(ws + (41ull << 20));       // 32 MB
    short* w_oT     = (short*)(ws + (73ull << 20));       // 16 MB
    short* xbf      = (short*)(ws + (89ull << 20));       // 16 MB
    short* wdT      = (short*)(ws + (105ull << 20));      // 1.25 MB

    kcast_x<<<dim3(ROWS_TOT * DIM / (256 * 8)), dim3(256), 0, stream>>>(x, xbf);
    kprep_wd<<<dim3(160), dim3(256), 0, stream>>>(w_dq, w_dkv, wdT);
    k0t_transpose_wo<<<dim3(2048), dim3(256), 0, stream>>>(w_o, w_oT);

    k1_mfma<<<dim3(ROWS_TOT / 16), dim3(256), 0, stream>>>(
        xbf, wdT, gamma_q, gamma_kv, cq_ln, ckv_ln, kr_rope);

    k2_upq_rope<<<dim3(ROWS_TOT / K2_ROWS), dim3(256), 0, stream>>>(
        cq_ln, w_uq, q_states);

    k3_upkv<<<dim3(ROWS_TOT / K3_ROWS), dim3(256), 0, stream>>>(
        ckv_ln, w_ukv, kr_rope, k_states, v_states);

    k3t_transpose_v<<<dim3(BATCH * NKV * 32 * 4), dim3(256), 0, stream>>>(
        v_states, vt);

    k4_attn_mfma<<<dim3(BATCH * NH * 16), dim3(256), 0, stream>>>(
        q_states, k_states, vt, attn_out);

    k5_gemm_mfma<<<dim3((ROWS_TOT / 128) * (DIM / 128)), dim3(256), 0, stream>>>(
        attn_out, w_oT, out);
}

// Round 5
// 310.170 us; speedup vs baseline: 11.3643x; 1.8138x over previous
//
#include <hip/hip_runtime.h>
#include <hip/hip_bf16.h>
#include <math.h>

#define DIM   2048
#define S_LEN 2048
#define BATCH 2
#define NH    16
#define NKV   4
#define CQ_   128
#define QN_   96
#define QR_   32
#define CKV_  128
#define KN_   64
#define KR_   64
#define VD_   256
#define ROWS_TOT (BATCH*S_LEN)   // 4096
#define QK_SCALE 0.08838834764831845f

typedef __attribute__((ext_vector_type(8))) short short8;
typedef __attribute__((ext_vector_type(4))) float float4v;

__device__ inline short f2bf(float x) {
    union { __hip_bfloat16 h; short s; } u;
    u.h = __float2bfloat16(x);
    return u.s;
}

// async global->LDS, 16B/lane; LDS dest wave-uniform base (HW: base+lane*16,
// linear). Swizzle via pre-swizzled per-lane GLOBAL source (m173 pattern).
__device__ __forceinline__ void gl_lds16(const short* g, short* lds) {
    __builtin_amdgcn_global_load_lds(
        (const __attribute__((address_space(1))) unsigned int*)(g),
        (__attribute__((address_space(3))) unsigned int*)(lds),
        16, 0, 0);
}

// ---------------------------------------------------------------------------
// KTAB: RoPE cos/sin tables. tq[spos][16][2] (D=32), tk[spos][32][2] (D=64).
// ---------------------------------------------------------------------------
__global__ __launch_bounds__(64)
void ktab_rope(float* __restrict__ tq, float* __restrict__ tk)
{
    const int spos = blockIdx.x, t = threadIdx.x;
    if (t < 16) {
        float inv = powf(10000.f, -(float)(2 * t) / 32.f);
        float sn, c; sincosf((float)spos * inv, &sn, &c);
        tq[(spos * 16 + t) * 2 + 0] = c;
        tq[(spos * 16 + t) * 2 + 1] = sn;
    } else if (t < 48) {
        int i2 = t - 16;
        float inv = powf(10000.f, -(float)(2 * i2) / 64.f);
        float sn, c; sincosf((float)spos * inv, &sn, &c);
        tk[(spos * 32 + i2) * 2 + 0] = c;
        tk[(spos * 32 + i2) * 2 + 1] = sn;
    }
}

// ---------------------------------------------------------------------------
// KC: x (4096x2048 f32) -> xbf bf16
// ---------------------------------------------------------------------------
__global__ __launch_bounds__(256)
void kcast_x(const float* __restrict__ x, short* __restrict__ xbf)
{
    int i = (blockIdx.x * 256 + threadIdx.x) * 8;
    float4 a = *reinterpret_cast<const float4*>(x + i);
    float4 b = *reinterpret_cast<const float4*>(x + i + 4);
    short8 o;
    o[0] = f2bf(a.x); o[1] = f2bf(a.y); o[2] = f2bf(a.z); o[3] = f2bf(a.w);
    o[4] = f2bf(b.x); o[5] = f2bf(b.y); o[6] = f2bf(b.z); o[7] = f2bf(b.w);
    *reinterpret_cast<short8*>(xbf + i) = o;
}

// ---------------------------------------------------------------------------
// KTRANS: generic f32 (R x C) -> bf16 transposed (C x R). 64x64 tiles.
// ---------------------------------------------------------------------------
__global__ __launch_bounds__(256)
void ktrans(const float* __restrict__ src, short* __restrict__ dst,
            int C, int R, int nct)
{
    __shared__ float tf[64][65];
    const int tid = threadIdx.x;
    const int ct = blockIdx.x % nct, rt = blockIdx.x / nct;
    const int r0 = rt * 64, c0 = ct * 64;

    #pragma unroll
    for (int u4 = 0; u4 < 4; ++u4) {
        int u = u4 * 256 + tid;
        int kr = u >> 4, nc = (u & 15) * 4;
        float4 v = *reinterpret_cast<const float4*>(&src[(size_t)(r0 + kr) * C + c0 + nc]);
        tf[kr][nc + 0] = v.x; tf[kr][nc + 1] = v.y;
        tf[kr][nc + 2] = v.z; tf[kr][nc + 3] = v.w;
    }
    __syncthreads();
    #pragma unroll
    for (int u2 = 0; u2 < 2; ++u2) {
        int u = u2 * 256 + tid;
        int nr = u >> 3, kc8 = (u & 7) * 8;
        short8 o;
        #pragma unroll
        for (int j = 0; j < 8; ++j) o[j] = f2bf(tf[kc8 + j][nr]);
        *reinterpret_cast<short8*>(&dst[(size_t)(c0 + nr) * R + r0 + kc8]) = o;
    }
}

// ---------------------------------------------------------------------------
// KW: wdT (320 x 2048) bf16 = [w_dq | w_dkv]^T
// ---------------------------------------------------------------------------
__global__ __launch_bounds__(256)
void kprep_wd(const float* __restrict__ w_dq, const float* __restrict__ w_dkv,
              short* __restrict__ wdT)
{
    __shared__ float tf[64][65];
    const int tid = threadIdx.x;
    const int nt = blockIdx.x % 5, kt = blockIdx.x / 5;
    const int k0 = kt * 64, n0 = nt * 64;
    const float* src; int stride, nbase;
    if (nt < 2) { src = w_dq;  stride = 128; nbase = n0; }
    else        { src = w_dkv; stride = 192; nbase = n0 - 128; }

    #pragma unroll
    for (int u4 = 0; u4 < 4; ++u4) {
        int u = u4 * 256 + tid;
        int kr = u >> 4, nc = (u & 15) * 4;
        float4 v = *reinterpret_cast<const float4*>(&src[(size_t)(k0 + kr) * stride + nbase + nc]);
        tf[kr][nc + 0] = v.x; tf[kr][nc + 1] = v.y;
        tf[kr][nc + 2] = v.z; tf[kr][nc + 3] = v.w;
    }
    __syncthreads();
    #pragma unroll
    for (int u2 = 0; u2 < 2; ++u2) {
        int u = u2 * 256 + tid;
        int nr = u >> 3, kc8 = (u & 7) * 8;
        short8 o;
        #pragma unroll
        for (int j = 0; j < 8; ++j) o[j] = f2bf(tf[kc8 + j][nr]);
        *reinterpret_cast<short8*>(&wdT[(size_t)(n0 + nr) * 2048 + k0 + kc8]) = o;
    }
}

// ---------------------------------------------------------------------------
// K1: MFMA GEMM (M-tile 16, N=320, K=2048) + fused LN + K-RoPE (table).
//   cq_bf gets QK_SCALE folded in.
// ---------------------------------------------------------------------------
__global__ __launch_bounds__(256)
void k1_mfma(const short* __restrict__ xbf, const short* __restrict__ wdT,
             const float* __restrict__ gamma_q, const float* __restrict__ gamma_kv,
             const float* __restrict__ tk,
             short* __restrict__ cq_bf, short* __restrict__ ckv_bf,
             float* __restrict__ kr_rope)
{
    __shared__ float ys[16][321];
    __shared__ float st[16][4];
    const int tid = threadIdx.x, lane = tid & 63, w = tid >> 6;
    const int g = lane >> 4, l15 = lane & 15;
    const int m0 = blockIdx.x * 16;
    const int wn0 = w * 80;

    float4v acc[5];
    #pragma unroll
    for (int nj = 0; nj < 5; ++nj) acc[nj] = (float4v){0.f, 0.f, 0.f, 0.f};

    const short* arow = xbf + (size_t)(m0 + l15) * 2048 + g * 8;
    for (int ks = 0; ks < 64; ++ks) {
        short8 a = *reinterpret_cast<const short8*>(arow + ks * 32);
        #pragma unroll
        for (int nj = 0; nj < 5; ++nj) {
            short8 bf = *reinterpret_cast<const short8*>(
                wdT + (size_t)(wn0 + nj * 16 + l15) * 2048 + ks * 32 + g * 8);
            acc[nj] = __builtin_amdgcn_mfma_f32_16x16x32_bf16(a, bf, acc[nj], 0, 0, 0);
        }
    }

    #pragma unroll
    for (int nj = 0; nj < 5; ++nj)
        #pragma unroll
        for (int r = 0; r < 4; ++r)
            ys[g * 4 + r][wn0 + nj * 16 + l15] = acc[nj][r];
    __syncthreads();

    if (tid < 32) {
        int row = tid >> 1, seg = tid & 1, base = seg * 128;
        float s1 = 0.f, s2 = 0.f;
        for (int j = 0; j < 128; ++j) { float v = ys[row][base + j]; s1 += v; s2 += v * v; }
        float mu  = s1 * (1.f / 128.f);
        float var = s2 * (1.f / 128.f) - mu * mu;
        st[row][seg * 2 + 0] = mu;
        st[row][seg * 2 + 1] = rsqrtf(var + 1e-5f);
    }
    __syncthreads();

    for (int i = tid; i < 16 * 320; i += 256) {
        int row = i / 320, col = i - row * 320;
        int r = m0 + row, spos = r & (S_LEN - 1);
        float v = ys[row][col];
        if (col < 128) {
            cq_bf[(size_t)r * CQ_ + col] =
                f2bf((v - st[row][0]) * st[row][1] * gamma_q[col] * QK_SCALE);
        } else if (col < 256) {
            ckv_bf[(size_t)r * CKV_ + (col - 128)] =
                f2bf((v - st[row][2]) * st[row][3] * gamma_kv[col - 128]);
        } else {
            int d = col - 256, i2 = d >> 1;
            float xe = ys[row][256 + (d & ~1)];
            float xo = ys[row][256 + (d | 1)];
            float c  = tk[(spos * 32 + i2) * 2 + 0];
            float sn = tk[(spos * 32 + i2) * 2 + 1];
            kr_rope[(size_t)r * KR_ + d] = (d & 1) ? (xe * sn + xo * c)
                                                   : (xe * c - xo * sn);
        }
    }
}

// ---------------------------------------------------------------------------
// K2: q = cq_bf @ w_uq (MFMA, K=128) + Q-RoPE (table) -> q_states bf16 (B,H,S,128)
// ---------------------------------------------------------------------------
__global__ __launch_bounds__(256)
void k2_mfma(const short* __restrict__ cq_bf, const short* __restrict__ w_uqT,
             const float* __restrict__ tq, short* __restrict__ q_states)
{
    const int tid = threadIdx.x, lane = tid & 63, w = tid >> 6;
    const int g = lane >> 4, l15 = lane & 15;
    const int bm = blockIdx.x >> 1, ns = blockIdx.x & 1;
    const int m0 = bm * 16;
    const int nb = ns * 1024 + w * 256;

    short8 af[4];
    #pragma unroll
    for (int ks = 0; ks < 4; ++ks)
        af[ks] = *reinterpret_cast<const short8*>(
            cq_bf + (size_t)(m0 + l15) * 128 + ks * 32 + g * 8);

    float4v acc[16];
    #pragma unroll
    for (int nj = 0; nj < 16; ++nj) acc[nj] = (float4v){0.f, 0.f, 0.f, 0.f};

    #pragma unroll
    for (int ks = 0; ks < 4; ++ks)
        #pragma unroll
        for (int nj = 0; nj < 16; ++nj) {
            short8 bf = *reinterpret_cast<const short8*>(
                w_uqT + (size_t)(nb + nj * 16 + l15) * 128 + ks * 32 + g * 8);
            acc[nj] = __builtin_amdgcn_mfma_f32_16x16x32_bf16(af[ks], bf, acc[nj], 0, 0, 0);
        }

    #pragma unroll
    for (int nj = 0; nj < 16; ++nj) {
        int j = nb + nj * 16 + l15;
        if (j < NH * QN_) {
            int h = j / QN_, d = j - h * QN_;
            #pragma unroll
            for (int r = 0; r < 4; ++r) {
                int rg = m0 + g * 4 + r, bb = rg >> 11, spos = rg & (S_LEN - 1);
                q_states[(((size_t)bb * NH + h) * S_LEN + spos) * 128 + d] =
                    f2bf(acc[nj][r]);
            }
        } else {
            int jj = j - NH * QN_;
            int h = jj >> 5, d = jj & 31, i2 = d >> 1;
            #pragma unroll
            for (int r = 0; r < 4; ++r) {
                int rg = m0 + g * 4 + r, bb = rg >> 11, spos = rg & (S_LEN - 1);
                float v = acc[nj][r];
                float p = __shfl_xor(v, 1, 64);
                float c  = tq[(spos * 16 + i2) * 2 + 0];
                float sn = tq[(spos * 16 + i2) * 2 + 1];
                float out = (d & 1) ? (p * sn + v * c) : (v * c - p * sn);
                q_states[(((size_t)bb * NH + h) * S_LEN + spos) * 128 + QN_ + d] =
                    f2bf(out);
            }
        }
    }
}

// ---------------------------------------------------------------------------
// K3: kv = ckv_bf @ w_ukv (MFMA, K=128) -> k_states, v_states (+rope bcast)
// ---------------------------------------------------------------------------
__global__ __launch_bounds__(256)
void k3_mfma(const short* __restrict__ ckv_bf, const short* __restrict__ w_ukvT,
             const float* __restrict__ kr_rope,
             short* __restrict__ k_states, short* __restrict__ v_states)
{
    const int tid = threadIdx.x, lane = tid & 63, w = tid >> 6;
    const int g = lane >> 4, l15 = lane & 15;
    const int m0 = blockIdx.x * 16;
    const int nb = w * 320;

    short8 af[4];
    #pragma unroll
    for (int ks = 0; ks < 4; ++ks)
        af[ks] = *reinterpret_cast<const short8*>(
            ckv_bf + (size_t)(m0 + l15) * 128 + ks * 32 + g * 8);

    float4v acc[20];
    #pragma unroll
    for (int nj = 0; nj < 20; ++nj) acc[nj] = (float4v){0.f, 0.f, 0.f, 0.f};

    #pragma unroll
    for (int ks = 0; ks < 4; ++ks)
        #pragma unroll
        for (int nj = 0; nj < 20; ++nj) {
            short8 bf = *reinterpret_cast<const short8*>(
                w_ukvT + (size_t)(nb + nj * 16 + l15) * 128 + ks * 32 + g * 8);
            acc[nj] = __builtin_amdgcn_mfma_f32_16x16x32_bf16(af[ks], bf, acc[nj], 0, 0, 0);
        }

    #pragma unroll
    for (int nj = 0; nj < 20; ++nj) {
        int j = nb + nj * 16 + l15;
        if (j < NKV * KN_) {
            int kvh = j >> 6, d = j & 63;
            #pragma unroll
            for (int r = 0; r < 4; ++r) {
                int rg = m0 + g * 4 + r, bb = rg >> 11, spos = rg & (S_LEN - 1);
                k_states[(((size_t)bb * NKV + kvh) * S_LEN + spos) * 128 + d] =
                    f2bf(acc[nj][r]);
            }
        } else {
            int jj = j - NKV * KN_;
            int kvh = jj >> 8, d = jj & 255;
            #pragma unroll
            for (int r = 0; r < 4; ++r) {
                int rg = m0 + g * 4 + r, bb = rg >> 11, spos = rg & (S_LEN - 1);
                v_states[(((size_t)bb * NKV + kvh) * S_LEN + spos) * VD_ + d] =
                    f2bf(acc[nj][r]);
            }
        }
    }

    for (int i = tid; i < 16 * KR_; i += 256) {
        int rr = i >> 6, d = i & 63;
        int rg = m0 + rr, bb = rg >> 11, spos = rg & (S_LEN - 1);
        short vv = f2bf(kr_rope[(size_t)rg * KR_ + d]);
        #pragma unroll
        for (int kvh = 0; kvh < NKV; ++kvh)
            k_states[(((size_t)bb * NKV + kvh) * S_LEN + spos) * 128 + KN_ + d] = vv;
    }
}

// ---------------------------------------------------------------------------
// K3T: v_states (B,KV,S,VD) bf16 -> vt (B,KV,VD,S) bf16
// ---------------------------------------------------------------------------
__global__ __launch_bounds__(256)
void k3t_transpose_v(const short* __restrict__ v, short* __restrict__ vt)
{
    __shared__ short t[64][66];
    const int tid = threadIdx.x;
    const int vtile = blockIdx.x & 3;
    const int stile = (blockIdx.x >> 2) & 31;
    const int bk    = blockIdx.x >> 7;

    const short* src = v + ((size_t)bk * S_LEN + stile * 64) * VD_ + vtile * 64;
    #pragma unroll
    for (int u2 = 0; u2 < 2; ++u2) {
        int u = u2 * 256 + tid;
        int srow = u >> 3, vc8 = (u & 7) * 8;
        short8 val = *reinterpret_cast<const short8*>(src + (size_t)srow * VD_ + vc8);
        #pragma unroll
        for (int j = 0; j < 8; ++j) t[srow][vc8 + j] = val[j];
    }
    __syncthreads();
    short* dst = vt + ((size_t)bk * VD_ + vtile * 64) * S_LEN + stile * 64;
    #pragma unroll
    for (int u2 = 0; u2 < 2; ++u2) {
        int u = u2 * 256 + tid;
        int vr = u >> 3, sc8 = (u & 7) * 8;
        short8 o;
        #pragma unroll
        for (int j = 0; j < 8; ++j) o[j] = t[sc8 + j][vr];
        *reinterpret_cast<short8*>(dst + (size_t)vr * S_LEN + sc8) = o;
    }
}

// ---------------------------------------------------------------------------
// K4: bf16 MFMA causal flash attention, counted-vmcnt pipeline.
//   8 waves (512 thr), q-tile 128 rows (16/wave), KV tiles of 64.
//   K TRIPLE-buffered, V DOUBLE-buffered => writer of iter seq never touches
//   a buffer readable in iters seq-1..seq  =>  1 barrier + 1 wait per iter.
//   Queue invariant at top of iter: [K[seq](2), V[seq](4), K[seq+1](2)]
//   -> s_waitcnt vmcnt(2). Issue order V-then-K keeps this exact.
//   Paired q-tiles (tA, 15-tA): every block = 34 iters. 256 blocks = 1/CU.
// ---------------------------------------------------------------------------
__global__ __launch_bounds__(512, 1)
void k4_attn_mfma(const short* __restrict__ q_states,
                  const short* __restrict__ k_states,
                  const short* __restrict__ vt,
                  short* __restrict__ attn_out)
{
    __shared__ __align__(16) short ks_lds[3][64 * 128];   // 3 x 16 KB
    __shared__ __align__(16) short vt_lds[2][256 * 64];   // 2 x 32 KB
    __shared__ __align__(16) short ps_lds[8 * 16 * 64];   // 16 KB (per-wave strips)

    const int tid = threadIdx.x, lane = tid & 63, w = tid >> 6;   // w 0..7
    const int g = lane >> 4, l15 = lane & 15;
    const int tA = blockIdx.x >> 5;       // 0..7
    const int tB = 15 - tA;
    const int bh = blockIdx.x & 31;
    const int h = bh & 15, b = bh >> 4, kvh = h >> 2;

    const short* kbase  = k_states + (((size_t)b * NKV + kvh) * S_LEN) * 128;
    const short* vtbase = vt + (((size_t)b * NKV + kvh) * VD_) * S_LEN;

    // Q fragments for both runs (16 rows per wave)
    short8 qcur[4], qfB[4];
    {
        const short* qa = q_states + (((size_t)b * NH + h) * S_LEN + tA * 128 + w * 16 + l15) * 128 + g * 8;
        const short* qb = q_states + (((size_t)b * NH + h) * S_LEN + tB * 128 + w * 16 + l15) * 128 + g * 8;
        #pragma unroll
        for (int kb = 0; kb < 4; ++kb) {
            qcur[kb] = *reinterpret_cast<const short8*>(qa + kb * 32);
            qfB[kb]  = *reinterpret_cast<const short8*>(qb + kb * 32);
        }
    }

    float4v o[16];
    #pragma unroll
    for (int cb = 0; cb < 16; ++cb) o[cb] = (float4v){0.f, 0.f, 0.f, 0.f};
    float m[4] = {-1e30f, -1e30f, -1e30f, -1e30f};
    float l[4] = {0.f, 0.f, 0.f, 0.f};

    const int nA  = 2 * tA + 2;   // iters in run A
    const int NIT = 34;           // total iters (uniform across blocks)

    auto kvTile = [&](int s) { return (s < nA) ? s : s - nA; };

    // K tile 64x128 bf16 = 16 KB: 2 gl_lds16 per wave (8 rows/wave)
    auto issueK = [&](int kt, int bufi) {
        const short* ksrc = kbase + (size_t)kt * 64 * 128;
        short* dst = &ks_lds[bufi][w * 1024];
        #pragma unroll
        for (int i = 0; i < 2; ++i) {
            int c = i * 64 + lane;
            int row = w * 8 + (c >> 4), ch = c & 15;
            gl_lds16(ksrc + row * 128 + ((ch ^ (row & 7)) * 8), dst + i * 512);
        }
    };
    // V^T tile 256x64 bf16 = 32 KB: 4 gl_lds16 per wave (32 rows/wave)
    auto issueV = [&](int kt, int bufi) {
        const short* vsrc = vtbase + kt * 64;
        short* dst = &vt_lds[bufi][w * 2048];
        #pragma unroll
        for (int i = 0; i < 4; ++i) {
            int c = i * 64 + lane;
            int row = w * 32 + (c >> 3), ch = c & 7;
            gl_lds16(vsrc + (size_t)row * S_LEN + ((ch ^ (row & 7)) * 8),
                     dst + i * 512);
        }
    };
    auto epilogue = [&](int qt) {
        float invl[4];
        #pragma unroll
        for (int r = 0; r < 4; ++r) invl[r] = 1.f / l[r];
        #pragma unroll
        for (int cb = 0; cb < 16; ++cb)
            #pragma unroll
            for (int r = 0; r < 4; ++r) {
                int spos = qt * 128 + w * 16 + g * 4 + r;
                attn_out[(((size_t)b * S_LEN + spos) * NH + h) * VD_ + cb * 16 + l15] =
                    f2bf(o[cb][r] * invl[r]);
            }
    };

    // prologue: queue = [K0(2), V0(4), K1(2)] = 8 outstanding
    issueK(kvTile(0), 0);
    issueV(kvTile(0), 0);
    issueK(kvTile(1), 1);

    for (int seq = 0; seq < NIT; ++seq) {
        const bool runA = (seq < nA);
        const int kt = runA ? seq : seq - nA;
        const int qt = runA ? tA : tB;
        const int qrow0 = qt * 128 + w * 16;

        // ---- wait: K[seq] & V[seq] landed; K[seq+1] may stay in flight ----
        if (seq < NIT - 1) { asm volatile("s_waitcnt vmcnt(2)" ::: "memory"); }
        else               { asm volatile("s_waitcnt vmcnt(0)" ::: "memory"); }
        __builtin_amdgcn_s_barrier();
        __builtin_amdgcn_sched_barrier(0);

        // ---- issue next tiles (V FIRST, then K — keeps vmcnt(2) exact) ----
        // V[seq+1] -> vbuf[(seq+1)&1]  (PV[seq] reads vbuf[seq&1]; barrier above
        //   guarantees PV[seq-1] (same buffer) is complete block-wide)
        // K[seq+2] -> kbuf[(seq+2)%3]  (QK[seq] reads kbuf[seq%3], K[seq+1] in
        //   kbuf[(seq+1)%3]; QK[seq-1] on this buffer done at barrier above)
        if (seq + 1 < NIT) issueV(kvTile(seq + 1), (seq + 1) & 1);
        if (seq + 2 < NIT) issueK(kvTile(seq + 2), (seq + 2) % 3);

        if (kt * 64 <= qrow0 + 15) {   // wave has >=1 unmasked key
            // ---- S = Q K^T ----
            const short* kbuf = ks_lds[seq % 3];
            float4v s[4];
            #pragma unroll
            for (int nj = 0; nj < 4; ++nj) s[nj] = (float4v){0.f, 0.f, 0.f, 0.f};
            __builtin_amdgcn_s_setprio(1);
            #pragma unroll
            for (int kb = 0; kb < 4; ++kb)
                #pragma unroll
                for (int nj = 0; nj < 4; ++nj) {
                    int row = nj * 16 + l15;
                    short8 kf = *reinterpret_cast<const short8*>(
                        kbuf + row * 128 + (((g + 4 * kb) ^ (row & 7)) * 8));
                    s[nj] = __builtin_amdgcn_mfma_f32_16x16x32_bf16(qcur[kb], kf, s[nj], 0, 0, 0);
                }
            __builtin_amdgcn_s_setprio(0);

            // ---- causal mask (near-diagonal tiles only) ----
            if (kt * 64 + 63 > qrow0) {
                #pragma unroll
                for (int nj = 0; nj < 4; ++nj)
                    #pragma unroll
                    for (int r = 0; r < 4; ++r) {
                        int qrow = qrow0 + g * 4 + r;
                        int kcol = kt * 64 + nj * 16 + l15;
                        if (kcol > qrow) s[nj][r] = -1e30f;
                    }
            }

            // ---- online softmax w/ defer-max (THR=8) ----
            float mx[4];
            #pragma unroll
            for (int r = 0; r < 4; ++r) {
                float v = fmaxf(fmaxf(s[0][r], s[1][r]), fmaxf(s[2][r], s[3][r]));
                v = fmaxf(v, __shfl_xor(v, 1, 64));
                v = fmaxf(v, __shfl_xor(v, 2, 64));
                v = fmaxf(v, __shfl_xor(v, 4, 64));
                v = fmaxf(v, __shfl_xor(v, 8, 64));
                mx[r] = v;
            }
            bool need = (mx[0] > m[0] + 8.f) || (mx[1] > m[1] + 8.f) ||
                        (mx[2] > m[2] + 8.f) || (mx[3] > m[3] + 8.f);
            if (__ballot(need)) {
                #pragma unroll
                for (int r = 0; r < 4; ++r) {
                    float mnew = fmaxf(m[r], mx[r]);
                    float corr = __expf(m[r] - mnew);
                    m[r] = mnew;
                    l[r] *= corr;
                    #pragma unroll
                    for (int cb = 0; cb < 16; ++cb) o[cb][r] *= corr;
                }
            }
            #pragma unroll
            for (int r = 0; r < 4; ++r) {
                float psum = 0.f;
                #pragma unroll
                for (int nj = 0; nj < 4; ++nj) {
                    float p = __expf(s[nj][r] - m[r]);
                    s[nj][r] = p;
                    psum += p;
                }
                psum += __shfl_xor(psum, 1, 64);
                psum += __shfl_xor(psum, 2, 64);
                psum += __shfl_xor(psum, 4, 64);
                psum += __shfl_xor(psum, 8, 64);
                l[r] += psum;
            }
            // ---- P -> own wave strip (same-wave DS ordering) ----
            {
                char* pb = (char*)(ps_lds + w * 1024);
                #pragma unroll
                for (int nj = 0; nj < 4; ++nj)
                    #pragma unroll
                    for (int r = 0; r < 4; ++r) {
                        int prow = g * 4 + r, pcol = nj * 16 + l15;
                        *reinterpret_cast<short*>(
                            pb + prow * 128 + ((pcol * 2) ^ ((prow & 7) << 4))) =
                            f2bf(s[nj][r]);
                    }
            }

            // ---- O += P @ V ----
            {
                const short* pbase = ps_lds + w * 1024;
                const short* vbuf  = vt_lds[seq & 1];
                __builtin_amdgcn_s_setprio(1);
                #pragma unroll
                for (int kb = 0; kb < 2; ++kb) {
                    int prow = l15;
                    short8 pa = *reinterpret_cast<const short8*>(
                        pbase + prow * 64 + (((g + 4 * kb) ^ (prow & 7)) * 8));
                    #pragma unroll
                    for (int cb = 0; cb < 16; ++cb) {
                        int vrow = cb * 16 + l15;
                        short8 vb = *reinterpret_cast<const short8*>(
                            vbuf + vrow * 64 + (((g + 4 * kb) ^ (vrow & 7)) * 8));
                        o[cb] = __builtin_amdgcn_mfma_f32_16x16x32_bf16(pa, vb, o[cb], 0, 0, 0);
                    }
                }
                __builtin_amdgcn_s_setprio(0);
            }
        }

        // ---- run boundary: finish tile A, reset state (no vmcnt drain) ----
        if (seq == nA - 1) {
            epilogue(tA);
            #pragma unroll
            for (int cb = 0; cb < 16; ++cb) o[cb] = (float4v){0.f, 0.f, 0.f, 0.f};
            #pragma unroll
            for (int r = 0; r < 4; ++r) { m[r] = -1e30f; l[r] = 0.f; }
            #pragma unroll
            for (int kb = 0; kb < 4; ++kb) qcur[kb] = qfB[kb];
        }
    }

    epilogue(tB);
}

// ---------------------------------------------------------------------------
// K5: out = attn_out (4096x4096 bf16) @ w_oT (2048x4096 bf16), f32 out.
// ---------------------------------------------------------------------------
__global__ __launch_bounds__(256)
void k5_gemm_mfma(const short* __restrict__ A,
                  const short* __restrict__ Bt,
                  float* __restrict__ C)
{
    __shared__ __align__(16) short at[128 * 64];
    __shared__ __align__(16) short bt[128 * 64];
    const int tid  = threadIdx.x;
    const int lane = tid & 63;
    const int wid  = tid >> 6;
    const int wm = wid >> 1, wn = wid & 1;
    const int g = lane >> 4, l15 = lane & 15;
    const int bn = blockIdx.x & 15, bm = blockIdx.x >> 4;
    const int m0 = bm * 128, n0 = bn * 128;

    float4v acc[4][4];
    #pragma unroll
    for (int mi = 0; mi < 4; ++mi)
        #pragma unroll
        for (int nj = 0; nj < 4; ++nj) acc[mi][nj] = (float4v){0.f, 0.f, 0.f, 0.f};

    for (int k0 = 0; k0 < 4096; k0 += 64) {
        __syncthreads();
        #pragma unroll
        for (int i = 0; i < 4; ++i) {
            int row = wid * 32 + i * 8 + (lane >> 3);
            int ch  = lane & 7;
            gl_lds16(A + (size_t)(m0 + row) * 4096 + k0 + ((ch ^ (row & 7)) * 8),
                     at + wid * 2048 + i * 512);
            gl_lds16(Bt + (size_t)(n0 + row) * 4096 + k0 + ((ch ^ (row & 7)) * 8),
                     bt + wid * 2048 + i * 512);
        }
        __syncthreads();

        #pragma unroll
        for (int kb = 0; kb < 2; ++kb) {
            short8 af[4], bfr[4];
            #pragma unroll
            for (int mi = 0; mi < 4; ++mi) {
                int row = wm * 64 + mi * 16 + l15;
                af[mi] = *reinterpret_cast<const short8*>(
                    at + row * 64 + (((g + 4 * kb) ^ (row & 7)) * 8));
            }
            #pragma unroll
            for (int nj = 0; nj < 4; ++nj) {
                int row = wn * 64 + nj * 16 + l15;
                bfr[nj] = *reinterpret_cast<const short8*>(
                    bt + row * 64 + (((g + 4 * kb) ^ (row & 7)) * 8));
            }
            #pragma unroll
            for (int mi = 0; mi < 4; ++mi)
                #pragma unroll
                for (int nj = 0; nj < 4; ++nj)
                    acc[mi][nj] = __builtin_amdgcn_mfma_f32_16x16x32_bf16(
                        af[mi], bfr[nj], acc[mi][nj], 0, 0, 0);
        }
    }

    #pragma unroll
    for (int mi = 0; mi < 4; ++mi)
        #pragma unroll
        for (int nj = 0; nj < 4; ++nj)
            #pragma unroll
            for (int r = 0; r < 4; ++r)
                C[(size_t)(m0 + wm * 64 + mi * 16 + g * 4 + r) * DIM + n0 + wn * 64 + nj * 16 + l15] =
                    acc[mi][nj][r];
}

// ---------------------------------------------------------------------------
extern "C" void kernel_launch(void* const* d_in, const int* in_sizes, int n_in,
                              void* d_out, int out_size, void* d_ws, size_t ws_size,
                              hipStream_t stream)
{
    const float* x        = (const float*)d_in[0];
    const float* w_dq     = (const float*)d_in[1];
    const float* gamma_q  = (const float*)d_in[2];
    const float* w_uq     = (const float*)d_in[3];
    const float* w_dkv    = (const float*)d_in[4];
    const float* gamma_kv = (const float*)d_in[5];
    const float* w_ukv    = (const float*)d_in[6];
    const float* w_o      = (const float*)d_in[7];
    float* out = (float*)d_out;

    char* ws = (char*)d_ws;
    float* kr_rope  = (float*)(ws);                       // 1 MB
    short* cq_bf    = (short*)(ws + (1ull  << 20));       // 1 MB
    short* ckv_bf   = (short*)(ws + (2ull  << 20));       // 1 MB
    float* tq       = (float*)(ws + (3ull  << 20));       // 0.25 MB
    float* tk       = (float*)(ws + (4ull  << 20));       // 0.5 MB
    short* w_uqT    = (short*)(ws + (5ull  << 20));       // 0.5 MB
    short* w_ukvT   = (short*)(ws + (6ull  << 20));       // 0.32 MB
    short* wdT      = (short*)(ws + (7ull  << 20));       // 1.25 MB
    short* q_states = (short*)(ws + (9ull  << 20));       // 16 MB
    short* k_states = (short*)(ws + (25ull << 20));       // 4 MB
    short* v_states = (short*)(ws + (29ull << 20));       // 8 MB
    short* vt       = (short*)(ws + (37ull << 20));       // 8 MB
    short* attn_out = (short*)(ws + (45ull << 20));       // 32 MB
    short* w_oT     = (short*)(ws + (77ull << 20));       // 16 MB
    short* xbf      = (short*)(ws + (93ull << 20));       // 16 MB
    // total 109 MB

    ktab_rope<<<dim3(S_LEN), dim3(64), 0, stream>>>(tq, tk);
    kcast_x<<<dim3(ROWS_TOT * DIM / (256 * 8)), dim3(256), 0, stream>>>(x, xbf);
    kprep_wd<<<dim3(160), dim3(256), 0, stream>>>(w_dq, w_dkv, wdT);
    ktrans<<<dim3(64),   dim3(256), 0, stream>>>(w_uq,  w_uqT,  2048, 128, 32);
    ktrans<<<dim3(40),   dim3(256), 0, stream>>>(w_ukv, w_ukvT, 1280, 128, 20);
    ktrans<<<dim3(2048), dim3(256), 0, stream>>>(w_o,   w_oT,   2048, 4096, 32);

    k1_mfma<<<dim3(ROWS_TOT / 16), dim3(256), 0, stream>>>(
        xbf, wdT, gamma_q, gamma_kv, tk, cq_bf, ckv_bf, kr_rope);

    k2_mfma<<<dim3((ROWS_TOT / 16) * 2), dim3(256), 0, stream>>>(
        cq_bf, w_uqT, tq, q_states);

    k3_mfma<<<dim3(ROWS_TOT / 16), dim3(256), 0, stream>>>(
        ckv_bf, w_ukvT, kr_rope, k_states, v_states);

    k3t_transpose_v<<<dim3(BATCH * NKV * 32 * 4), dim3(256), 0, stream>>>(
        v_states, vt);

    k4_attn_mfma<<<dim3(8 * 32), dim3(512), 0, stream>>>(
        q_states, k_states, vt, attn_out);

    k5_gemm_mfma<<<dim3((ROWS_TOT / 128) * (DIM / 128)), dim3(256), 0, stream>>>(
        attn_out, w_oT, out);
}

// Round 6
// 305.457 us; speedup vs baseline: 11.5397x; 1.0154x over previous
//
#include <hip/hip_runtime.h>
#include <hip/hip_bf16.h>
#include <math.h>

#define DIM   2048
#define S_LEN 2048
#define BATCH 2
#define NH    16
#define NKV   4
#define CQ_   128
#define QN_   96
#define QR_   32
#define CKV_  128
#define KN_   64
#define KR_   64
#define VD_   256
#define ROWS_TOT (BATCH*S_LEN)   // 4096
#define QK_SCALE 0.08838834764831845f
#define LOG2E    1.4426950408889634f

typedef __attribute__((ext_vector_type(8)))  short short8;
typedef __attribute__((ext_vector_type(4)))  short short4v;
typedef __attribute__((ext_vector_type(4)))  float float4v;
typedef __attribute__((ext_vector_type(16))) float float16v;
typedef __attribute__((ext_vector_type(4)))  int   int4v;

__device__ inline short f2bf(float x) {
    union { __hip_bfloat16 h; short s; } u;
    u.h = __float2bfloat16(x);
    return u.s;
}

// async global->LDS, 16B/lane; LDS dest wave-uniform base (HW: base+lane*16,
// linear). Swizzle via pre-swizzled per-lane GLOBAL source (m173 pattern).
__device__ __forceinline__ void gl_lds16(const short* g, short* lds) {
    __builtin_amdgcn_global_load_lds(
        (const __attribute__((address_space(1))) unsigned int*)(g),
        (__attribute__((address_space(3))) unsigned int*)(lds),
        16, 0, 0);
}

// ---------------------------------------------------------------------------
// KTAB: RoPE cos/sin tables. tq[spos][16][2] (D=32), tk[spos][32][2] (D=64).
// ---------------------------------------------------------------------------
__global__ __launch_bounds__(64)
void ktab_rope(float* __restrict__ tq, float* __restrict__ tk)
{
    const int spos = blockIdx.x, t = threadIdx.x;
    if (t < 16) {
        float inv = powf(10000.f, -(float)(2 * t) / 32.f);
        float sn, c; sincosf((float)spos * inv, &sn, &c);
        tq[(spos * 16 + t) * 2 + 0] = c;
        tq[(spos * 16 + t) * 2 + 1] = sn;
    } else if (t < 48) {
        int i2 = t - 16;
        float inv = powf(10000.f, -(float)(2 * i2) / 64.f);
        float sn, c; sincosf((float)spos * inv, &sn, &c);
        tk[(spos * 32 + i2) * 2 + 0] = c;
        tk[(spos * 32 + i2) * 2 + 1] = sn;
    }
}

// ---------------------------------------------------------------------------
// KC: x (4096x2048 f32) -> xbf bf16
// ---------------------------------------------------------------------------
__global__ __launch_bounds__(256)
void kcast_x(const float* __restrict__ x, short* __restrict__ xbf)
{
    int i = (blockIdx.x * 256 + threadIdx.x) * 8;
    float4 a = *reinterpret_cast<const float4*>(x + i);
    float4 b = *reinterpret_cast<const float4*>(x + i + 4);
    short8 o;
    o[0] = f2bf(a.x); o[1] = f2bf(a.y); o[2] = f2bf(a.z); o[3] = f2bf(a.w);
    o[4] = f2bf(b.x); o[5] = f2bf(b.y); o[6] = f2bf(b.z); o[7] = f2bf(b.w);
    *reinterpret_cast<short8*>(xbf + i) = o;
}

// ---------------------------------------------------------------------------
// KTRANS: generic f32 (R x C) -> bf16 transposed (C x R). 64x64 tiles.
// ---------------------------------------------------------------------------
__global__ __launch_bounds__(256)
void ktrans(const float* __restrict__ src, short* __restrict__ dst,
            int C, int R, int nct)
{
    __shared__ float tf[64][65];
    const int tid = threadIdx.x;
    const int ct = blockIdx.x % nct, rt = blockIdx.x / nct;
    const int r0 = rt * 64, c0 = ct * 64;

    #pragma unroll
    for (int u4 = 0; u4 < 4; ++u4) {
        int u = u4 * 256 + tid;
        int kr = u >> 4, nc = (u & 15) * 4;
        float4 v = *reinterpret_cast<const float4*>(&src[(size_t)(r0 + kr) * C + c0 + nc]);
        tf[kr][nc + 0] = v.x; tf[kr][nc + 1] = v.y;
        tf[kr][nc + 2] = v.z; tf[kr][nc + 3] = v.w;
    }
    __syncthreads();
    #pragma unroll
    for (int u2 = 0; u2 < 2; ++u2) {
        int u = u2 * 256 + tid;
        int nr = u >> 3, kc8 = (u & 7) * 8;
        short8 o;
        #pragma unroll
        for (int j = 0; j < 8; ++j) o[j] = f2bf(tf[kc8 + j][nr]);
        *reinterpret_cast<short8*>(&dst[(size_t)(c0 + nr) * R + r0 + kc8]) = o;
    }
}

// ---------------------------------------------------------------------------
// KW: wdT (320 x 2048) bf16 = [w_dq | w_dkv]^T
// ---------------------------------------------------------------------------
__global__ __launch_bounds__(256)
void kprep_wd(const float* __restrict__ w_dq, const float* __restrict__ w_dkv,
              short* __restrict__ wdT)
{
    __shared__ float tf[64][65];
    const int tid = threadIdx.x;
    const int nt = blockIdx.x % 5, kt = blockIdx.x / 5;
    const int k0 = kt * 64, n0 = nt * 64;
    const float* src; int stride, nbase;
    if (nt < 2) { src = w_dq;  stride = 128; nbase = n0; }
    else        { src = w_dkv; stride = 192; nbase = n0 - 128; }

    #pragma unroll
    for (int u4 = 0; u4 < 4; ++u4) {
        int u = u4 * 256 + tid;
        int kr = u >> 4, nc = (u & 15) * 4;
        float4 v = *reinterpret_cast<const float4*>(&src[(size_t)(k0 + kr) * stride + nbase + nc]);
        tf[kr][nc + 0] = v.x; tf[kr][nc + 1] = v.y;
        tf[kr][nc + 2] = v.z; tf[kr][nc + 3] = v.w;
    }
    __syncthreads();
    #pragma unroll
    for (int u2 = 0; u2 < 2; ++u2) {
        int u = u2 * 256 + tid;
        int nr = u >> 3, kc8 = (u & 7) * 8;
        short8 o;
        #pragma unroll
        for (int j = 0; j < 8; ++j) o[j] = f2bf(tf[kc8 + j][nr]);
        *reinterpret_cast<short8*>(&wdT[(size_t)(n0 + nr) * 2048 + k0 + kc8]) = o;
    }
}

// ---------------------------------------------------------------------------
// K1: MFMA GEMM (M-tile 16, N=320, K=2048) + fused LN + K-RoPE (table).
//   cq_bf gets QK_SCALE*LOG2E folded in (exp2-domain softmax downstream).
// ---------------------------------------------------------------------------
__global__ __launch_bounds__(256)
void k1_mfma(const short* __restrict__ xbf, const short* __restrict__ wdT,
             const float* __restrict__ gamma_q, const float* __restrict__ gamma_kv,
             const float* __restrict__ tk,
             short* __restrict__ cq_bf, short* __restrict__ ckv_bf,
             float* __restrict__ kr_rope)
{
    __shared__ float ys[16][321];
    __shared__ float st[16][4];
    const int tid = threadIdx.x, lane = tid & 63, w = tid >> 6;
    const int g = lane >> 4, l15 = lane & 15;
    const int m0 = blockIdx.x * 16;
    const int wn0 = w * 80;

    float4v acc[5];
    #pragma unroll
    for (int nj = 0; nj < 5; ++nj) acc[nj] = (float4v){0.f, 0.f, 0.f, 0.f};

    const short* arow = xbf + (size_t)(m0 + l15) * 2048 + g * 8;
    for (int ks = 0; ks < 64; ++ks) {
        short8 a = *reinterpret_cast<const short8*>(arow + ks * 32);
        #pragma unroll
        for (int nj = 0; nj < 5; ++nj) {
            short8 bf = *reinterpret_cast<const short8*>(
                wdT + (size_t)(wn0 + nj * 16 + l15) * 2048 + ks * 32 + g * 8);
            acc[nj] = __builtin_amdgcn_mfma_f32_16x16x32_bf16(a, bf, acc[nj], 0, 0, 0);
        }
    }

    #pragma unroll
    for (int nj = 0; nj < 5; ++nj)
        #pragma unroll
        for (int r = 0; r < 4; ++r)
            ys[g * 4 + r][wn0 + nj * 16 + l15] = acc[nj][r];
    __syncthreads();

    if (tid < 32) {
        int row = tid >> 1, seg = tid & 1, base = seg * 128;
        float s1 = 0.f, s2 = 0.f;
        for (int j = 0; j < 128; ++j) { float v = ys[row][base + j]; s1 += v; s2 += v * v; }
        float mu  = s1 * (1.f / 128.f);
        float var = s2 * (1.f / 128.f) - mu * mu;
        st[row][seg * 2 + 0] = mu;
        st[row][seg * 2 + 1] = rsqrtf(var + 1e-5f);
    }
    __syncthreads();

    for (int i = tid; i < 16 * 320; i += 256) {
        int row = i / 320, col = i - row * 320;
        int r = m0 + row, spos = r & (S_LEN - 1);
        float v = ys[row][col];
        if (col < 128) {
            cq_bf[(size_t)r * CQ_ + col] =
                f2bf((v - st[row][0]) * st[row][1] * gamma_q[col] * (QK_SCALE * LOG2E));
        } else if (col < 256) {
            ckv_bf[(size_t)r * CKV_ + (col - 128)] =
                f2bf((v - st[row][2]) * st[row][3] * gamma_kv[col - 128]);
        } else {
            int d = col - 256, i2 = d >> 1;
            float xe = ys[row][256 + (d & ~1)];
            float xo = ys[row][256 + (d | 1)];
            float c  = tk[(spos * 32 + i2) * 2 + 0];
            float sn = tk[(spos * 32 + i2) * 2 + 1];
            kr_rope[(size_t)r * KR_ + d] = (d & 1) ? (xe * sn + xo * c)
                                                   : (xe * c - xo * sn);
        }
    }
}

// ---------------------------------------------------------------------------
// K2: q = cq_bf @ w_uq (MFMA, K=128) + Q-RoPE (table) -> q_states bf16 (B,H,S,128)
// ---------------------------------------------------------------------------
__global__ __launch_bounds__(256)
void k2_mfma(const short* __restrict__ cq_bf, const short* __restrict__ w_uqT,
             const float* __restrict__ tq, short* __restrict__ q_states)
{
    const int tid = threadIdx.x, lane = tid & 63, w = tid >> 6;
    const int g = lane >> 4, l15 = lane & 15;
    const int bm = blockIdx.x >> 1, ns = blockIdx.x & 1;
    const int m0 = bm * 16;
    const int nb = ns * 1024 + w * 256;

    short8 af[4];
    #pragma unroll
    for (int ks = 0; ks < 4; ++ks)
        af[ks] = *reinterpret_cast<const short8*>(
            cq_bf + (size_t)(m0 + l15) * 128 + ks * 32 + g * 8);

    float4v acc[16];
    #pragma unroll
    for (int nj = 0; nj < 16; ++nj) acc[nj] = (float4v){0.f, 0.f, 0.f, 0.f};

    #pragma unroll
    for (int ks = 0; ks < 4; ++ks)
        #pragma unroll
        for (int nj = 0; nj < 16; ++nj) {
            short8 bf = *reinterpret_cast<const short8*>(
                w_uqT + (size_t)(nb + nj * 16 + l15) * 128 + ks * 32 + g * 8);
            acc[nj] = __builtin_amdgcn_mfma_f32_16x16x32_bf16(af[ks], bf, acc[nj], 0, 0, 0);
        }

    #pragma unroll
    for (int nj = 0; nj < 16; ++nj) {
        int j = nb + nj * 16 + l15;
        if (j < NH * QN_) {
            int h = j / QN_, d = j - h * QN_;
            #pragma unroll
            for (int r = 0; r < 4; ++r) {
                int rg = m0 + g * 4 + r, bb = rg >> 11, spos = rg & (S_LEN - 1);
                q_states[(((size_t)bb * NH + h) * S_LEN + spos) * 128 + d] =
                    f2bf(acc[nj][r]);
            }
        } else {
            int jj = j - NH * QN_;
            int h = jj >> 5, d = jj & 31, i2 = d >> 1;
            #pragma unroll
            for (int r = 0; r < 4; ++r) {
                int rg = m0 + g * 4 + r, bb = rg >> 11, spos = rg & (S_LEN - 1);
                float v = acc[nj][r];
                float p = __shfl_xor(v, 1, 64);
                float c  = tq[(spos * 16 + i2) * 2 + 0];
                float sn = tq[(spos * 16 + i2) * 2 + 1];
                float out = (d & 1) ? (p * sn + v * c) : (v * c - p * sn);
                q_states[(((size_t)bb * NH + h) * S_LEN + spos) * 128 + QN_ + d] =
                    f2bf(out);
            }
        }
    }
}

// ---------------------------------------------------------------------------
// K3: kv = ckv_bf @ w_ukv (MFMA, K=128) -> k_states, v_states (+rope bcast)
// ---------------------------------------------------------------------------
__global__ __launch_bounds__(256)
void k3_mfma(const short* __restrict__ ckv_bf, const short* __restrict__ w_ukvT,
             const float* __restrict__ kr_rope,
             short* __restrict__ k_states, short* __restrict__ v_states)
{
    const int tid = threadIdx.x, lane = tid & 63, w = tid >> 6;
    const int g = lane >> 4, l15 = lane & 15;
    const int m0 = blockIdx.x * 16;
    const int nb = w * 320;

    short8 af[4];
    #pragma unroll
    for (int ks = 0; ks < 4; ++ks)
        af[ks] = *reinterpret_cast<const short8*>(
            ckv_bf + (size_t)(m0 + l15) * 128 + ks * 32 + g * 8);

    float4v acc[20];
    #pragma unroll
    for (int nj = 0; nj < 20; ++nj) acc[nj] = (float4v){0.f, 0.f, 0.f, 0.f};

    #pragma unroll
    for (int ks = 0; ks < 4; ++ks)
        #pragma unroll
        for (int nj = 0; nj < 20; ++nj) {
            short8 bf = *reinterpret_cast<const short8*>(
                w_ukvT + (size_t)(nb + nj * 16 + l15) * 128 + ks * 32 + g * 8);
            acc[nj] = __builtin_amdgcn_mfma_f32_16x16x32_bf16(af[ks], bf, acc[nj], 0, 0, 0);
        }

    #pragma unroll
    for (int nj = 0; nj < 20; ++nj) {
        int j = nb + nj * 16 + l15;
        if (j < NKV * KN_) {
            int kvh = j >> 6, d = j & 63;
            #pragma unroll
            for (int r = 0; r < 4; ++r) {
                int rg = m0 + g * 4 + r, bb = rg >> 11, spos = rg & (S_LEN - 1);
                k_states[(((size_t)bb * NKV + kvh) * S_LEN + spos) * 128 + d] =
                    f2bf(acc[nj][r]);
            }
        } else {
            int jj = j - NKV * KN_;
            int kvh = jj >> 8, d = jj & 255;
            #pragma unroll
            for (int r = 0; r < 4; ++r) {
                int rg = m0 + g * 4 + r, bb = rg >> 11, spos = rg & (S_LEN - 1);
                v_states[(((size_t)bb * NKV + kvh) * S_LEN + spos) * VD_ + d] =
                    f2bf(acc[nj][r]);
            }
        }
    }

    for (int i = tid; i < 16 * KR_; i += 256) {
        int rr = i >> 6, d = i & 63;
        int rg = m0 + rr, bb = rg >> 11, spos = rg & (S_LEN - 1);
        short vv = f2bf(kr_rope[(size_t)rg * KR_ + d]);
        #pragma unroll
        for (int kvh = 0; kvh < NKV; ++kvh)
            k_states[(((size_t)bb * NKV + kvh) * S_LEN + spos) * 128 + KN_ + d] = vv;
    }
}

// ---------------------------------------------------------------------------
// K3T: v_states (B,KV,S,VD) bf16 -> vt (B,KV,VD,S) bf16
// ---------------------------------------------------------------------------
__global__ __launch_bounds__(256)
void k3t_transpose_v(const short* __restrict__ v, short* __restrict__ vt)
{
    __shared__ short t[64][66];
    const int tid = threadIdx.x;
    const int vtile = blockIdx.x & 3;
    const int stile = (blockIdx.x >> 2) & 31;
    const int bk    = blockIdx.x >> 7;

    const short* src = v + ((size_t)bk * S_LEN + stile * 64) * VD_ + vtile * 64;
    #pragma unroll
    for (int u2 = 0; u2 < 2; ++u2) {
        int u = u2 * 256 + tid;
        int srow = u >> 3, vc8 = (u & 7) * 8;
        short8 val = *reinterpret_cast<const short8*>(src + (size_t)srow * VD_ + vc8);
        #pragma unroll
        for (int j = 0; j < 8; ++j) t[srow][vc8 + j] = val[j];
    }
    __syncthreads();
    short* dst = vt + ((size_t)bk * VD_ + vtile * 64) * S_LEN + stile * 64;
    #pragma unroll
    for (int u2 = 0; u2 < 2; ++u2) {
        int u = u2 * 256 + tid;
        int vr = u >> 3, sc8 = (u & 7) * 8;
        short8 o;
        #pragma unroll
        for (int j = 0; j < 8; ++j) o[j] = t[sc8 + j][vr];
        *reinterpret_cast<short8*>(dst + (size_t)vr * S_LEN + sc8) = o;
    }
}

// ---------------------------------------------------------------------------
// K4: swapped-QK 32x32 MFMA causal flash attention, counted-vmcnt pipeline.
//   4 warps x 32 q-rows = 128-row q-tile; KVBLK=64; paired tiles (tA,15-tA)
//   -> uniform 34 iters; 256 blocks = 1/CU.
//   S^T = mfma32(K,Q): lane owns q = lane&31; softmax = per-lane scalars +
//   one shfl_xor(32) merge. P -> PA frags in-register via v_cvt_pk_bf16_f32 +
//   v_permlane32_swap_b32 (no P LDS). O^T = mfma32(V^T, PA).
//   K 3-buf, V 2-buf, 1 barrier + vmcnt(4) per iter (R5-proven invariants):
//   top-of-iter queue = [K[seq](4), V[seq](8), K[seq+1](4)] -> vmcnt(4).
// ---------------------------------------------------------------------------
__global__ __launch_bounds__(256, 1)
void k4_attn_mfma(const short* __restrict__ q_states,
                  const short* __restrict__ k_states,
                  const short* __restrict__ vt,
                  short* __restrict__ attn_out)
{
    __shared__ __align__(16) short ks_lds[3][64 * 128];   // 3 x 16 KB
    __shared__ __align__(16) short vt_lds[2][256 * 64];   // 2 x 32 KB

    const int tid = threadIdx.x, lane = tid & 63, w = tid >> 6;   // w 0..3
    const int l31 = lane & 31, hi = lane >> 5;
    const int tA = blockIdx.x >> 5;            // 0..7
    const int tB = 15 - tA;
    const int bh = blockIdx.x & 31;
    const int h = bh & 15, b = bh >> 4, kvh = h >> 2;

    const short* kbase  = k_states + (((size_t)b * NKV + kvh) * S_LEN) * 128;
    const short* vtbase = vt + (((size_t)b * NKV + kvh) * VD_) * S_LEN;

    // Q fragments: B-operand of 32x32x16: col=q=l31, k = st*16 + hi*8 + [0..8)
    short8 qcur[8];
    auto loadQ = [&](int qt) {
        const short* qr = q_states +
            (((size_t)b * NH + h) * S_LEN + qt * 128 + w * 32 + l31) * 128 + hi * 8;
        #pragma unroll
        for (int st = 0; st < 8; ++st)
            qcur[st] = *reinterpret_cast<const short8*>(qr + st * 16);
    };
    loadQ(tA);

    float16v o[8];
    #pragma unroll
    for (int dt = 0; dt < 8; ++dt)
        #pragma unroll
        for (int r = 0; r < 16; ++r) o[dt][r] = 0.f;
    float mreg = -1e30f, lreg = 0.f;

    const int nA  = 2 * (tA + 1);
    const int NIT = 34;
    auto kvTile = [&](int s) { return (s < nA) ? s : s - nA; };

    // K tile 64x128 = 16KB: 4 gl_lds16/wave (16 rows/wave)
    auto issueK = [&](int kt, int bufi) {
        const short* ksrc = kbase + (size_t)kt * 64 * 128;
        short* dst = &ks_lds[bufi][w * 2048];
        #pragma unroll
        for (int i = 0; i < 4; ++i) {
            int row = w * 16 + i * 4 + (lane >> 4), ch = lane & 15;
            gl_lds16(ksrc + row * 128 + ((ch ^ (row & 7)) * 8), dst + i * 512);
        }
    };
    // V^T tile 256x64 = 32KB: 8 gl_lds16/wave (64 rows/wave)
    auto issueV = [&](int kt, int bufi) {
        const short* vsrc = vtbase + kt * 64;
        short* dst = &vt_lds[bufi][w * 4096];
        #pragma unroll
        for (int i = 0; i < 8; ++i) {
            int row = w * 64 + i * 8 + (lane >> 3), ch = lane & 7;
            gl_lds16(vsrc + (size_t)row * S_LEN + ((ch ^ (row & 7)) * 8),
                     dst + i * 512);
        }
    };
    auto epilogue = [&](int qt) {
        float invl = 1.f / lreg;
        int spos = qt * 128 + w * 32 + l31;
        short* obase = attn_out + (((size_t)b * S_LEN + spos) * NH + h) * VD_;
        #pragma unroll
        for (int dt = 0; dt < 8; ++dt)
            #pragma unroll
            for (int k4 = 0; k4 < 4; ++k4) {
                int d0 = dt * 32 + k4 * 8 + hi * 4;
                short4v pk;
                #pragma unroll
                for (int j = 0; j < 4; ++j) pk[j] = f2bf(o[dt][k4 * 4 + j] * invl);
                *reinterpret_cast<short4v*>(obase + d0) = pk;
            }
    };

    // prologue: queue = [K0(4), V0(8), K1(4)] = 16 outstanding
    issueK(kvTile(0), 0);
    issueV(kvTile(0), 0);
    issueK(kvTile(1), 1);

    for (int seq = 0; seq < NIT; ++seq) {
        const bool runA = (seq < nA);
        const int kt = runA ? seq : seq - nA;
        const int qt = runA ? tA : tB;
        const int qrow0 = qt * 128 + w * 32;

        if (seq < NIT - 1) { asm volatile("s_waitcnt vmcnt(4)" ::: "memory"); }
        else               { asm volatile("s_waitcnt vmcnt(0)" ::: "memory"); }
        __builtin_amdgcn_s_barrier();
        __builtin_amdgcn_sched_barrier(0);

        // issue next tiles (V first, then K — keeps the count invariant exact)
        if (seq + 1 < NIT) issueV(kvTile(seq + 1), (seq + 1) & 1);
        if (seq + 2 < NIT) issueK(kvTile(seq + 2), (seq + 2) % 3);

        if (kt * 64 <= qrow0 + 31) {
            const short* kbuf = ks_lds[seq % 3];
            const int qglob = qrow0 + l31;

            // ---- S^T = K Q^T (2 x 32x32 tiles over kv) ----
            float16v s0, s1;
            #pragma unroll
            for (int r = 0; r < 16; ++r) { s0[r] = 0.f; s1[r] = 0.f; }
            #pragma unroll
            for (int st = 0; st < 8; ++st) {
                int row0 = l31;
                short8 kf0 = *reinterpret_cast<const short8*>(
                    kbuf + row0 * 128 + (((st * 2 + hi) ^ (row0 & 7)) * 8));
                s0 = __builtin_amdgcn_mfma_f32_32x32x16_bf16(kf0, qcur[st], s0, 0, 0, 0);
                int row1 = 32 + l31;
                short8 kf1 = *reinterpret_cast<const short8*>(
                    kbuf + row1 * 128 + (((st * 2 + hi) ^ (row1 & 7)) * 8));
                s1 = __builtin_amdgcn_mfma_f32_32x32x16_bf16(kf1, qcur[st], s1, 0, 0, 0);
            }

            // ---- causal mask (rows = kv = (r&3)+8*(r>>2)+4*hi) ----
            if (kt * 64 + 63 > qrow0) {
                #pragma unroll
                for (int r = 0; r < 16; ++r) {
                    int kc = kt * 64 + ((r & 3) + 8 * (r >> 2) + 4 * hi);
                    if (kc > qglob)      s0[r] = -1e30f;
                    if (kc + 32 > qglob) s1[r] = -1e30f;
                }
            }

            // ---- per-lane scalar online softmax (exp2 domain) ----
            float mx = s0[0];
            #pragma unroll
            for (int r = 1; r < 16; ++r) mx = fmaxf(mx, s0[r]);
            #pragma unroll
            for (int r = 0; r < 16; ++r) mx = fmaxf(mx, s1[r]);
            mx = fmaxf(mx, __shfl_xor(mx, 32, 64));
            bool need = mx > mreg + 8.f;
            if (__ballot(need)) {
                float mnew = fmaxf(mreg, mx);
                float corr = exp2f(mreg - mnew);
                mreg = mnew;
                lreg *= corr;
                #pragma unroll
                for (int dt = 0; dt < 8; ++dt)
                    #pragma unroll
                    for (int r = 0; r < 16; ++r) o[dt][r] *= corr;
            }
            #pragma unroll
            for (int r = 0; r < 16; ++r) {
                s0[r] = exp2f(s0[r] - mreg);
                s1[r] = exp2f(s1[r] - mreg);
            }
            float ps = 0.f;
            #pragma unroll
            for (int r = 0; r < 16; ++r) ps += s0[r] + s1[r];
            ps += __shfl_xor(ps, 32, 64);
            lreg += ps;

            // ---- PA frags in-register + O^T += V^T * P^T ----
            const short* vbuf = vt_lds[seq & 1];
            #pragma unroll
            for (int ks = 0; ks < 4; ++ks) {
                const int rb = (ks & 1) * 8;
                float p0, p1, p2, p3, p4, p5, p6, p7;
                if (ks < 2) {
                    p0 = s0[rb+0]; p1 = s0[rb+1]; p2 = s0[rb+2]; p3 = s0[rb+3];
                    p4 = s0[rb+4]; p5 = s0[rb+5]; p6 = s0[rb+6]; p7 = s0[rb+7];
                } else {
                    p0 = s1[rb+0]; p1 = s1[rb+1]; p2 = s1[rb+2]; p3 = s1[rb+3];
                    p4 = s1[rb+4]; p5 = s1[rb+5]; p6 = s1[rb+6]; p7 = s1[rb+7];
                }
                int c01, c23, c45, c67;
                asm("v_cvt_pk_bf16_f32 %0, %1, %2" : "=v"(c01) : "v"(p0), "v"(p1));
                asm("v_cvt_pk_bf16_f32 %0, %1, %2" : "=v"(c23) : "v"(p2), "v"(p3));
                asm("v_cvt_pk_bf16_f32 %0, %1, %2" : "=v"(c45) : "v"(p4), "v"(p5));
                asm("v_cvt_pk_bf16_f32 %0, %1, %2" : "=v"(c67) : "v"(p6), "v"(p7));
                // swap hi-half of first with lo-half of second:
                // c01 -> [own lo pairs | partner (8,9)-style], etc.
                asm("v_permlane32_swap_b32 %0, %1" : "+v"(c01), "+v"(c45));
                asm("v_permlane32_swap_b32 %0, %1" : "+v"(c23), "+v"(c67));
                union { int4v i4; short8 s8; } u_;
                u_.i4.x = c01; u_.i4.y = c23; u_.i4.z = c45; u_.i4.w = c67;
                short8 pa = u_.s8;
                #pragma unroll
                for (int dt = 0; dt < 8; ++dt) {
                    int row = dt * 32 + l31;
                    short8 vf = *reinterpret_cast<const short8*>(
                        vbuf + row * 64 + (((ks * 2 + hi) ^ (row & 7)) * 8));
                    o[dt] = __builtin_amdgcn_mfma_f32_32x32x16_bf16(vf, pa, o[dt], 0, 0, 0);
                }
            }
        }

        // ---- run boundary: finish tile A, reset, load Q for tile B ----
        if (seq == nA - 1) {
            epilogue(tA);
            #pragma unroll
            for (int dt = 0; dt < 8; ++dt)
                #pragma unroll
                for (int r = 0; r < 16; ++r) o[dt][r] = 0.f;
            mreg = -1e30f; lreg = 0.f;
            loadQ(tB);
        }
    }

    epilogue(tB);
}

// ---------------------------------------------------------------------------
// K5: out = attn_out (4096x4096 bf16) @ w_oT (2048x4096 bf16), f32 out.
// ---------------------------------------------------------------------------
__global__ __launch_bounds__(256)
void k5_gemm_mfma(const short* __restrict__ A,
                  const short* __restrict__ Bt,
                  float* __restrict__ C)
{
    __shared__ __align__(16) short at[128 * 64];
    __shared__ __align__(16) short bt[128 * 64];
    const int tid  = threadIdx.x;
    const int lane = tid & 63;
    const int wid  = tid >> 6;
    const int wm = wid >> 1, wn = wid & 1;
    const int g = lane >> 4, l15 = lane & 15;
    const int bn = blockIdx.x & 15, bm = blockIdx.x >> 4;
    const int m0 = bm * 128, n0 = bn * 128;

    float4v acc[4][4];
    #pragma unroll
    for (int mi = 0; mi < 4; ++mi)
        #pragma unroll
        for (int nj = 0; nj < 4; ++nj) acc[mi][nj] = (float4v){0.f, 0.f, 0.f, 0.f};

    for (int k0 = 0; k0 < 4096; k0 += 64) {
        __syncthreads();
        #pragma unroll
        for (int i = 0; i < 4; ++i) {
            int row = wid * 32 + i * 8 + (lane >> 3);
            int ch  = lane & 7;
            gl_lds16(A + (size_t)(m0 + row) * 4096 + k0 + ((ch ^ (row & 7)) * 8),
                     at + wid * 2048 + i * 512);
            gl_lds16(Bt + (size_t)(n0 + row) * 4096 + k0 + ((ch ^ (row & 7)) * 8),
                     bt + wid * 2048 + i * 512);
        }
        __syncthreads();

        #pragma unroll
        for (int kb = 0; kb < 2; ++kb) {
            short8 af[4], bfr[4];
            #pragma unroll
            for (int mi = 0; mi < 4; ++mi) {
                int row = wm * 64 + mi * 16 + l15;
                af[mi] = *reinterpret_cast<const short8*>(
                    at + row * 64 + (((g + 4 * kb) ^ (row & 7)) * 8));
            }
            #pragma unroll
            for (int nj = 0; nj < 4; ++nj) {
                int row = wn * 64 + nj * 16 + l15;
                bfr[nj] = *reinterpret_cast<const short8*>(
                    bt + row * 64 + (((g + 4 * kb) ^ (row & 7)) * 8));
            }
            #pragma unroll
            for (int mi = 0; mi < 4; ++mi)
                #pragma unroll
                for (int nj = 0; nj < 4; ++nj)
                    acc[mi][nj] = __builtin_amdgcn_mfma_f32_16x16x32_bf16(
                        af[mi], bfr[nj], acc[mi][nj], 0, 0, 0);
        }
    }

    #pragma unroll
    for (int mi = 0; mi < 4; ++mi)
        #pragma unroll
        for (int nj = 0; nj < 4; ++nj)
            #pragma unroll
            for (int r = 0; r < 4; ++r)
                C[(size_t)(m0 + wm * 64 + mi * 16 + g * 4 + r) * DIM + n0 + wn * 64 + nj * 16 + l15] =
                    acc[mi][nj][r];
}

// ---------------------------------------------------------------------------
extern "C" void kernel_launch(void* const* d_in, const int* in_sizes, int n_in,
                              void* d_out, int out_size, void* d_ws, size_t ws_size,
                              hipStream_t stream)
{
    const float* x        = (const float*)d_in[0];
    const float* w_dq     = (const float*)d_in[1];
    const float* gamma_q  = (const float*)d_in[2];
    const float* w_uq     = (const float*)d_in[3];
    const float* w_dkv    = (const float*)d_in[4];
    const float* gamma_kv = (const float*)d_in[5];
    const float* w_ukv    = (const float*)d_in[6];
    const float* w_o      = (const float*)d_in[7];
    float* out = (float*)d_out;

    char* ws = (char*)d_ws;
    float* kr_rope  = (float*)(ws);                       // 1 MB
    short* cq_bf    = (short*)(ws + (1ull  << 20));       // 1 MB
    short* ckv_bf   = (short*)(ws + (2ull  << 20));       // 1 MB
    float* tq       = (float*)(ws + (3ull  << 20));       // 0.25 MB
    float* tk       = (float*)(ws + (4ull  << 20));       // 0.5 MB
    short* w_uqT    = (short*)(ws + (5ull  << 20));       // 0.5 MB
    short* w_ukvT   = (short*)(ws + (6ull  << 20));       // 0.32 MB
    short* wdT      = (short*)(ws + (7ull  << 20));       // 1.25 MB
    short* q_states = (short*)(ws + (9ull  << 20));       // 16 MB
    short* k_states = (short*)(ws + (25ull << 20));       // 4 MB
    short* v_states = (short*)(ws + (29ull << 20));       // 8 MB
    short* vt       = (short*)(ws + (37ull << 20));       // 8 MB
    short* attn_out = (short*)(ws + (45ull << 20));       // 32 MB
    short* w_oT     = (short*)(ws + (77ull << 20));       // 16 MB
    short* xbf      = (short*)(ws + (93ull << 20));       // 16 MB
    // total 109 MB

    ktab_rope<<<dim3(S_LEN), dim3(64), 0, stream>>>(tq, tk);
    kcast_x<<<dim3(ROWS_TOT * DIM / (256 * 8)), dim3(256), 0, stream>>>(x, xbf);
    kprep_wd<<<dim3(160), dim3(256), 0, stream>>>(w_dq, w_dkv, wdT);
    ktrans<<<dim3(64),   dim3(256), 0, stream>>>(w_uq,  w_uqT,  2048, 128, 32);
    ktrans<<<dim3(40),   dim3(256), 0, stream>>>(w_ukv, w_ukvT, 1280, 128, 20);
    ktrans<<<dim3(2048), dim3(256), 0, stream>>>(w_o,   w_oT,   2048, 4096, 32);

    k1_mfma<<<dim3(ROWS_TOT / 16), dim3(256), 0, stream>>>(
        xbf, wdT, gamma_q, gamma_kv, tk, cq_bf, ckv_bf, kr_rope);

    k2_mfma<<<dim3((ROWS_TOT / 16) * 2), dim3(256), 0, stream>>>(
        cq_bf, w_uqT, tq, q_states);

    k3_mfma<<<dim3(ROWS_TOT / 16), dim3(256), 0, stream>>>(
        ckv_bf, w_ukvT, kr_rope, k_states, v_states);

    k3t_transpose_v<<<dim3(BATCH * NKV * 32 * 4), dim3(256), 0, stream>>>(
        v_states, vt);

    k4_attn_mfma<<<dim3(8 * 32), dim3(256), 0, stream>>>(
        q_states, k_states, vt, attn_out);

    k5_gemm_mfma<<<dim3((ROWS_TOT / 128) * (DIM / 128)), dim3(256), 0, stream>>>(
        attn_out, w_oT, out);
}

// Round 7
// 298.309 us; speedup vs baseline: 11.8162x; 1.0240x over previous
//
#include <hip/hip_runtime.h>
#include <hip/hip_bf16.h>
#include <math.h>

#define DIM   2048
#define S_LEN 2048
#define BATCH 2
#define NH    16
#define NKV   4
#define CQ_   128
#define QN_   96
#define QR_   32
#define CKV_  128
#define KN_   64
#define KR_   64
#define VD_   256
#define ROWS_TOT (BATCH*S_LEN)   // 4096
#define QK_SCALE 0.08838834764831845f
#define LOG2E    1.4426950408889634f

typedef __attribute__((ext_vector_type(8)))  short short8;
typedef __attribute__((ext_vector_type(4)))  short short4v;
typedef __attribute__((ext_vector_type(4)))  float float4v;
typedef __attribute__((ext_vector_type(16))) float float16v;
typedef __attribute__((ext_vector_type(4)))  int   int4v;

__device__ inline short f2bf(float x) {
    union { __hip_bfloat16 h; short s; } u;
    u.h = __float2bfloat16(x);
    return u.s;
}

// async global->LDS, 16B/lane; LDS dest wave-uniform base (HW: base+lane*16,
// linear). Swizzle via pre-swizzled per-lane GLOBAL source (m173 pattern).
__device__ __forceinline__ void gl_lds16(const short* g, short* lds) {
    __builtin_amdgcn_global_load_lds(
        (const __attribute__((address_space(1))) unsigned int*)(g),
        (__attribute__((address_space(3))) unsigned int*)(lds),
        16, 0, 0);
}

// ---------------------------------------------------------------------------
// KPREP: all weight transposes (f32 -> bf16^T) + RoPE tables in ONE launch.
//   blocks [0,2048)    : w_o   (4096x2048) -> w_oT   (2048x4096)
//   blocks [2048,2112) : w_uq  (128x2048)  -> w_uqT  (2048x128)
//   blocks [2112,2152) : w_ukv (128x1280)  -> w_ukvT (1280x128)
//   blocks [2152,2312) : [w_dq|w_dkv]      -> wdT    (320x2048)
//   blocks [2312,2696) : RoPE cos/sin tables tq (S,16,2), tk (S,32,2)
// ---------------------------------------------------------------------------
__global__ __launch_bounds__(256)
void kprep_all(const float* __restrict__ w_o, const float* __restrict__ w_uq,
               const float* __restrict__ w_ukv, const float* __restrict__ w_dq,
               const float* __restrict__ w_dkv,
               short* __restrict__ w_oT, short* __restrict__ w_uqT,
               short* __restrict__ w_ukvT, short* __restrict__ wdT,
               float* __restrict__ tq, float* __restrict__ tk)
{
    const int bid = blockIdx.x, tid = threadIdx.x;
    if (bid >= 2312) {   // RoPE tables: 384*256 = 98304 = 2048*48 slots exactly
        int gid = (bid - 2312) * 256 + tid;
        int spos = gid / 48, e = gid - spos * 48;
        if (e < 16) {
            float inv = powf(10000.f, -(float)(2 * e) / 32.f);
            float sn, c; sincosf((float)spos * inv, &sn, &c);
            tq[(spos * 16 + e) * 2 + 0] = c;
            tq[(spos * 16 + e) * 2 + 1] = sn;
        } else {
            int i2 = e - 16;
            float inv = powf(10000.f, -(float)(2 * i2) / 64.f);
            float sn, c; sincosf((float)spos * inv, &sn, &c);
            tk[(spos * 32 + i2) * 2 + 0] = c;
            tk[(spos * 32 + i2) * 2 + 1] = sn;
        }
        return;
    }

    __shared__ float tf[64][65];
    int lb, nct, R; short* dst;
    if (bid < 2048)      { lb = bid;        nct = 32; R = 4096; dst = w_oT;   }
    else if (bid < 2112) { lb = bid - 2048; nct = 32; R = 128;  dst = w_uqT;  }
    else if (bid < 2152) { lb = bid - 2112; nct = 20; R = 128;  dst = w_ukvT; }
    else                 { lb = bid - 2152; nct = 5;  R = 2048; dst = wdT;    }
    const int ct = lb % nct, rt = lb / nct;
    const int r0 = rt * 64, c0 = ct * 64;
    const float* src; int stride, nbase;
    if (bid < 2048)      { src = w_o;   stride = 2048; nbase = c0; }
    else if (bid < 2112) { src = w_uq;  stride = 2048; nbase = c0; }
    else if (bid < 2152) { src = w_ukv; stride = 1280; nbase = c0; }
    else if (ct < 2)     { src = w_dq;  stride = 128;  nbase = c0; }
    else                 { src = w_dkv; stride = 192;  nbase = c0 - 128; }

    #pragma unroll
    for (int u4 = 0; u4 < 4; ++u4) {
        int u = u4 * 256 + tid;
        int kr = u >> 4, nc = (u & 15) * 4;
        float4 v = *reinterpret_cast<const float4*>(&src[(size_t)(r0 + kr) * stride + nbase + nc]);
        tf[kr][nc + 0] = v.x; tf[kr][nc + 1] = v.y;
        tf[kr][nc + 2] = v.z; tf[kr][nc + 3] = v.w;
    }
    __syncthreads();
    #pragma unroll
    for (int u2 = 0; u2 < 2; ++u2) {
        int u = u2 * 256 + tid;
        int nr = u >> 3, kc8 = (u & 7) * 8;
        short8 o;
        #pragma unroll
        for (int j = 0; j < 8; ++j) o[j] = f2bf(tf[kc8 + j][nr]);
        *reinterpret_cast<short8*>(&dst[(size_t)(c0 + nr) * R + r0 + kc8]) = o;
    }
}

// ---------------------------------------------------------------------------
// K1: MFMA GEMM (M-tile 16, N=320, K=2048) + fused LN + K-RoPE (table).
//   Reads x f32 directly (in-reg bf16 convert). cq_bf gets QK_SCALE*LOG2E.
// ---------------------------------------------------------------------------
__global__ __launch_bounds__(256)
void k1_mfma(const float* __restrict__ x, const short* __restrict__ wdT,
             const float* __restrict__ gamma_q, const float* __restrict__ gamma_kv,
             const float* __restrict__ tk,
             short* __restrict__ cq_bf, short* __restrict__ ckv_bf,
             float* __restrict__ kr_rope)
{
    __shared__ float ys[16][321];
    __shared__ float st[16][4];
    const int tid = threadIdx.x, lane = tid & 63, w = tid >> 6;
    const int g = lane >> 4, l15 = lane & 15;
    const int m0 = blockIdx.x * 16;
    const int wn0 = w * 80;

    float4v acc[5];
    #pragma unroll
    for (int nj = 0; nj < 5; ++nj) acc[nj] = (float4v){0.f, 0.f, 0.f, 0.f};

    const float* arow = x + (size_t)(m0 + l15) * 2048 + g * 8;
    for (int ks = 0; ks < 64; ++ks) {
        float4 a0 = *reinterpret_cast<const float4*>(arow + ks * 32);
        float4 a1 = *reinterpret_cast<const float4*>(arow + ks * 32 + 4);
        short8 a;
        a[0] = f2bf(a0.x); a[1] = f2bf(a0.y); a[2] = f2bf(a0.z); a[3] = f2bf(a0.w);
        a[4] = f2bf(a1.x); a[5] = f2bf(a1.y); a[6] = f2bf(a1.z); a[7] = f2bf(a1.w);
        #pragma unroll
        for (int nj = 0; nj < 5; ++nj) {
            short8 bf = *reinterpret_cast<const short8*>(
                wdT + (size_t)(wn0 + nj * 16 + l15) * 2048 + ks * 32 + g * 8);
            acc[nj] = __builtin_amdgcn_mfma_f32_16x16x32_bf16(a, bf, acc[nj], 0, 0, 0);
        }
    }

    #pragma unroll
    for (int nj = 0; nj < 5; ++nj)
        #pragma unroll
        for (int r = 0; r < 4; ++r)
            ys[g * 4 + r][wn0 + nj * 16 + l15] = acc[nj][r];
    __syncthreads();

    if (tid < 32) {
        int row = tid >> 1, seg = tid & 1, base = seg * 128;
        float s1 = 0.f, s2 = 0.f;
        for (int j = 0; j < 128; ++j) { float v = ys[row][base + j]; s1 += v; s2 += v * v; }
        float mu  = s1 * (1.f / 128.f);
        float var = s2 * (1.f / 128.f) - mu * mu;
        st[row][seg * 2 + 0] = mu;
        st[row][seg * 2 + 1] = rsqrtf(var + 1e-5f);
    }
    __syncthreads();

    for (int i = tid; i < 16 * 320; i += 256) {
        int row = i / 320, col = i - row * 320;
        int r = m0 + row, spos = r & (S_LEN - 1);
        float v = ys[row][col];
        if (col < 128) {
            cq_bf[(size_t)r * CQ_ + col] =
                f2bf((v - st[row][0]) * st[row][1] * gamma_q[col] * (QK_SCALE * LOG2E));
        } else if (col < 256) {
            ckv_bf[(size_t)r * CKV_ + (col - 128)] =
                f2bf((v - st[row][2]) * st[row][3] * gamma_kv[col - 128]);
        } else {
            int d = col - 256, i2 = d >> 1;
            float xe = ys[row][256 + (d & ~1)];
            float xo = ys[row][256 + (d | 1)];
            float c  = tk[(spos * 32 + i2) * 2 + 0];
            float sn = tk[(spos * 32 + i2) * 2 + 1];
            kr_rope[(size_t)r * KR_ + d] = (d & 1) ? (xe * sn + xo * c)
                                                   : (xe * c - xo * sn);
        }
    }
}

// ---------------------------------------------------------------------------
// K2: q = cq_bf @ w_uq (MFMA, K=128) + Q-RoPE (table) -> q_states bf16 (B,H,S,128)
// ---------------------------------------------------------------------------
__global__ __launch_bounds__(256)
void k2_mfma(const short* __restrict__ cq_bf, const short* __restrict__ w_uqT,
             const float* __restrict__ tq, short* __restrict__ q_states)
{
    const int tid = threadIdx.x, lane = tid & 63, w = tid >> 6;
    const int g = lane >> 4, l15 = lane & 15;
    const int bm = blockIdx.x >> 1, ns = blockIdx.x & 1;
    const int m0 = bm * 16;
    const int nb = ns * 1024 + w * 256;

    short8 af[4];
    #pragma unroll
    for (int ks = 0; ks < 4; ++ks)
        af[ks] = *reinterpret_cast<const short8*>(
            cq_bf + (size_t)(m0 + l15) * 128 + ks * 32 + g * 8);

    float4v acc[16];
    #pragma unroll
    for (int nj = 0; nj < 16; ++nj) acc[nj] = (float4v){0.f, 0.f, 0.f, 0.f};

    #pragma unroll
    for (int ks = 0; ks < 4; ++ks)
        #pragma unroll
        for (int nj = 0; nj < 16; ++nj) {
            short8 bf = *reinterpret_cast<const short8*>(
                w_uqT + (size_t)(nb + nj * 16 + l15) * 128 + ks * 32 + g * 8);
            acc[nj] = __builtin_amdgcn_mfma_f32_16x16x32_bf16(af[ks], bf, acc[nj], 0, 0, 0);
        }

    #pragma unroll
    for (int nj = 0; nj < 16; ++nj) {
        int j = nb + nj * 16 + l15;
        if (j < NH * QN_) {
            int h = j / QN_, d = j - h * QN_;
            #pragma unroll
            for (int r = 0; r < 4; ++r) {
                int rg = m0 + g * 4 + r, bb = rg >> 11, spos = rg & (S_LEN - 1);
                q_states[(((size_t)bb * NH + h) * S_LEN + spos) * 128 + d] =
                    f2bf(acc[nj][r]);
            }
        } else {
            int jj = j - NH * QN_;
            int h = jj >> 5, d = jj & 31, i2 = d >> 1;
            #pragma unroll
            for (int r = 0; r < 4; ++r) {
                int rg = m0 + g * 4 + r, bb = rg >> 11, spos = rg & (S_LEN - 1);
                float v = acc[nj][r];
                float p = __shfl_xor(v, 1, 64);
                float c  = tq[(spos * 16 + i2) * 2 + 0];
                float sn = tq[(spos * 16 + i2) * 2 + 1];
                float out = (d & 1) ? (p * sn + v * c) : (v * c - p * sn);
                q_states[(((size_t)bb * NH + h) * S_LEN + spos) * 128 + QN_ + d] =
                    f2bf(out);
            }
        }
    }
}

// ---------------------------------------------------------------------------
// K3: kv = ckv_bf @ w_ukv (MFMA, K=128) -> k_states, v_states (+rope bcast)
// ---------------------------------------------------------------------------
__global__ __launch_bounds__(256)
void k3_mfma(const short* __restrict__ ckv_bf, const short* __restrict__ w_ukvT,
             const float* __restrict__ kr_rope,
             short* __restrict__ k_states, short* __restrict__ v_states)
{
    const int tid = threadIdx.x, lane = tid & 63, w = tid >> 6;
    const int g = lane >> 4, l15 = lane & 15;
    const int m0 = blockIdx.x * 16;
    const int nb = w * 320;

    short8 af[4];
    #pragma unroll
    for (int ks = 0; ks < 4; ++ks)
        af[ks] = *reinterpret_cast<const short8*>(
            ckv_bf + (size_t)(m0 + l15) * 128 + ks * 32 + g * 8);

    float4v acc[20];
    #pragma unroll
    for (int nj = 0; nj < 20; ++nj) acc[nj] = (float4v){0.f, 0.f, 0.f, 0.f};

    #pragma unroll
    for (int ks = 0; ks < 4; ++ks)
        #pragma unroll
        for (int nj = 0; nj < 20; ++nj) {
            short8 bf = *reinterpret_cast<const short8*>(
                w_ukvT + (size_t)(nb + nj * 16 + l15) * 128 + ks * 32 + g * 8);
            acc[nj] = __builtin_amdgcn_mfma_f32_16x16x32_bf16(af[ks], bf, acc[nj], 0, 0, 0);
        }

    #pragma unroll
    for (int nj = 0; nj < 20; ++nj) {
        int j = nb + nj * 16 + l15;
        if (j < NKV * KN_) {
            int kvh = j >> 6, d = j & 63;
            #pragma unroll
            for (int r = 0; r < 4; ++r) {
                int rg = m0 + g * 4 + r, bb = rg >> 11, spos = rg & (S_LEN - 1);
                k_states[(((size_t)bb * NKV + kvh) * S_LEN + spos) * 128 + d] =
                    f2bf(acc[nj][r]);
            }
        } else {
            int jj = j - NKV * KN_;
            int kvh = jj >> 8, d = jj & 255;
            #pragma unroll
            for (int r = 0; r < 4; ++r) {
                int rg = m0 + g * 4 + r, bb = rg >> 11, spos = rg & (S_LEN - 1);
                v_states[(((size_t)bb * NKV + kvh) * S_LEN + spos) * VD_ + d] =
                    f2bf(acc[nj][r]);
            }
        }
    }

    for (int i = tid; i < 16 * KR_; i += 256) {
        int rr = i >> 6, d = i & 63;
        int rg = m0 + rr, bb = rg >> 11, spos = rg & (S_LEN - 1);
        short vv = f2bf(kr_rope[(size_t)rg * KR_ + d]);
        #pragma unroll
        for (int kvh = 0; kvh < NKV; ++kvh)
            k_states[(((size_t)bb * NKV + kvh) * S_LEN + spos) * 128 + KN_ + d] = vv;
    }
}

// ---------------------------------------------------------------------------
// K3T: v_states (B,KV,S,VD) bf16 -> vt (B,KV,VD,S) bf16
// ---------------------------------------------------------------------------
__global__ __launch_bounds__(256)
void k3t_transpose_v(const short* __restrict__ v, short* __restrict__ vt)
{
    __shared__ short t[64][66];
    const int tid = threadIdx.x;
    const int vtile = blockIdx.x & 3;
    const int stile = (blockIdx.x >> 2) & 31;
    const int bk    = blockIdx.x >> 7;

    const short* src = v + ((size_t)bk * S_LEN + stile * 64) * VD_ + vtile * 64;
    #pragma unroll
    for (int u2 = 0; u2 < 2; ++u2) {
        int u = u2 * 256 + tid;
        int srow = u >> 3, vc8 = (u & 7) * 8;
        short8 val = *reinterpret_cast<const short8*>(src + (size_t)srow * VD_ + vc8);
        #pragma unroll
        for (int j = 0; j < 8; ++j) t[srow][vc8 + j] = val[j];
    }
    __syncthreads();
    short* dst = vt + ((size_t)bk * VD_ + vtile * 64) * S_LEN + stile * 64;
    #pragma unroll
    for (int u2 = 0; u2 < 2; ++u2) {
        int u = u2 * 256 + tid;
        int vr = u >> 3, sc8 = (u & 7) * 8;
        short8 o;
        #pragma unroll
        for (int j = 0; j < 8; ++j) o[j] = t[sc8 + j][vr];
        *reinterpret_cast<short8*>(dst + (size_t)vr * S_LEN + sc8) = o;
    }
}

// ---------------------------------------------------------------------------
// K4: swapped-QK 32x32 MFMA causal flash attention; KVBLK=32; 2 blocks/CU.
//   4 warps x 32 q-rows = 128-row q-tile. Grid 512: bid<256 -> qt 15..8
//   (heavy, dispatched first), bid>=256 -> qt 0..7, so CU c (getting bid c
//   and c+256 under XCD round-robin) sums to a uniform 68 iter-units.
//   LDS 56 KB: K 3-buf (8KB ea), V^T 2-buf (16KB ea) -> 2 blocks/CU,
//   2 waves/SIMD => softmax VALU of one wave overlaps MFMA of the other.
//   Counted-vmcnt pipeline (R5-proven): queue [K(2),V(4),K(2)] -> vmcnt(2).
//   K swizzle domain widened to row&15 (16 chunks/row) -> 2-way banks only.
// ---------------------------------------------------------------------------
__global__ __launch_bounds__(256, 2)
void k4_attn_mfma(const short* __restrict__ q_states,
                  const short* __restrict__ k_states,
                  const short* __restrict__ vt,
                  short* __restrict__ attn_out)
{
    __shared__ __align__(16) short ks_lds[3][32 * 128];   // 3 x 8 KB
    __shared__ __align__(16) short vt_lds[2][256 * 32];   // 2 x 16 KB

    const int tid = threadIdx.x, lane = tid & 63, w = tid >> 6;   // w 0..3
    const int l31 = lane & 31, hi = lane >> 5;
    const int bid = blockIdx.x;
    const int qt = (bid < 256) ? (15 - (bid >> 5)) : ((bid >> 5) - 8);
    const int bh = bid & 31;
    const int h = bh & 15, b = bh >> 4, kvh = h >> 2;

    const short* kbase  = k_states + (((size_t)b * NKV + kvh) * S_LEN) * 128;
    const short* vtbase = vt + (((size_t)b * NKV + kvh) * VD_) * S_LEN;

    const int qrow0 = qt * 128 + w * 32;
    const int qglob = qrow0 + l31;

    // Q fragments: B-operand of 32x32x16: col=q=l31, k = st*16 + hi*8 + [0..8)
    short8 qcur[8];
    {
        const short* qr = q_states +
            (((size_t)b * NH + h) * S_LEN + qt * 128 + w * 32 + l31) * 128 + hi * 8;
        #pragma unroll
        for (int st = 0; st < 8; ++st)
            qcur[st] = *reinterpret_cast<const short8*>(qr + st * 16);
    }

    float16v o[8];
    #pragma unroll
    for (int dt = 0; dt < 8; ++dt)
        #pragma unroll
        for (int r = 0; r < 16; ++r) o[dt][r] = 0.f;
    float mreg = -1e30f, lreg = 0.f;

    const int nkt = (qt + 1) * 4;   // KV tiles of 32

    // K tile 32x128 = 8KB: 2 gl_lds16/wave (8 rows/wave); swizzle row&15
    auto issueK = [&](int kt, int bufi) {
        const short* ksrc = kbase + (size_t)kt * 32 * 128;
        short* dst = &ks_lds[bufi][w * 1024];
        #pragma unroll
        for (int i = 0; i < 2; ++i) {
            int row = w * 8 + i * 4 + (lane >> 4), ch = lane & 15;
            gl_lds16(ksrc + row * 128 + ((ch ^ (row & 15)) * 8), dst + i * 512);
        }
    };
    // V^T tile 256x32 = 16KB: 4 gl_lds16/wave (64 rows/wave); swizzle row&3
    auto issueV = [&](int kt, int bufi) {
        const short* vsrc = vtbase + kt * 32;
        short* dst = &vt_lds[bufi][w * 2048];
        #pragma unroll
        for (int i = 0; i < 4; ++i) {
            int row = w * 64 + i * 16 + (lane >> 2), ch = lane & 3;
            gl_lds16(vsrc + (size_t)row * S_LEN + ((ch ^ (row & 3)) * 8),
                     dst + i * 512);
        }
    };

    // prologue: queue = [K0(2), V0(4), K1(2)] = 8 outstanding
    issueK(0, 0);
    issueV(0, 0);
    issueK(1, 1);

    for (int seq = 0; seq < nkt; ++seq) {
        if (seq < nkt - 1) { asm volatile("s_waitcnt vmcnt(2)" ::: "memory"); }
        else               { asm volatile("s_waitcnt vmcnt(0)" ::: "memory"); }
        __builtin_amdgcn_s_barrier();
        __builtin_amdgcn_sched_barrier(0);

        // issue next tiles (V first, then K — keeps the count invariant exact)
        if (seq + 1 < nkt) issueV(seq + 1, (seq + 1) & 1);
        if (seq + 2 < nkt) issueK(seq + 2, (seq + 2) % 3);

        if (seq * 32 <= qrow0 + 31) {
            const short* kbuf = ks_lds[seq % 3];

            // ---- S^T = K Q^T (one 32x32 tile) ----
            float16v s;
            #pragma unroll
            for (int r = 0; r < 16; ++r) s[r] = 0.f;
            __builtin_amdgcn_s_setprio(1);
            #pragma unroll
            for (int st = 0; st < 8; ++st) {
                short8 kf = *reinterpret_cast<const short8*>(
                    kbuf + l31 * 128 + (((st * 2 + hi) ^ (l31 & 15)) * 8));
                s = __builtin_amdgcn_mfma_f32_32x32x16_bf16(kf, qcur[st], s, 0, 0, 0);
            }
            __builtin_amdgcn_s_setprio(0);

            // ---- causal mask (rows = kv = (r&3)+8*(r>>2)+4*hi) ----
            if (seq * 32 + 31 > qrow0) {
                #pragma unroll
                for (int r = 0; r < 16; ++r) {
                    int kc = seq * 32 + ((r & 3) + 8 * (r >> 2) + 4 * hi);
                    if (kc > qglob) s[r] = -1e30f;
                }
            }

            // ---- per-lane scalar online softmax (exp2 domain) ----
            float mx = s[0];
            #pragma unroll
            for (int r = 1; r < 16; ++r) mx = fmaxf(mx, s[r]);
            mx = fmaxf(mx, __shfl_xor(mx, 32, 64));
            bool need = mx > mreg + 8.f;
            if (__ballot(need)) {
                float mnew = fmaxf(mreg, mx);
                float corr = exp2f(mreg - mnew);
                mreg = mnew;
                lreg *= corr;
                #pragma unroll
                for (int dt = 0; dt < 8; ++dt)
                    #pragma unroll
                    for (int r = 0; r < 16; ++r) o[dt][r] *= corr;
            }
            #pragma unroll
            for (int r = 0; r < 16; ++r) s[r] = exp2f(s[r] - mreg);
            float ps = 0.f;
            #pragma unroll
            for (int r = 0; r < 16; ++r) ps += s[r];
            ps += __shfl_xor(ps, 32, 64);
            lreg += ps;

            // ---- PA frags in-register + O^T += V^T * P^T ----
            const short* vbuf = vt_lds[seq & 1];
            __builtin_amdgcn_s_setprio(1);
            #pragma unroll
            for (int ks = 0; ks < 2; ++ks) {
                const int rb = ks * 8;
                int c01, c23, c45, c67;
                asm("v_cvt_pk_bf16_f32 %0, %1, %2" : "=v"(c01) : "v"(s[rb+0]), "v"(s[rb+1]));
                asm("v_cvt_pk_bf16_f32 %0, %1, %2" : "=v"(c23) : "v"(s[rb+2]), "v"(s[rb+3]));
                asm("v_cvt_pk_bf16_f32 %0, %1, %2" : "=v"(c45) : "v"(s[rb+4]), "v"(s[rb+5]));
                asm("v_cvt_pk_bf16_f32 %0, %1, %2" : "=v"(c67) : "v"(s[rb+6]), "v"(s[rb+7]));
                asm("v_permlane32_swap_b32 %0, %1" : "+v"(c01), "+v"(c45));
                asm("v_permlane32_swap_b32 %0, %1" : "+v"(c23), "+v"(c67));
                union { int4v i4; short8 s8; } u_;
                u_.i4.x = c01; u_.i4.y = c23; u_.i4.z = c45; u_.i4.w = c67;
                short8 pa = u_.s8;
                #pragma unroll
                for (int dt = 0; dt < 8; ++dt) {
                    int row = dt * 32 + l31;
                    short8 vf = *reinterpret_cast<const short8*>(
                        vbuf + row * 32 + (((ks * 2 + hi) ^ (row & 3)) * 8));
                    o[dt] = __builtin_amdgcn_mfma_f32_32x32x16_bf16(vf, pa, o[dt], 0, 0, 0);
                }
            }
            __builtin_amdgcn_s_setprio(0);
        }
    }

    // ---- epilogue ----
    {
        float invl = 1.f / lreg;
        int spos = qt * 128 + w * 32 + l31;
        short* obase = attn_out + (((size_t)b * S_LEN + spos) * NH + h) * VD_;
        #pragma unroll
        for (int dt = 0; dt < 8; ++dt)
            #pragma unroll
            for (int k4 = 0; k4 < 4; ++k4) {
                int d0 = dt * 32 + k4 * 8 + hi * 4;
                short4v pk;
                #pragma unroll
                for (int j = 0; j < 4; ++j) pk[j] = f2bf(o[dt][k4 * 4 + j] * invl);
                *reinterpret_cast<short4v*>(obase + d0) = pk;
            }
    }
}

// ---------------------------------------------------------------------------
// K5: out = attn_out (4096x4096 bf16) @ w_oT (2048x4096 bf16), f32 out.
//   XCD-aware block swizzle (512 % 8 == 0 -> simple bijective form).
// ---------------------------------------------------------------------------
__global__ __launch_bounds__(256)
void k5_gemm_mfma(const short* __restrict__ A,
                  const short* __restrict__ Bt,
                  float* __restrict__ C)
{
    __shared__ __align__(16) short at[128 * 64];
    __shared__ __align__(16) short bt[128 * 64];
    const int tid  = threadIdx.x;
    const int lane = tid & 63;
    const int wid  = tid >> 6;
    const int wm = wid >> 1, wn = wid & 1;
    const int g = lane >> 4, l15 = lane & 15;
    const int wg = (blockIdx.x & 7) * 64 + (blockIdx.x >> 3);   // XCD swizzle
    const int bn = wg & 15, bm = wg >> 4;
    const int m0 = bm * 128, n0 = bn * 128;

    float4v acc[4][4];
    #pragma unroll
    for (int mi = 0; mi < 4; ++mi)
        #pragma unroll
        for (int nj = 0; nj < 4; ++nj) acc[mi][nj] = (float4v){0.f, 0.f, 0.f, 0.f};

    for (int k0 = 0; k0 < 4096; k0 += 64) {
        __syncthreads();
        #pragma unroll
        for (int i = 0; i < 4; ++i) {
            int row = wid * 32 + i * 8 + (lane >> 3);
            int ch  = lane & 7;
            gl_lds16(A + (size_t)(m0 + row) * 4096 + k0 + ((ch ^ (row & 7)) * 8),
                     at + wid * 2048 + i * 512);
            gl_lds16(Bt + (size_t)(n0 + row) * 4096 + k0 + ((ch ^ (row & 7)) * 8),
                     bt + wid * 2048 + i * 512);
        }
        __syncthreads();

        #pragma unroll
        for (int kb = 0; kb < 2; ++kb) {
            short8 af[4], bfr[4];
            #pragma unroll
            for (int mi = 0; mi < 4; ++mi) {
                int row = wm * 64 + mi * 16 + l15;
                af[mi] = *reinterpret_cast<const short8*>(
                    at + row * 64 + (((g + 4 * kb) ^ (row & 7)) * 8));
            }
            #pragma unroll
            for (int nj = 0; nj < 4; ++nj) {
                int row = wn * 64 + nj * 16 + l15;
                bfr[nj] = *reinterpret_cast<const short8*>(
                    bt + row * 64 + (((g + 4 * kb) ^ (row & 7)) * 8));
            }
            #pragma unroll
            for (int mi = 0; mi < 4; ++mi)
                #pragma unroll
                for (int nj = 0; nj < 4; ++nj)
                    acc[mi][nj] = __builtin_amdgcn_mfma_f32_16x16x32_bf16(
                        af[mi], bfr[nj], acc[mi][nj], 0, 0, 0);
        }
    }

    #pragma unroll
    for (int mi = 0; mi < 4; ++mi)
        #pragma unroll
        for (int nj = 0; nj < 4; ++nj)
            #pragma unroll
            for (int r = 0; r < 4; ++r)
                C[(size_t)(m0 + wm * 64 + mi * 16 + g * 4 + r) * DIM + n0 + wn * 64 + nj * 16 + l15] =
                    acc[mi][nj][r];
}

// ---------------------------------------------------------------------------
extern "C" void kernel_launch(void* const* d_in, const int* in_sizes, int n_in,
                              void* d_out, int out_size, void* d_ws, size_t ws_size,
                              hipStream_t stream)
{
    const float* x        = (const float*)d_in[0];
    const float* w_dq     = (const float*)d_in[1];
    const float* gamma_q  = (const float*)d_in[2];
    const float* w_uq     = (const float*)d_in[3];
    const float* w_dkv    = (const float*)d_in[4];
    const float* gamma_kv = (const float*)d_in[5];
    const float* w_ukv    = (const float*)d_in[6];
    const float* w_o      = (const float*)d_in[7];
    float* out = (float*)d_out;

    char* ws = (char*)d_ws;
    float* kr_rope  = (float*)(ws);                       // 1 MB
    short* cq_bf    = (short*)(ws + (1ull  << 20));       // 1 MB
    short* ckv_bf   = (short*)(ws + (2ull  << 20));       // 1 MB
    float* tq       = (float*)(ws + (3ull  << 20));       // 0.25 MB
    float* tk       = (float*)(ws + (4ull  << 20));       // 0.5 MB
    short* w_uqT    = (short*)(ws + (5ull  << 20));       // 0.5 MB
    short* w_ukvT   = (short*)(ws + (6ull  << 20));       // 0.32 MB
    short* wdT      = (short*)(ws + (7ull  << 20));       // 1.25 MB
    short* q_states = (short*)(ws + (9ull  << 20));       // 16 MB
    short* k_states = (short*)(ws + (25ull << 20));       // 4 MB
    short* v_states = (short*)(ws + (29ull << 20));       // 8 MB
    short* vt       = (short*)(ws + (37ull << 20));       // 8 MB
    short* attn_out = (short*)(ws + (45ull << 20));       // 32 MB
    short* w_oT     = (short*)(ws + (77ull << 20));       // 16 MB
    // total 93 MB

    kprep_all<<<dim3(2696), dim3(256), 0, stream>>>(
        w_o, w_uq, w_ukv, w_dq, w_dkv, w_oT, w_uqT, w_ukvT, wdT, tq, tk);

    k1_mfma<<<dim3(ROWS_TOT / 16), dim3(256), 0, stream>>>(
        x, wdT, gamma_q, gamma_kv, tk, cq_bf, ckv_bf, kr_rope);

    k2_mfma<<<dim3((ROWS_TOT / 16) * 2), dim3(256), 0, stream>>>(
        cq_bf, w_uqT, tq, q_states);

    k3_mfma<<<dim3(ROWS_TOT / 16), dim3(256), 0, stream>>>(
        ckv_bf, w_ukvT, kr_rope, k_states, v_states);

    k3t_transpose_v<<<dim3(BATCH * NKV * 32 * 4), dim3(256), 0, stream>>>(
        v_states, vt);

    k4_attn_mfma<<<dim3(512), dim3(256), 0, stream>>>(
        q_states, k_states, vt, attn_out);

    k5_gemm_mfma<<<dim3((ROWS_TOT / 128) * (DIM / 128)), dim3(256), 0, stream>>>(
        attn_out, w_oT, out);
}

// Round 8
// 262.455 us; speedup vs baseline: 13.4304x; 1.1366x over previous
//
#include <hip/hip_runtime.h>
#include <hip/hip_bf16.h>
#include <math.h>

#define DIM   2048
#define S_LEN 2048
#define BATCH 2
#define NH    16
#define NKV   4
#define CQ_   128
#define QN_   96
#define QR_   32
#define CKV_  128
#define KN_   64
#define KR_   64
#define VD_   256
#define ROWS_TOT (BATCH*S_LEN)   // 4096
#define QK_SCALE 0.08838834764831845f
#define LOG2E    1.4426950408889634f

typedef __attribute__((ext_vector_type(8)))  short short8;
typedef __attribute__((ext_vector_type(4)))  short short4v;
typedef __attribute__((ext_vector_type(4)))  float float4v;
typedef __attribute__((ext_vector_type(16))) float float16v;
typedef __attribute__((ext_vector_type(4)))  int   int4v;

__device__ inline short f2bf(float x) {
    union { __hip_bfloat16 h; short s; } u;
    u.h = __float2bfloat16(x);
    return u.s;
}

// async global->LDS, 16B/lane; LDS dest wave-uniform base (HW: base+lane*16).
__device__ __forceinline__ void gl_lds16(const short* g, short* lds) {
    __builtin_amdgcn_global_load_lds(
        (const __attribute__((address_space(1))) unsigned int*)(g),
        (__attribute__((address_space(3))) unsigned int*)(lds),
        16, 0, 0);
}

// k_frag 16B-slot index (shorts): tile kt=kv>>6, then
//   u = ((kv&63)>>5)*512 + (d>>4)*64 + ((d>>3)&1)*32 + (kv&31); elem j = d&7
// v_frag: u = (d>>5)*256 + ((kv&63)>>5)*128 + ((kv>>4)&1)*64 + ((kv>>3)&1)*32
//             + (d&31); elem j = kv&7

// ---------------------------------------------------------------------------
// KPREP: all weight transposes (f32 -> bf16^T) + RoPE tables in ONE launch.
// ---------------------------------------------------------------------------
__global__ __launch_bounds__(256)
void kprep_all(const float* __restrict__ w_o, const float* __restrict__ w_uq,
               const float* __restrict__ w_ukv, const float* __restrict__ w_dq,
               const float* __restrict__ w_dkv,
               short* __restrict__ w_oT, short* __restrict__ w_uqT,
               short* __restrict__ w_ukvT, short* __restrict__ wdT,
               float* __restrict__ tq, float* __restrict__ tk)
{
    const int bid = blockIdx.x, tid = threadIdx.x;
    if (bid >= 2312) {
        int gid = (bid - 2312) * 256 + tid;
        int spos = gid / 48, e = gid - spos * 48;
        if (e < 16) {
            float inv = powf(10000.f, -(float)(2 * e) / 32.f);
            float sn, c; sincosf((float)spos * inv, &sn, &c);
            tq[(spos * 16 + e) * 2 + 0] = c;
            tq[(spos * 16 + e) * 2 + 1] = sn;
        } else {
            int i2 = e - 16;
            float inv = powf(10000.f, -(float)(2 * i2) / 64.f);
            float sn, c; sincosf((float)spos * inv, &sn, &c);
            tk[(spos * 32 + i2) * 2 + 0] = c;
            tk[(spos * 32 + i2) * 2 + 1] = sn;
        }
        return;
    }

    __shared__ float tf[64][65];
    int lb, nct, R; short* dst;
    if (bid < 2048)      { lb = bid;        nct = 32; R = 4096; dst = w_oT;   }
    else if (bid < 2112) { lb = bid - 2048; nct = 32; R = 128;  dst = w_uqT;  }
    else if (bid < 2152) { lb = bid - 2112; nct = 20; R = 128;  dst = w_ukvT; }
    else                 { lb = bid - 2152; nct = 5;  R = 2048; dst = wdT;    }
    const int ct = lb % nct, rt = lb / nct;
    const int r0 = rt * 64, c0 = ct * 64;
    const float* src; int stride, nbase;
    if (bid < 2048)      { src = w_o;   stride = 2048; nbase = c0; }
    else if (bid < 2112) { src = w_uq;  stride = 2048; nbase = c0; }
    else if (bid < 2152) { src = w_ukv; stride = 1280; nbase = c0; }
    else if (ct < 2)     { src = w_dq;  stride = 128;  nbase = c0; }
    else                 { src = w_dkv; stride = 192;  nbase = c0 - 128; }

    #pragma unroll
    for (int u4 = 0; u4 < 4; ++u4) {
        int u = u4 * 256 + tid;
        int kr = u >> 4, nc = (u & 15) * 4;
        float4 v = *reinterpret_cast<const float4*>(&src[(size_t)(r0 + kr) * stride + nbase + nc]);
        tf[kr][nc + 0] = v.x; tf[kr][nc + 1] = v.y;
        tf[kr][nc + 2] = v.z; tf[kr][nc + 3] = v.w;
    }
    __syncthreads();
    #pragma unroll
    for (int u2 = 0; u2 < 2; ++u2) {
        int u = u2 * 256 + tid;
        int nr = u >> 3, kc8 = (u & 7) * 8;
        short8 o;
        #pragma unroll
        for (int j = 0; j < 8; ++j) o[j] = f2bf(tf[kc8 + j][nr]);
        *reinterpret_cast<short8*>(&dst[(size_t)(c0 + nr) * R + r0 + kc8]) = o;
    }
}

// ---------------------------------------------------------------------------
// K1: MFMA GEMM (M-tile 16, N=320, K=2048) + fused LN + K-RoPE (table).
// ---------------------------------------------------------------------------
__global__ __launch_bounds__(256)
void k1_mfma(const float* __restrict__ x, const short* __restrict__ wdT,
             const float* __restrict__ gamma_q, const float* __restrict__ gamma_kv,
             const float* __restrict__ tk,
             short* __restrict__ cq_bf, short* __restrict__ ckv_bf,
             float* __restrict__ kr_rope)
{
    __shared__ float ys[16][321];
    __shared__ float st[16][4];
    const int tid = threadIdx.x, lane = tid & 63, w = tid >> 6;
    const int g = lane >> 4, l15 = lane & 15;
    const int m0 = blockIdx.x * 16;
    const int wn0 = w * 80;

    float4v acc[5];
    #pragma unroll
    for (int nj = 0; nj < 5; ++nj) acc[nj] = (float4v){0.f, 0.f, 0.f, 0.f};

    const float* arow = x + (size_t)(m0 + l15) * 2048 + g * 8;
    for (int ks = 0; ks < 64; ++ks) {
        float4 a0 = *reinterpret_cast<const float4*>(arow + ks * 32);
        float4 a1 = *reinterpret_cast<const float4*>(arow + ks * 32 + 4);
        short8 a;
        a[0] = f2bf(a0.x); a[1] = f2bf(a0.y); a[2] = f2bf(a0.z); a[3] = f2bf(a0.w);
        a[4] = f2bf(a1.x); a[5] = f2bf(a1.y); a[6] = f2bf(a1.z); a[7] = f2bf(a1.w);
        #pragma unroll
        for (int nj = 0; nj < 5; ++nj) {
            short8 bf = *reinterpret_cast<const short8*>(
                wdT + (size_t)(wn0 + nj * 16 + l15) * 2048 + ks * 32 + g * 8);
            acc[nj] = __builtin_amdgcn_mfma_f32_16x16x32_bf16(a, bf, acc[nj], 0, 0, 0);
        }
    }

    #pragma unroll
    for (int nj = 0; nj < 5; ++nj)
        #pragma unroll
        for (int r = 0; r < 4; ++r)
            ys[g * 4 + r][wn0 + nj * 16 + l15] = acc[nj][r];
    __syncthreads();

    if (tid < 32) {
        int row = tid >> 1, seg = tid & 1, base = seg * 128;
        float s1 = 0.f, s2 = 0.f;
        for (int j = 0; j < 128; ++j) { float v = ys[row][base + j]; s1 += v; s2 += v * v; }
        float mu  = s1 * (1.f / 128.f);
        float var = s2 * (1.f / 128.f) - mu * mu;
        st[row][seg * 2 + 0] = mu;
        st[row][seg * 2 + 1] = rsqrtf(var + 1e-5f);
    }
    __syncthreads();

    for (int i = tid; i < 16 * 320; i += 256) {
        int row = i / 320, col = i - row * 320;
        int r = m0 + row, spos = r & (S_LEN - 1);
        float v = ys[row][col];
        if (col < 128) {
            cq_bf[(size_t)r * CQ_ + col] =
                f2bf((v - st[row][0]) * st[row][1] * gamma_q[col] * (QK_SCALE * LOG2E));
        } else if (col < 256) {
            ckv_bf[(size_t)r * CKV_ + (col - 128)] =
                f2bf((v - st[row][2]) * st[row][3] * gamma_kv[col - 128]);
        } else {
            int d = col - 256, i2 = d >> 1;
            float xe = ys[row][256 + (d & ~1)];
            float xo = ys[row][256 + (d | 1)];
            float c  = tk[(spos * 32 + i2) * 2 + 0];
            float sn = tk[(spos * 32 + i2) * 2 + 1];
            kr_rope[(size_t)r * KR_ + d] = (d & 1) ? (xe * sn + xo * c)
                                                   : (xe * c - xo * sn);
        }
    }
}

// ---------------------------------------------------------------------------
// K2: q = cq_bf @ w_uq (MFMA, K=128) + Q-RoPE -> q_states bf16 (B,H,S,128)
// ---------------------------------------------------------------------------
__global__ __launch_bounds__(256)
void k2_mfma(const short* __restrict__ cq_bf, const short* __restrict__ w_uqT,
             const float* __restrict__ tq, short* __restrict__ q_states)
{
    const int tid = threadIdx.x, lane = tid & 63, w = tid >> 6;
    const int g = lane >> 4, l15 = lane & 15;
    const int bm = blockIdx.x >> 1, ns = blockIdx.x & 1;
    const int m0 = bm * 16;
    const int nb = ns * 1024 + w * 256;

    short8 af[4];
    #pragma unroll
    for (int ks = 0; ks < 4; ++ks)
        af[ks] = *reinterpret_cast<const short8*>(
            cq_bf + (size_t)(m0 + l15) * 128 + ks * 32 + g * 8);

    float4v acc[16];
    #pragma unroll
    for (int nj = 0; nj < 16; ++nj) acc[nj] = (float4v){0.f, 0.f, 0.f, 0.f};

    #pragma unroll
    for (int ks = 0; ks < 4; ++ks)
        #pragma unroll
        for (int nj = 0; nj < 16; ++nj) {
            short8 bf = *reinterpret_cast<const short8*>(
                w_uqT + (size_t)(nb + nj * 16 + l15) * 128 + ks * 32 + g * 8);
            acc[nj] = __builtin_amdgcn_mfma_f32_16x16x32_bf16(af[ks], bf, acc[nj], 0, 0, 0);
        }

    #pragma unroll
    for (int nj = 0; nj < 16; ++nj) {
        int j = nb + nj * 16 + l15;
        if (j < NH * QN_) {
            int h = j / QN_, d = j - h * QN_;
            #pragma unroll
            for (int r = 0; r < 4; ++r) {
                int rg = m0 + g * 4 + r, bb = rg >> 11, spos = rg & (S_LEN - 1);
                q_states[(((size_t)bb * NH + h) * S_LEN + spos) * 128 + d] =
                    f2bf(acc[nj][r]);
            }
        } else {
            int jj = j - NH * QN_;
            int h = jj >> 5, d = jj & 31, i2 = d >> 1;
            #pragma unroll
            for (int r = 0; r < 4; ++r) {
                int rg = m0 + g * 4 + r, bb = rg >> 11, spos = rg & (S_LEN - 1);
                float v = acc[nj][r];
                float p = __shfl_xor(v, 1, 64);
                float c  = tq[(spos * 16 + i2) * 2 + 0];
                float sn = tq[(spos * 16 + i2) * 2 + 1];
                float out = (d & 1) ? (p * sn + v * c) : (v * c - p * sn);
                q_states[(((size_t)bb * NH + h) * S_LEN + spos) * 128 + QN_ + d] =
                    f2bf(out);
            }
        }
    }
}

// ---------------------------------------------------------------------------
// K3: kv = ckv_bf @ w_ukv (MFMA, K=128) -> k_frag (fragment-major) + v_states
// ---------------------------------------------------------------------------
__global__ __launch_bounds__(256)
void k3_mfma(const short* __restrict__ ckv_bf, const short* __restrict__ w_ukvT,
             const float* __restrict__ kr_rope,
             short* __restrict__ k_frag, short* __restrict__ v_states)
{
    const int tid = threadIdx.x, lane = tid & 63, w = tid >> 6;
    const int g = lane >> 4, l15 = lane & 15;
    const int m0 = blockIdx.x * 16;
    const int nb = w * 320;

    short8 af[4];
    #pragma unroll
    for (int ks = 0; ks < 4; ++ks)
        af[ks] = *reinterpret_cast<const short8*>(
            ckv_bf + (size_t)(m0 + l15) * 128 + ks * 32 + g * 8);

    float4v acc[20];
    #pragma unroll
    for (int nj = 0; nj < 20; ++nj) acc[nj] = (float4v){0.f, 0.f, 0.f, 0.f};

    #pragma unroll
    for (int ks = 0; ks < 4; ++ks)
        #pragma unroll
        for (int nj = 0; nj < 20; ++nj) {
            short8 bf = *reinterpret_cast<const short8*>(
                w_ukvT + (size_t)(nb + nj * 16 + l15) * 128 + ks * 32 + g * 8);
            acc[nj] = __builtin_amdgcn_mfma_f32_16x16x32_bf16(af[ks], bf, acc[nj], 0, 0, 0);
        }

    #pragma unroll
    for (int nj = 0; nj < 20; ++nj) {
        int j = nb + nj * 16 + l15;
        if (j < NKV * KN_) {
            int kvh = j >> 6, d = j & 63;
            int stf = d >> 4, hif = (d >> 3) & 1, jo = d & 7;
            #pragma unroll
            for (int r = 0; r < 4; ++r) {
                int rg = m0 + g * 4 + r, bb = rg >> 11, spos = rg & (S_LEN - 1);
                int bk = bb * NKV + kvh;
                size_t idx = ((size_t)(bk * 32 + (spos >> 6)) * 1024
                              + ((spos >> 5) & 1) * 512 + stf * 64 + hif * 32
                              + (spos & 31)) * 8 + jo;
                k_frag[idx] = f2bf(acc[nj][r]);
            }
        } else {
            int jj = j - NKV * KN_;
            int kvh = jj >> 8, d = jj & 255;
            #pragma unroll
            for (int r = 0; r < 4; ++r) {
                int rg = m0 + g * 4 + r, bb = rg >> 11, spos = rg & (S_LEN - 1);
                v_states[(((size_t)bb * NKV + kvh) * S_LEN + spos) * VD_ + d] =
                    f2bf(acc[nj][r]);
            }
        }
    }

    for (int i = tid; i < 16 * KR_; i += 256) {
        int rr = i >> 6, dd = i & 63;       // rope dim dd -> d = 64+dd
        int rg = m0 + rr, bb = rg >> 11, spos = rg & (S_LEN - 1);
        short vv = f2bf(kr_rope[(size_t)rg * KR_ + dd]);
        int d = 64 + dd;
        int stf = d >> 4, hif = (d >> 3) & 1, jo = d & 7;
        size_t ubase = ((size_t)(spos >> 6)) * 1024
                       + ((spos >> 5) & 1) * 512 + stf * 64 + hif * 32 + (spos & 31);
        #pragma unroll
        for (int kvh = 0; kvh < NKV; ++kvh) {
            int bk = bb * NKV + kvh;
            k_frag[((size_t)bk * 32 * 1024 + ubase) * 8 + jo] = vv;
        }
    }
}

// ---------------------------------------------------------------------------
// K3T: v_states (B,KV,S,VD) bf16 -> v_frag (fragment-major LDS image).
// ---------------------------------------------------------------------------
__global__ __launch_bounds__(256)
void k3t_transpose_v(const short* __restrict__ v, short* __restrict__ v_frag)
{
    __shared__ short t[64][66];
    const int tid = threadIdx.x;
    const int vtile = blockIdx.x & 3;
    const int stile = (blockIdx.x >> 2) & 31;
    const int bk    = blockIdx.x >> 7;

    const short* src = v + ((size_t)bk * S_LEN + stile * 64) * VD_ + vtile * 64;
    #pragma unroll
    for (int u2 = 0; u2 < 2; ++u2) {
        int u = u2 * 256 + tid;
        int srow = u >> 3, vc8 = (u & 7) * 8;
        short8 val = *reinterpret_cast<const short8*>(src + (size_t)srow * VD_ + vc8);
        #pragma unroll
        for (int j = 0; j < 8; ++j) t[srow][vc8 + j] = val[j];
    }
    __syncthreads();
    short* dstbase = v_frag + (size_t)(bk * 32 + stile) * 16384;
    #pragma unroll
    for (int u2 = 0; u2 < 2; ++u2) {
        int u = u2 * 256 + tid;
        int vr = u >> 3, sc8 = (u & 7) * 8;   // d-local row, kv-local 8-chunk
        short8 o;
        #pragma unroll
        for (int j = 0; j < 8; ++j) o[j] = t[sc8 + j][vr];
        int d = vtile * 64 + vr;
        int dt = d >> 5, l31d = d & 31;
        int half = sc8 >> 5, ksf = (sc8 >> 4) & 1, hif = (sc8 >> 3) & 1;
        size_t idx16 = (size_t)dt * 256 + half * 128 + ksf * 64 + hif * 32 + l31d;
        *reinterpret_cast<short8*>(dstbase + idx16 * 8) = o;
    }
}

// ---------------------------------------------------------------------------
// K4: swapped-QK 32x32 MFMA flash attention, fragment-major LDS (0 bank
//   conflicts), coalesced frag-global staging, counted-vmcnt pipeline.
//   8 waves = 4 q-groups x 2 kv-halves; qtile 128; KVBLK=64; 112KB LDS,
//   1 block/CU, 2 waves/SIMD. Grid 512: heavy (qt 15..8) first, light
//   (qt 7..0) picked greedily by freeing CUs -> each CU ~34 iters.
//   Per-wave queue: [K(2),V(4),K(2)] -> vmcnt(2). Split-softmax merged
//   across kv-half wave pairs in the epilogue via LDS.
// ---------------------------------------------------------------------------
__global__ __launch_bounds__(512, 1)
void k4_attn_mfma(const short* __restrict__ q_states,
                  const short* __restrict__ k_frag,
                  const short* __restrict__ v_frag,
                  short* __restrict__ attn_out)
{
    __shared__ __align__(16) short ks_lds[3][8192];    // 3 x 16 KB
    __shared__ __align__(16) short vt_lds[2][16384];   // 2 x 32 KB

    const int tid = threadIdx.x, lane = tid & 63, w = tid >> 6;   // w 0..7
    const int l31 = lane & 31, hi = lane >> 5;
    const int g = w & 3, h = w >> 2;     // q-group, kv-half
    const int bid = blockIdx.x;
    const int qt = (bid < 256) ? (15 - (bid >> 5)) : (7 - ((bid - 256) >> 5));
    const int bh = bid & 31;
    const int h_head = bh & 15, b = bh >> 4, kvh = h_head >> 2;
    const int bk = b * NKV + kvh;

    const short* kfbase = k_frag + (size_t)bk * 32 * 8192;
    const short* vfbase = v_frag + (size_t)bk * 32 * 16384;

    const int qrow0 = qt * 128 + g * 32;
    const int qglob = qrow0 + l31;

    // Q fragments (B-operand): col=q=l31, k = st*16 + hi*8 + [0..8)
    short8 qcur[8];
    {
        const short* qr = q_states +
            (((size_t)b * NH + h_head) * S_LEN + qrow0 + l31) * 128 + hi * 8;
        #pragma unroll
        for (int st = 0; st < 8; ++st)
            qcur[st] = *reinterpret_cast<const short8*>(qr + st * 16);
    }

    float16v o[8];
    #pragma unroll
    for (int dt = 0; dt < 8; ++dt)
        #pragma unroll
        for (int r = 0; r < 16; ++r) o[dt][r] = 0.f;
    float mreg = -1e30f, lreg = 0.f;

    const int nkt = 2 * (qt + 1);   // KV tiles of 64

    // K tile: 16 chunks of 1KB; wave w stages chunks w*2, w*2+1 (coalesced)
    auto issueK = [&](int kt, int bufi) {
        const short* src = kfbase + (size_t)kt * 8192;
        #pragma unroll
        for (int i = 0; i < 2; ++i) {
            int c = w * 2 + i;
            gl_lds16(src + c * 512 + lane * 8, &ks_lds[bufi][c * 512]);
        }
    };
    // V tile: 32 chunks of 1KB; wave w stages chunks w*4..w*4+3
    auto issueV = [&](int kt, int bufi) {
        const short* src = vfbase + (size_t)kt * 16384;
        #pragma unroll
        for (int i = 0; i < 4; ++i) {
            int c = w * 4 + i;
            gl_lds16(src + c * 512 + lane * 8, &vt_lds[bufi][c * 512]);
        }
    };

    // prologue: queue per wave = [K0(2), V0(4), K1(2)] = 8 outstanding
    issueK(0, 0);
    issueV(0, 0);
    issueK(1, 1);

    for (int seq = 0; seq < nkt; ++seq) {
        if (seq < nkt - 1) { asm volatile("s_waitcnt vmcnt(2)" ::: "memory"); }
        else               { asm volatile("s_waitcnt vmcnt(0)" ::: "memory"); }
        __builtin_amdgcn_s_barrier();
        __builtin_amdgcn_sched_barrier(0);

        if (seq + 1 < nkt) issueV(seq + 1, (seq + 1) & 1);
        if (seq + 2 < nkt) issueK(seq + 2, (seq + 2) % 3);

        const int kvb = seq * 64 + h * 32;     // this wave's kv base
        if (kvb <= qrow0 + 31) {
            // ---- S^T = K Q^T (this wave's 32-kv half) ----
            const short* kbuf = &ks_lds[seq % 3][h * 4096];
            float16v s;
            #pragma unroll
            for (int r = 0; r < 16; ++r) s[r] = 0.f;
            __builtin_amdgcn_s_setprio(1);
            #pragma unroll
            for (int st = 0; st < 8; ++st) {
                short8 kf = *reinterpret_cast<const short8*>(kbuf + st * 512 + lane * 8);
                s = __builtin_amdgcn_mfma_f32_32x32x16_bf16(kf, qcur[st], s, 0, 0, 0);
            }
            __builtin_amdgcn_s_setprio(0);

            // ---- causal mask (rows = kv = (r&3)+8*(r>>2)+4*hi) ----
            if (kvb + 31 > qglob - (l31 == 31 ? 0 : 0)) {   // tile not fully below diag
                #pragma unroll
                for (int r = 0; r < 16; ++r) {
                    int kc = kvb + ((r & 3) + 8 * (r >> 2) + 4 * hi);
                    if (kc > qglob) s[r] = -1e30f;
                }
            }

            // ---- per-lane scalar online softmax (exp2 domain) ----
            float mx = s[0];
            #pragma unroll
            for (int r = 1; r < 16; ++r) mx = fmaxf(mx, s[r]);
            mx = fmaxf(mx, __shfl_xor(mx, 32, 64));
            bool need = mx > mreg + 8.f;
            if (__ballot(need)) {
                float mnew = fmaxf(mreg, mx);
                float corr = exp2f(mreg - mnew);
                mreg = mnew;
                lreg *= corr;
                #pragma unroll
                for (int dt = 0; dt < 8; ++dt)
                    #pragma unroll
                    for (int r = 0; r < 16; ++r) o[dt][r] *= corr;
            }
            #pragma unroll
            for (int r = 0; r < 16; ++r) s[r] = exp2f(s[r] - mreg);
            float ps = 0.f;
            #pragma unroll
            for (int r = 0; r < 16; ++r) ps += s[r];
            ps += __shfl_xor(ps, 32, 64);
            lreg += ps;

            // ---- PA frags in-register + O^T += V^T * P^T ----
            const short* vbuf = &vt_lds[seq & 1][h * 1024];
            __builtin_amdgcn_s_setprio(1);
            #pragma unroll
            for (int ks = 0; ks < 2; ++ks) {
                const int rb = ks * 8;
                int c01, c23, c45, c67;
                asm("v_cvt_pk_bf16_f32 %0, %1, %2" : "=v"(c01) : "v"(s[rb+0]), "v"(s[rb+1]));
                asm("v_cvt_pk_bf16_f32 %0, %1, %2" : "=v"(c23) : "v"(s[rb+2]), "v"(s[rb+3]));
                asm("v_cvt_pk_bf16_f32 %0, %1, %2" : "=v"(c45) : "v"(s[rb+4]), "v"(s[rb+5]));
                asm("v_cvt_pk_bf16_f32 %0, %1, %2" : "=v"(c67) : "v"(s[rb+6]), "v"(s[rb+7]));
                asm("v_permlane32_swap_b32 %0, %1" : "+v"(c01), "+v"(c45));
                asm("v_permlane32_swap_b32 %0, %1" : "+v"(c23), "+v"(c67));
                union { int4v i4; short8 s8; } u_;
                u_.i4.x = c01; u_.i4.y = c23; u_.i4.z = c45; u_.i4.w = c67;
                short8 pa = u_.s8;
                #pragma unroll
                for (int dt = 0; dt < 8; ++dt) {
                    short8 vf = *reinterpret_cast<const short8*>(
                        vbuf + dt * 2048 + ks * 512 + lane * 8);
                    o[dt] = __builtin_amdgcn_mfma_f32_32x32x16_bf16(vf, pa, o[dt], 0, 0, 0);
                }
            }
            __builtin_amdgcn_s_setprio(0);
        }
    }

    // ---- epilogue: merge kv-half wave pairs (split-softmax), store ----
    __syncthreads();
    {
        float* mlb = (float*)(&ks_lds[0][0]);
        mlb[w * 64 + lane] = mreg;
        mlb[512 + w * 64 + lane] = lreg;
    }
    __syncthreads();
    float s0f = 0.f, s1f = 0.f;
    if (h == 0) {
        float* mlb = (float*)(&ks_lds[0][0]);
        float m1 = mlb[(w + 4) * 64 + lane];
        float l1 = mlb[512 + (w + 4) * 64 + lane];
        float ms = fmaxf(mreg, m1);
        float c0 = exp2f(mreg - ms), c1 = exp2f(m1 - ms);
        float ls = lreg * c0 + l1 * c1;
        s0f = c0 / ls; s1f = c1 / ls;
    }
    float* cb = (float*)(&ks_lds[0][0]) + 1024;    // [16][4][64] f32 = 16KB
    short* obase = attn_out + (((size_t)b * S_LEN + qglob) * NH + h_head) * VD_;
    for (int dt = 0; dt < 8; ++dt) {
        __syncthreads();
        if (h == 1) {
            #pragma unroll
            for (int r = 0; r < 16; ++r)
                cb[r * 256 + g * 64 + lane] = o[dt][r];
        }
        __syncthreads();
        if (h == 0) {
            #pragma unroll
            for (int r = 0; r < 16; ++r)
                o[dt][r] = o[dt][r] * s0f + cb[r * 256 + g * 64 + lane] * s1f;
            #pragma unroll
            for (int k4i = 0; k4i < 4; ++k4i) {
                int d0 = dt * 32 + k4i * 8 + hi * 4;
                short4v pk;
                #pragma unroll
                for (int j = 0; j < 4; ++j) pk[j] = f2bf(o[dt][k4i * 4 + j]);
                *reinterpret_cast<short4v*>(obase + d0) = pk;
            }
        }
    }
}

// ---------------------------------------------------------------------------
// K5: out = attn_out (4096x4096 bf16) @ w_oT (2048x4096 bf16), f32 out.
// ---------------------------------------------------------------------------
__global__ __launch_bounds__(256)
void k5_gemm_mfma(const short* __restrict__ A,
                  const short* __restrict__ Bt,
                  float* __restrict__ C)
{
    __shared__ __align__(16) short at[128 * 64];
    __shared__ __align__(16) short bt[128 * 64];
    const int tid  = threadIdx.x;
    const int lane = tid & 63;
    const int wid  = tid >> 6;
    const int wm = wid >> 1, wn = wid & 1;
    const int g = lane >> 4, l15 = lane & 15;
    const int wg = (blockIdx.x & 7) * 64 + (blockIdx.x >> 3);   // XCD swizzle
    const int bn = wg & 15, bm = wg >> 4;
    const int m0 = bm * 128, n0 = bn * 128;

    float4v acc[4][4];
    #pragma unroll
    for (int mi = 0; mi < 4; ++mi)
        #pragma unroll
        for (int nj = 0; nj < 4; ++nj) acc[mi][nj] = (float4v){0.f, 0.f, 0.f, 0.f};

    for (int k0 = 0; k0 < 4096; k0 += 64) {
        __syncthreads();
        #pragma unroll
        for (int i = 0; i < 4; ++i) {
            int row = wid * 32 + i * 8 + (lane >> 3);
            int ch  = lane & 7;
            gl_lds16(A + (size_t)(m0 + row) * 4096 + k0 + ((ch ^ (row & 7)) * 8),
                     at + wid * 2048 + i * 512);
            gl_lds16(Bt + (size_t)(n0 + row) * 4096 + k0 + ((ch ^ (row & 7)) * 8),
                     bt + wid * 2048 + i * 512);
        }
        __syncthreads();

        #pragma unroll
        for (int kb = 0; kb < 2; ++kb) {
            short8 af[4], bfr[4];
            #pragma unroll
            for (int mi = 0; mi < 4; ++mi) {
                int row = wm * 64 + mi * 16 + l15;
                af[mi] = *reinterpret_cast<const short8*>(
                    at + row * 64 + (((g + 4 * kb) ^ (row & 7)) * 8));
            }
            #pragma unroll
            for (int nj = 0; nj < 4; ++nj) {
                int row = wn * 64 + nj * 16 + l15;
                bfr[nj] = *reinterpret_cast<const short8*>(
                    bt + row * 64 + (((g + 4 * kb) ^ (row & 7)) * 8));
            }
            #pragma unroll
            for (int mi = 0; mi < 4; ++mi)
                #pragma unroll
                for (int nj = 0; nj < 4; ++nj)
                    acc[mi][nj] = __builtin_amdgcn_mfma_f32_16x16x32_bf16(
                        af[mi], bfr[nj], acc[mi][nj], 0, 0, 0);
        }
    }

    #pragma unroll
    for (int mi = 0; mi < 4; ++mi)
        #pragma unroll
        for (int nj = 0; nj < 4; ++nj)
            #pragma unroll
            for (int r = 0; r < 4; ++r)
                C[(size_t)(m0 + wm * 64 + mi * 16 + g * 4 + r) * DIM + n0 + wn * 64 + nj * 16 + l15] =
                    acc[mi][nj][r];
}

// ---------------------------------------------------------------------------
extern "C" void kernel_launch(void* const* d_in, const int* in_sizes, int n_in,
                              void* d_out, int out_size, void* d_ws, size_t ws_size,
                              hipStream_t stream)
{
    const float* x        = (const float*)d_in[0];
    const float* w_dq     = (const float*)d_in[1];
    const float* gamma_q  = (const float*)d_in[2];
    const float* w_uq     = (const float*)d_in[3];
    const float* w_dkv    = (const float*)d_in[4];
    const float* gamma_kv = (const float*)d_in[5];
    const float* w_ukv    = (const float*)d_in[6];
    const float* w_o      = (const float*)d_in[7];
    float* out = (float*)d_out;

    char* ws = (char*)d_ws;
    float* kr_rope  = (float*)(ws);                       // 1 MB
    short* cq_bf    = (short*)(ws + (1ull  << 20));       // 1 MB
    short* ckv_bf   = (short*)(ws + (2ull  << 20));       // 1 MB
    float* tq       = (float*)(ws + (3ull  << 20));       // 0.25 MB
    float* tk       = (float*)(ws + (4ull  << 20));       // 0.5 MB
    short* w_uqT    = (short*)(ws + (5ull  << 20));       // 0.5 MB
    short* w_ukvT   = (short*)(ws + (6ull  << 20));       // 0.32 MB
    short* wdT      = (short*)(ws + (7ull  << 20));       // 1.25 MB
    short* q_states = (short*)(ws + (9ull  << 20));       // 16 MB
    short* k_frag   = (short*)(ws + (25ull << 20));       // 4 MB
    short* v_states = (short*)(ws + (29ull << 20));       // 8 MB
    short* v_frag   = (short*)(ws + (37ull << 20));       // 8 MB
    short* attn_out = (short*)(ws + (45ull << 20));       // 32 MB
    short* w_oT     = (short*)(ws + (77ull << 20));       // 16 MB
    // total 93 MB

    kprep_all<<<dim3(2696), dim3(256), 0, stream>>>(
        w_o, w_uq, w_ukv, w_dq, w_dkv, w_oT, w_uqT, w_ukvT, wdT, tq, tk);

    k1_mfma<<<dim3(ROWS_TOT / 16), dim3(256), 0, stream>>>(
        x, wdT, gamma_q, gamma_kv, tk, cq_bf, ckv_bf, kr_rope);

    k2_mfma<<<dim3((ROWS_TOT / 16) * 2), dim3(256), 0, stream>>>(
        cq_bf, w_uqT, tq, q_states);

    k3_mfma<<<dim3(ROWS_TOT / 16), dim3(256), 0, stream>>>(
        ckv_bf, w_ukvT, kr_rope, k_frag, v_states);

    k3t_transpose_v<<<dim3(BATCH * NKV * 32 * 4), dim3(256), 0, stream>>>(
        v_states, v_frag);

    k4_attn_mfma<<<dim3(512), dim3(512), 0, stream>>>(
        q_states, k_frag, v_frag, attn_out);

    k5_gemm_mfma<<<dim3((ROWS_TOT / 128) * (DIM / 128)), dim3(256), 0, stream>>>(
        attn_out, w_oT, out);
}